// Round 3
// baseline (476.158 us; speedup 1.0000x reference)
//
#include <hip/hip_runtime.h>
#include <math.h>

static constexpr int Bn = 2048;   // batch
static constexpr int Nn = 256;    // memory locations
static constexpr int Mn = 128;    // memory width
static constexpr int Un = 512;    // units

// Workspace layout (f32 offsets)
static constexpr size_t OFF_H0C   = 0;        // 512
static constexpr size_t OFF_Z0C   = 512;      // 2048 (gate-permuted)
static constexpr size_t OFF_Z1C   = 2560;     // 2048 (gate-permuted)
static constexpr size_t OFF_MNORM = 4608;     // 256
static constexpr size_t OFF_APREV = 4864;     // 1024
static constexpr size_t OFF_BIASH = 5888;     // 1152
static constexpr size_t OFF_KNORM = 7040;     // 8192
static constexpr size_t OFF_KMAT  = 16384;                          // f32 [8192][256]
static constexpr size_t OFF_HEADS = OFF_KMAT + (size_t)8192 * 256;  // f32 [2048][1048]
static constexpr size_t OFF_AT    = OFF_HEADS + (size_t)2048 * 1048;// f32 [2][2048][256]
static constexpr size_t OFF_ERA   = OFF_AT + (size_t)2 * 2048 * 256;// f32 [2048][2][128]
static constexpr size_t OFF_ADD   = OFF_ERA + (size_t)2048 * 256;
static constexpr size_t OFF_XHB   = OFF_ADD + (size_t)2048 * 256;   // bf16 [2048][1024]
static constexpr size_t OFF_HCAT  = OFF_XHB + 524288;               // bf16 [2048][1024]
static constexpr size_t OFF_W0T   = OFF_HCAT + 524288;              // bf16 [2048][512]
static constexpr size_t OFF_W1T   = OFF_W0T + 524288;               // bf16 [2048][1024]
static constexpr size_t OFF_WRWT  = OFF_W1T + 1048576;              // bf16 [1152][512]
static constexpr size_t OFF_WCOMB = OFF_WRWT + 294912;              // bf16 [512][1024]
static constexpr size_t OFF_WR2T  = OFF_WCOMB + 262144;             // bf16 [512][256]
static constexpr size_t OFF_M0B   = OFF_WR2T + 65536;               // bf16 [256][128]
static constexpr size_t OFF_KBUF  = OFF_M0B + 16384;                // bf16 [8192][128]

#define DEV __device__ __forceinline__

typedef __attribute__((ext_vector_type(8))) short bf16x8;
typedef __attribute__((ext_vector_type(4))) float f32x4;
typedef __attribute__((ext_vector_type(8))) unsigned short ushort8;
typedef unsigned int u32;

DEV float sigf(float x) { return 1.0f / (1.0f + expf(-x)); }
DEV float softplusf(float x) { return x > 20.0f ? x : log1pf(expf(x)); }
DEV unsigned short f2bf(float f) {   // RNE float->bf16
    unsigned u = __float_as_uint(f);
    u = (u + 0x7FFFu + ((u >> 16) & 1u)) >> 16;
    return (unsigned short)u;
}
DEV void gload16(const unsigned short* g, unsigned short* l) {
    __builtin_amdgcn_global_load_lds(
        (const __attribute__((address_space(1))) u32*)g,
        (__attribute__((address_space(3))) u32*)l, 16, 0, 0);
}

DEV float blk_reduce_max(float v, float* red) {
    int tid = threadIdx.x;
    red[tid] = v; __syncthreads();
    for (int s = (int)blockDim.x >> 1; s > 0; s >>= 1) {
        if (tid < s) red[tid] = fmaxf(red[tid], red[tid + s]);
        __syncthreads();
    }
    float r = red[0]; __syncthreads();
    return r;
}
DEV float blk_reduce_sum(float v, float* red) {
    int tid = threadIdx.x;
    red[tid] = v; __syncthreads();
    for (int s = (int)blockDim.x >> 1; s > 0; s >>= 1) {
        if (tid < s) red[tid] += red[tid + s];
        __syncthreads();
    }
    float r = red[0]; __syncthreads();
    return r;
}

// ===========================================================================
// Shared GEMM machinery: 128x128 tile, 4 waves (2x2), BK=64, double-buffered
// LDS filled via global_load_lds (16B), XOR-swizzled via pre-swizzled source.
// A bf16 [M][lda], Wt bf16 [N][ldw] (weights pre-transposed).
// ===========================================================================
#define GEMM_STAGE(buf, k0)                                                     \
    {                                                                           \
        _Pragma("unroll")                                                       \
        for (int q = 0; q < 4; ++q) {                                           \
            gload16(A  + (size_t)(row0 + q * 32 + (tid >> 3)) * lda + (k0) + ke,\
                    &As[buf][q * 2048 + tid * 8]);                              \
            gload16(Wt + (size_t)(col0 + q * 32 + (tid >> 3)) * ldw + (k0) + ke,\
                    &Ws[buf][q * 2048 + tid * 8]);                              \
        }                                                                       \
    }

#define GEMM_PROLOG                                                             \
    __shared__ __align__(16) unsigned short As[2][128 * 64];                    \
    __shared__ __align__(16) unsigned short Ws[2][128 * 64];                    \
    const int tid  = threadIdx.x;                                               \
    const int lane = tid & 63;                                                  \
    const int wave = tid >> 6;                                                  \
    const int wr = wave >> 1, wc = wave & 1;                                    \
    const int row0 = blockIdx.x * 128;                                          \
    const int col0 = blockIdx.y * 128;                                          \
    const int ke = ((tid & 7) * 8) ^ (((tid >> 3) & 7) << 3);                   \
    const int frow = lane & 15;                                                 \
    const int fko  = (lane >> 4) * 8;                                           \
    const int fxm  = (frow & 7) << 3;                                           \
    f32x4 acc[4][4];                                                            \
    _Pragma("unroll")                                                           \
    for (int i = 0; i < 4; ++i)                                                 \
        _Pragma("unroll")                                                       \
        for (int j = 0; j < 4; ++j) acc[i][j] = (f32x4){0.f, 0.f, 0.f, 0.f};

#define GEMM_MAINLOOP(Kr)                                                       \
    {                                                                           \
        const int nt = (Kr) >> 6;                                               \
        int cur = 0;                                                            \
        GEMM_STAGE(0, 0);                                                       \
        for (int t = 0; t < nt; ++t) {                                          \
            __syncthreads();   /* drains vmcnt: buf[cur] ready, prev reads done */ \
            if (t + 1 < nt) GEMM_STAGE(cur ^ 1, (t + 1) * 64);                  \
            const unsigned short* Ab = As[cur];                                 \
            const unsigned short* Wb = Ws[cur];                                 \
            bf16x8 af[2][4], wf[2][4];                                          \
            _Pragma("unroll")                                                   \
            for (int kk = 0; kk < 2; ++kk) {                                    \
                _Pragma("unroll")                                               \
                for (int i = 0; i < 4; ++i) {                                   \
                    int fr = wr * 64 + i * 16 + frow;                           \
                    af[kk][i] = *(const bf16x8*)&Ab[fr * 64 + ((kk * 32 + fko) ^ fxm)]; \
                }                                                               \
                _Pragma("unroll")                                               \
                for (int j = 0; j < 4; ++j) {                                   \
                    int fr = wc * 64 + j * 16 + frow;                           \
                    wf[kk][j] = *(const bf16x8*)&Wb[fr * 64 + ((kk * 32 + fko) ^ fxm)]; \
                }                                                               \
            }                                                                   \
            _Pragma("unroll")                                                   \
            for (int kk = 0; kk < 2; ++kk)                                      \
                _Pragma("unroll")                                               \
                for (int i = 0; i < 4; ++i)                                     \
                    _Pragma("unroll")                                           \
                    for (int j = 0; j < 4; ++j)                                 \
                        acc[i][j] = __builtin_amdgcn_mfma_f32_16x16x32_bf16(    \
                            af[kk][i], wf[kk][j], acc[i][j], 0, 0, 0);          \
            cur ^= 1;                                                           \
        }                                                                       \
    }

// Generic GEMM. epi: 0=f32 out(+bias), 1=f32+bias+clip, 2=bf16 out (Cb)
__global__ __launch_bounds__(256) void gemm_bf16(
    const unsigned short* __restrict__ A, int lda,
    const unsigned short* __restrict__ Wt, int ldw,
    const float* __restrict__ bias,
    float* __restrict__ C, unsigned short* __restrict__ Cb, int ldc,
    int Nr, int Kr, int epi)
{
    GEMM_PROLOG
    GEMM_MAINLOOP(Kr)
    #pragma unroll
    for (int i = 0; i < 4; ++i) {
        int m0r = row0 + wr * 64 + i * 16 + (lane >> 4) * 4;
        #pragma unroll
        for (int j = 0; j < 4; ++j) {
            int n = col0 + wc * 64 + j * 16 + (lane & 15);
            if (n >= Nr) continue;
            float bv = bias ? bias[n] : 0.f;
            #pragma unroll
            for (int r = 0; r < 4; ++r) {
                float v = acc[i][j][r] + bv;
                if (epi == 1) v = fminf(fmaxf(v, -20.f), 20.f);
                if (epi == 2) Cb[(size_t)(m0r + r) * ldc + n] = f2bf(v);
                else          C [(size_t)(m0r + r) * ldc + n] = v;
            }
        }
    }
}

// LSTM GEMM: W columns gate-permuted (c = 64q+16g+uu -> orig col g*512+q*16+uu),
// so each wave's j-fragments are the 4 gates of unit u. Epilogue applies the
// cell nonlinearity and writes h (bf16) directly.
__global__ __launch_bounds__(256) void gemm_lstm(
    const unsigned short* __restrict__ A, int lda,
    const unsigned short* __restrict__ Wt, int ldw,
    const float* __restrict__ biasP, const float* __restrict__ c0,
    unsigned short* __restrict__ hout, int ldh, int Kr, int doclip)
{
    GEMM_PROLOG
    GEMM_MAINLOOP(Kr)
    const int uu = lane & 15;
    const int uq = ((col0 >> 6) + wc) * 16 + uu;     // unit index
    const float c0v = c0[uq];
    const int cb = col0 + wc * 64 + uu;
    const float bi = biasP[cb], bfv = biasP[cb + 16],
                bgv = biasP[cb + 32], bov = biasP[cb + 48];
    #pragma unroll
    for (int i = 0; i < 4; ++i) {
        int rbase = row0 + wr * 64 + i * 16 + (lane >> 4) * 4;
        #pragma unroll
        for (int r = 0; r < 4; ++r) {
            float ig = acc[i][0][r] + bi;
            float fg = acc[i][1][r] + bfv;
            float gg = acc[i][2][r] + bgv;
            float og = acc[i][3][r] + bov;
            float c = sigf(fg) * c0v + sigf(ig) * tanhf(gg);
            float h = sigf(og) * tanhf(c);
            if (doclip) h = fminf(fmaxf(h, -20.f), 20.f);
            hout[(size_t)(rbase + r) * ldh + uq] = f2bf(h);
        }
    }
}

// ===========================================================================
// f32 -> bf16 copy (8-wide)
__global__ void k_cvt8(const float* __restrict__ src, int lds,
                       unsigned short* __restrict__ dst, int ldd,
                       int c8, size_t total)
{
    for (size_t idx = (size_t)blockIdx.x * blockDim.x + threadIdx.x;
         idx < total; idx += (size_t)gridDim.x * blockDim.x) {
        size_t r = idx / c8, c = (idx % c8) * 8;
        const float* s = src + r * lds + c;
        float4 v0 = *(const float4*)s;
        float4 v1 = *(const float4*)(s + 4);
        ushort8 o;
        o[0] = f2bf(v0.x); o[1] = f2bf(v0.y); o[2] = f2bf(v0.z); o[3] = f2bf(v0.w);
        o[4] = f2bf(v1.x); o[5] = f2bf(v1.y); o[6] = f2bf(v1.z); o[7] = f2bf(v1.w);
        *(ushort8*)(dst + r * ldd + c) = o;
    }
}

// f32 -> bf16 transpose: dst[c][r] = src[r][map(c)]; mode 1 = LSTM gate permute
__global__ void k_cvtT(const float* __restrict__ src, int R, int C, int lds,
                       unsigned short* __restrict__ dst, int ldd, int mode)
{
    __shared__ float t[32][33];
    const int bx = blockIdx.x * 32;   // over C (dst rows)
    const int by = blockIdx.y * 32;   // over R
    const int x = threadIdx.x;
    for (int y = threadIdx.y; y < 32; y += 8) {
        int r = by + y, c = bx + x;
        int scol = c;
        if (mode == 1) scol = ((c >> 4) & 3) * 512 + (c >> 6) * 16 + (c & 15);
        t[y][x] = (r < R && c < C) ? src[(size_t)r * lds + scol] : 0.f;
    }
    __syncthreads();
    for (int y = threadIdx.y; y < 32; y += 8) {
        int c = bx + y, r = by + x;
        if (c < C && r < R) dst[(size_t)c * ldd + r] = f2bf(t[x][y]);
    }
}

// Batch-invariant constants
__global__ __launch_bounds__(256) void k_const_a(
    const float* __restrict__ R0, const float* __restrict__ W_prep,
    const float* __restrict__ b_prep, const float* __restrict__ A0,
    const float* __restrict__ m0, const float* __restrict__ b_r,
    const float* __restrict__ b_w, float* __restrict__ ws)
{
    __shared__ float r0s[256];
    __shared__ float red[256];
    const int tid = threadIdx.x;
    r0s[tid] = tanhf(R0[tid]);
    __syncthreads();
    #pragma unroll
    for (int uu = 0; uu < 2; ++uu) {
        int u = tid + uu * 256;
        float acc = b_prep[u];
        for (int k = 0; k < 256; ++k)
            acc = fmaf(r0s[k], W_prep[(size_t)k * 512 + u], acc);
        ws[OFF_H0C + u] = acc;
    }
    for (int i = 0; i < 4; ++i) {
        float v = A0[i * 256 + tid];
        float mx = blk_reduce_max(v, red);
        float e = expf(v - mx);
        float s = blk_reduce_sum(e, red);
        ws[OFF_APREV + i * 256 + tid] = e / s;
    }
    float acc = 0.f;
    for (int m = 0; m < 128; ++m) {
        float t = m0[(size_t)tid * 128 + m];
        acc = fmaf(t, t, acc);
    }
    ws[OFF_MNORM + tid] = sqrtf(acc);
    for (int j = tid; j < 1152; j += 256)
        ws[OFF_BIASH + j] = (j < 268) ? b_r[j] : (j < 1048 ? b_w[j - 268] : 0.f);
}

// Constant LSTM gate contributions, stored GATE-PERMUTED
__global__ __launch_bounds__(256) void k_const_b(
    const float* __restrict__ H0, const float* __restrict__ W_lstm,
    const float* __restrict__ b_lstm, float* __restrict__ ws)
{
    const int blk = blockIdx.x, tid = threadIdx.x;
    const int c = (blk & 7) * 256 + tid;
    const int j = ((c >> 4) & 3) * 512 + (c >> 6) * 16 + (c & 15);
    if (blk < 8) {
        float acc = b_lstm[j];
        for (int u = 0; u < 512; ++u)
            acc = fmaf(ws[OFF_H0C + u], W_lstm[(size_t)(512 + u) * 2048 + j], acc);
        for (int u = 0; u < 512; ++u)
            acc = fmaf(H0[u], W_lstm[(size_t)(1024 + u) * 2048 + j], acc);
        ws[OFF_Z0C + c] = acc;
    } else {
        const float* W1 = W_lstm + (size_t)1536 * 2048;
        float acc = b_lstm[2048 + j];
        for (int u = 0; u < 512; ++u)
            acc = fmaf(H0[512 + u], W1[(size_t)(1024 + u) * 2048 + j], acc);
        ws[OFF_Z1C + c] = acc;
    }
}

// Per-(b,head): k = tanh(hd[:128]) -> KBUF bf16, knorm; write heads: erase/add
__global__ __launch_bounds__(128) void k_kprep(
    const float* __restrict__ heads, unsigned short* __restrict__ kbuf,
    float* __restrict__ knorm, float* __restrict__ era, float* __restrict__ addv)
{
    __shared__ float red[128];
    const int b = blockIdx.x, i = blockIdx.y, tid = threadIdx.x;
    const int cb = (i < 2) ? i * 134 : 268 + (i - 2) * 390;
    const float* hd = heads + (size_t)b * 1048 + cb;
    float k = tanhf(hd[tid]);
    kbuf[((size_t)b * 4 + i) * 128 + tid] = f2bf(k);
    float sq = blk_reduce_sum(k * k, red);
    if (tid == 0) knorm[b * 4 + i] = sqrtf(sq);
    if (i >= 2) {
        int ii = i - 2;
        era [((size_t)b * 2 + ii) * 128 + tid] = sigf(hd[134 + tid]);
        addv[((size_t)b * 2 + ii) * 128 + tid] = tanhf(hd[262 + tid]);
    }
}

// Addressing: read heads -> A (bf16 into HCAT); write heads -> AT f32
__global__ __launch_bounds__(256) void k_addr(
    const float* __restrict__ heads, const float* __restrict__ kmat,
    const float* __restrict__ knorm, const float* __restrict__ mnorm,
    const float* __restrict__ aprev, float* __restrict__ at,
    unsigned short* __restrict__ hcat)
{
    __shared__ float red[256];
    __shared__ float wgs[256];
    __shared__ float sc[6];
    const int b = blockIdx.x, i = blockIdx.y, tid = threadIdx.x;
    const int cb = (i < 2) ? i * 134 : 268 + (i - 2) * 390;
    const float* hd = heads + (size_t)b * 1048 + cb;
    if (tid == 0) {
        sc[0] = softplusf(hd[128]);
        sc[1] = sigf(hd[129]);
        float v0 = hd[130], v1 = hd[131], v2 = hd[132];
        float mx = fmaxf(v0, fmaxf(v1, v2));
        float e0 = expf(v0 - mx), e1 = expf(v1 - mx), e2 = expf(v2 - mx);
        float ssum = e0 + e1 + e2;
        sc[2] = e0 / ssum; sc[3] = e1 / ssum; sc[4] = e2 / ssum;
        sc[5] = softplusf(hd[133]);
    }
    __syncthreads();
    const float beta = sc[0], g = sc[1], s0 = sc[2], s1 = sc[3], s2 = sc[4],
                gamma = sc[5];
    float inner = kmat[((size_t)b * 4 + i) * 256 + tid];
    float kn = knorm[b * 4 + i];
    float K = inner / (kn * mnorm[tid] + 1e-8f);
    float x = beta * K;
    float mx = blk_reduce_max(x, red);
    float e = expf(x - mx);
    float se = blk_reduce_sum(e, red);
    float wc = e / se;
    float wg = g * wc + (1.f - g) * aprev[i * 256 + tid];
    wgs[tid] = wg;
    __syncthreads();
    float wconv = s0 * wg + s1 * wgs[(tid + 255) & 255] + s2 * wgs[(tid + 1) & 255];
    float wsh = powf(wconv, gamma);
    float ssum = blk_reduce_sum(wsh, red);
    float w = wsh / ssum;
    if (i < 2) hcat[(size_t)b * 1024 + 512 + i * 256 + tid] = f2bf(w);
    else       at[((size_t)(i - 2) * Bn + b) * 256 + tid] = w;
}

// m_t streaming update
__global__ void k_mem(const float* __restrict__ m0, const float* __restrict__ at,
                      const float* __restrict__ era, const float* __restrict__ addv,
                      float* __restrict__ outm)
{
    const size_t total = (size_t)Bn * Nn * (Mn / 4);
    for (size_t idx = (size_t)blockIdx.x * blockDim.x + threadIdx.x;
         idx < total; idx += (size_t)gridDim.x * blockDim.x) {
        int mq = (int)(idx & 31);
        int n  = (int)((idx >> 5) & 255);
        int b  = (int)(idx >> 13);
        float4 t  = reinterpret_cast<const float4*>(m0)[n * 32 + mq];
        float w0 = at[((size_t)0 * Bn + b) * 256 + n];
        float w1 = at[((size_t)1 * Bn + b) * 256 + n];
        float4 e0 = reinterpret_cast<const float4*>(era) [((size_t)b * 2 + 0) * 32 + mq];
        float4 a0 = reinterpret_cast<const float4*>(addv)[((size_t)b * 2 + 0) * 32 + mq];
        float4 e1 = reinterpret_cast<const float4*>(era) [((size_t)b * 2 + 1) * 32 + mq];
        float4 a1 = reinterpret_cast<const float4*>(addv)[((size_t)b * 2 + 1) * 32 + mq];
#define UPD(c) { t.c = t.c * (1.f - w0 * e0.c) + w0 * a0.c; \
                 t.c = t.c * (1.f - w1 * e1.c) + w1 * a1.c; }
        UPD(x) UPD(y) UPD(z) UPD(w)
#undef UPD
        reinterpret_cast<float4*>(outm)[idx] = t;
    }
}

extern "C" void kernel_launch(void* const* d_in, const int* in_sizes, int n_in,
                              void* d_out, int out_size, void* d_ws, size_t ws_size,
                              hipStream_t stream)
{
    const float* X      = (const float*)d_in[0];
    const float* m0     = (const float*)d_in[1];
    const float* H0     = (const float*)d_in[2];
    const float* C0     = (const float*)d_in[3];
    const float* R0     = (const float*)d_in[4];
    const float* A0     = (const float*)d_in[5];
    const float* W_prep = (const float*)d_in[6];
    const float* b_prep = (const float*)d_in[7];
    const float* W_lstm = (const float*)d_in[8];
    const float* b_lstm = (const float*)d_in[9];
    const float* W_r    = (const float*)d_in[10];
    const float* b_r    = (const float*)d_in[11];
    const float* W_w    = (const float*)d_in[12];
    const float* b_w    = (const float*)d_in[13];
    const float* W_ou   = (const float*)d_in[14];
    const float* b_ou   = (const float*)d_in[15];
    float* ws  = (float*)d_ws;
    float* out = (float*)d_out;

    unsigned short* XHB   = (unsigned short*)(ws + OFF_XHB);
    unsigned short* HCAT  = (unsigned short*)(ws + OFF_HCAT);
    unsigned short* W0T   = (unsigned short*)(ws + OFF_W0T);
    unsigned short* W1T   = (unsigned short*)(ws + OFF_W1T);
    unsigned short* WRWT  = (unsigned short*)(ws + OFF_WRWT);
    unsigned short* WCOMB = (unsigned short*)(ws + OFF_WCOMB);
    unsigned short* WR2T  = (unsigned short*)(ws + OFF_WR2T);
    unsigned short* M0B   = (unsigned short*)(ws + OFF_M0B);
    unsigned short* KBUF  = (unsigned short*)(ws + OFF_KBUF);

    // ---- constants & weight conversions ----
    k_const_a<<<1, 256, 0, stream>>>(R0, W_prep, b_prep, A0, m0, b_r, b_w, ws);
    k_const_b<<<16, 256, 0, stream>>>(H0, W_lstm, b_lstm, ws);
    k_cvt8<<<1024, 256, 0, stream>>>(X, 512, XHB, 1024, 64, (size_t)Bn * 64);
    k_cvt8<<<32, 256, 0, stream>>>(m0, 128, M0B, 128, 16, (size_t)256 * 16);
    dim3 tb(32, 8);
    k_cvtT<<<dim3(64, 16), tb, 0, stream>>>(W_lstm, 512, 2048, 2048, W0T, 512, 1);
    k_cvtT<<<dim3(64, 32), tb, 0, stream>>>(W_lstm + (size_t)1536 * 2048, 1024, 2048, 2048, W1T, 1024, 1);
    k_cvtT<<<dim3(9, 16),  tb, 0, stream>>>(W_r, 512, 268, 268, WRWT, 512, 0);
    k_cvtT<<<dim3(25, 16), tb, 0, stream>>>(W_w, 512, 780, 780, WRWT + (size_t)268 * 512, 512, 0);
    k_cvtT<<<dim3(16, 16), tb, 0, stream>>>(W_ou, 512, 512, 512, WCOMB, 1024, 0);
    k_cvtT<<<dim3(16, 8),  tb, 0, stream>>>(W_ou + (size_t)512 * 512, 256, 512, 512, WR2T, 256, 0);

    // P_i = (W_ou read-slice)^T @ m0^T folded into combined output weight
    gemm_bf16<<<dim3(4, 2), 256, 0, stream>>>(
        WR2T, 256, M0B, 128, nullptr, nullptr, WCOMB + 512, 1024, 256, 128, 2);
    gemm_bf16<<<dim3(4, 2), 256, 0, stream>>>(
        WR2T + 128, 256, M0B, 128, nullptr, nullptr, WCOMB + 768, 1024, 256, 128, 2);

    // ---- LSTM (fused gates) ----
    gemm_lstm<<<dim3(16, 16), 256, 0, stream>>>(
        XHB, 1024, W0T, 512, ws + OFF_Z0C, C0, XHB + 512, 1024, 512, 0);
    gemm_lstm<<<dim3(16, 16), 256, 0, stream>>>(
        XHB, 1024, W1T, 1024, ws + OFF_Z1C, C0 + 512, HCAT, 1024, 1024, 1);

    // ---- heads ----
    gemm_bf16<<<dim3(16, 9), 256, 0, stream>>>(
        HCAT, 1024, WRWT, 512, ws + OFF_BIASH, ws + OFF_HEADS, nullptr, 1048, 1048, 512, 0);

    k_kprep<<<dim3(Bn, 4), 128, 0, stream>>>(
        ws + OFF_HEADS, KBUF, ws + OFF_KNORM, ws + OFF_ERA, ws + OFF_ADD);

    // inner[b,i,n] = k . m0[n]
    gemm_bf16<<<dim3(64, 2), 256, 0, stream>>>(
        KBUF, 128, M0B, 128, nullptr, ws + OFF_KMAT, nullptr, 256, 256, 128, 0);

    k_addr<<<dim3(Bn, 4), 256, 0, stream>>>(
        ws + OFF_HEADS, ws + OFF_KMAT, ws + OFF_KNORM, ws + OFF_MNORM,
        ws + OFF_APREV, ws + OFF_AT, HCAT);

    // ---- y = clip([h|A0|A1] @ WCOMB + b_ou) ----
    gemm_bf16<<<dim3(16, 4), 256, 0, stream>>>(
        HCAT, 1024, WCOMB, 1024, b_ou, out, nullptr, 512, 512, 1024, 1);

    // ---- m_t ----
    k_mem<<<2048, 256, 0, stream>>>(
        m0, ws + OFF_AT, ws + OFF_ERA, ws + OFF_ADD, out + (size_t)Bn * Un);
}

// Round 4
// 291.343 us; speedup vs baseline: 1.6344x; 1.6344x over previous
//
#include <hip/hip_runtime.h>
#include <math.h>

static constexpr int Bn = 2048;   // batch
static constexpr int Nn = 256;    // memory locations
static constexpr int Mn = 128;    // memory width
static constexpr int Un = 512;    // units

// Workspace layout (f32 offsets)
static constexpr size_t OFF_H0C   = 0;        // 512
static constexpr size_t OFF_Z0C   = 512;      // 2048 (gate-permuted)
static constexpr size_t OFF_Z1C   = 2560;     // 2048 (gate-permuted)
static constexpr size_t OFF_MNORM = 4608;     // 256
static constexpr size_t OFF_APREV = 4864;     // 1024
static constexpr size_t OFF_BIASH = 5888;     // 1152
static constexpr size_t OFF_KNORM = 7040;     // 8192
static constexpr size_t OFF_KMAT  = 16384;                          // f32 [8192][256]
static constexpr size_t OFF_HEADS = OFF_KMAT + (size_t)8192 * 256;  // f32 [2048][1048]
static constexpr size_t OFF_AT    = OFF_HEADS + (size_t)2048 * 1048;// f32 [2][2048][256]
static constexpr size_t OFF_ERA   = OFF_AT + (size_t)2 * 2048 * 256;// f32 [2048][2][128]
static constexpr size_t OFF_ADD   = OFF_ERA + (size_t)2048 * 256;
static constexpr size_t OFF_XHB   = OFF_ADD + (size_t)2048 * 256;   // bf16 [2048][1024]
static constexpr size_t OFF_HCAT  = OFF_XHB + 524288;               // bf16 [2048][1024]
static constexpr size_t OFF_W0T   = OFF_HCAT + 524288;              // bf16 [2048][512]
static constexpr size_t OFF_W1T   = OFF_W0T + 524288;               // bf16 [2048][1024]
static constexpr size_t OFF_WRWT  = OFF_W1T + 1048576;              // bf16 [1152][512]
static constexpr size_t OFF_WCOMB = OFF_WRWT + 294912;              // bf16 [512][1024]
static constexpr size_t OFF_WR2T  = OFF_WCOMB + 262144;             // bf16 [512][256]
static constexpr size_t OFF_M0B   = OFF_WR2T + 65536;               // bf16 [256][128]
static constexpr size_t OFF_KBUF  = OFF_M0B + 16384;                // bf16 [8192][128]
static constexpr size_t OFF_ZPART = OFF_KBUF + 524288;              // f32 [2][8][2048]

#define DEV __device__ __forceinline__

typedef __attribute__((ext_vector_type(8))) short bf16x8;
typedef __attribute__((ext_vector_type(4))) float f32x4;
typedef __attribute__((ext_vector_type(8))) unsigned short ushort8;
typedef unsigned int u32;

DEV float sigf(float x) { return 1.0f / (1.0f + expf(-x)); }
DEV float softplusf(float x) { return x > 20.0f ? x : log1pf(expf(x)); }
DEV unsigned short f2bf(float f) {   // RNE float->bf16
    unsigned u = __float_as_uint(f);
    u = (u + 0x7FFFu + ((u >> 16) & 1u)) >> 16;
    return (unsigned short)u;
}
DEV void gload16(const unsigned short* g, unsigned short* l) {
    __builtin_amdgcn_global_load_lds(
        (const __attribute__((address_space(1))) u32*)g,
        (__attribute__((address_space(3))) u32*)l, 16, 0, 0);
}

DEV float blk_reduce_max(float v, float* red) {
    int tid = threadIdx.x;
    red[tid] = v; __syncthreads();
    for (int s = (int)blockDim.x >> 1; s > 0; s >>= 1) {
        if (tid < s) red[tid] = fmaxf(red[tid], red[tid + s]);
        __syncthreads();
    }
    float r = red[0]; __syncthreads();
    return r;
}
DEV float blk_reduce_sum(float v, float* red) {
    int tid = threadIdx.x;
    red[tid] = v; __syncthreads();
    for (int s = (int)blockDim.x >> 1; s > 0; s >>= 1) {
        if (tid < s) red[tid] += red[tid + s];
        __syncthreads();
    }
    float r = red[0]; __syncthreads();
    return r;
}

// ===========================================================================
// Shared GEMM machinery: 128x128 tile, 4 waves (2x2), BK=64, double-buffered
// LDS via global_load_lds (16B), XOR-swizzled via pre-swizzled source.
// A bf16 [M][lda], Wt bf16 [N][ldw] (weights pre-transposed).
// ===========================================================================
#define GEMM_STAGE(buf, k0)                                                     \
    {                                                                           \
        _Pragma("unroll")                                                       \
        for (int q = 0; q < 4; ++q) {                                           \
            gload16(A  + (size_t)(row0 + q * 32 + (tid >> 3)) * lda + (k0) + ke,\
                    &As[buf][q * 2048 + tid * 8]);                              \
            gload16(Wt + (size_t)(col0 + q * 32 + (tid >> 3)) * ldw + (k0) + ke,\
                    &Ws[buf][q * 2048 + tid * 8]);                              \
        }                                                                       \
    }

#define GEMM_PROLOG                                                             \
    __shared__ __align__(16) unsigned short As[2][128 * 64];                    \
    __shared__ __align__(16) unsigned short Ws[2][128 * 64];                    \
    const int tid  = threadIdx.x;                                               \
    const int lane = tid & 63;                                                  \
    const int wave = tid >> 6;                                                  \
    const int wr = wave >> 1, wc = wave & 1;                                    \
    const int row0 = blockIdx.x * 128;                                          \
    const int col0 = blockIdx.y * 128;                                          \
    const int ke = ((tid & 7) * 8) ^ (((tid >> 3) & 7) << 3);                   \
    const int frow = lane & 15;                                                 \
    const int fko  = (lane >> 4) * 8;                                           \
    const int fxm  = (frow & 7) << 3;                                           \
    f32x4 acc[4][4];                                                            \
    _Pragma("unroll")                                                           \
    for (int i = 0; i < 4; ++i)                                                 \
        _Pragma("unroll")                                                       \
        for (int j = 0; j < 4; ++j) acc[i][j] = (f32x4){0.f, 0.f, 0.f, 0.f};

#define GEMM_MAINLOOP(Kr)                                                       \
    {                                                                           \
        const int nt = (Kr) >> 6;                                               \
        int cur = 0;                                                            \
        GEMM_STAGE(0, 0);                                                       \
        for (int t = 0; t < nt; ++t) {                                          \
            __syncthreads();                                                    \
            if (t + 1 < nt) GEMM_STAGE(cur ^ 1, (t + 1) * 64);                  \
            const unsigned short* Ab = As[cur];                                 \
            const unsigned short* Wb = Ws[cur];                                 \
            bf16x8 af[2][4], wf[2][4];                                          \
            _Pragma("unroll")                                                   \
            for (int kk = 0; kk < 2; ++kk) {                                    \
                _Pragma("unroll")                                               \
                for (int i = 0; i < 4; ++i) {                                   \
                    int fr = wr * 64 + i * 16 + frow;                           \
                    af[kk][i] = *(const bf16x8*)&Ab[fr * 64 + ((kk * 32 + fko) ^ fxm)]; \
                }                                                               \
                _Pragma("unroll")                                               \
                for (int j = 0; j < 4; ++j) {                                   \
                    int fr = wc * 64 + j * 16 + frow;                           \
                    wf[kk][j] = *(const bf16x8*)&Wb[fr * 64 + ((kk * 32 + fko) ^ fxm)]; \
                }                                                               \
            }                                                                   \
            _Pragma("unroll")                                                   \
            for (int kk = 0; kk < 2; ++kk)                                      \
                _Pragma("unroll")                                               \
                for (int i = 0; i < 4; ++i)                                     \
                    _Pragma("unroll")                                           \
                    for (int j = 0; j < 4; ++j)                                 \
                        acc[i][j] = __builtin_amdgcn_mfma_f32_16x16x32_bf16(    \
                            af[kk][i], wf[kk][j], acc[i][j], 0, 0, 0);          \
            cur ^= 1;                                                           \
        }                                                                       \
    }

// Generic GEMM. epi: 0=f32 out(+bias), 1=f32+bias+clip, 2=bf16 out (Cb)
__global__ __launch_bounds__(256) void gemm_bf16(
    const unsigned short* __restrict__ A, int lda,
    const unsigned short* __restrict__ Wt, int ldw,
    const float* __restrict__ bias,
    float* __restrict__ C, unsigned short* __restrict__ Cb, int ldc,
    int Nr, int Kr, int epi)
{
    GEMM_PROLOG
    GEMM_MAINLOOP(Kr)
    #pragma unroll
    for (int i = 0; i < 4; ++i) {
        int m0r = row0 + wr * 64 + i * 16 + (lane >> 4) * 4;
        #pragma unroll
        for (int j = 0; j < 4; ++j) {
            int n = col0 + wc * 64 + j * 16 + (lane & 15);
            if (n >= Nr) continue;
            float bv = bias ? bias[n] : 0.f;
            #pragma unroll
            for (int r = 0; r < 4; ++r) {
                float v = acc[i][j][r] + bv;
                if (epi == 1) v = fminf(fmaxf(v, -20.f), 20.f);
                if (epi == 2) Cb[(size_t)(m0r + r) * ldc + n] = f2bf(v);
                else          C [(size_t)(m0r + r) * ldc + n] = v;
            }
        }
    }
}

// LSTM GEMM: W columns gate-permuted (c = 64q+16g+uu -> orig col g*512+q*16+uu).
__global__ __launch_bounds__(256) void gemm_lstm(
    const unsigned short* __restrict__ A, int lda,
    const unsigned short* __restrict__ Wt, int ldw,
    const float* __restrict__ biasP, const float* __restrict__ c0,
    unsigned short* __restrict__ hout, int ldh, int Kr, int doclip)
{
    GEMM_PROLOG
    GEMM_MAINLOOP(Kr)
    const int uu = lane & 15;
    const int uq = ((col0 >> 6) + wc) * 16 + uu;     // unit index
    const float c0v = c0[uq];
    const int cb = col0 + wc * 64 + uu;
    const float bi = biasP[cb], bfv = biasP[cb + 16],
                bgv = biasP[cb + 32], bov = biasP[cb + 48];
    #pragma unroll
    for (int i = 0; i < 4; ++i) {
        int rbase = row0 + wr * 64 + i * 16 + (lane >> 4) * 4;
        #pragma unroll
        for (int r = 0; r < 4; ++r) {
            float ig = acc[i][0][r] + bi;
            float fg = acc[i][1][r] + bfv;
            float gg = acc[i][2][r] + bgv;
            float og = acc[i][3][r] + bov;
            float c = sigf(fg) * c0v + sigf(ig) * tanhf(gg);
            float h = sigf(og) * tanhf(c);
            if (doclip) h = fminf(fmaxf(h, -20.f), 20.f);
            hout[(size_t)(rbase + r) * ldh + uq] = f2bf(h);
        }
    }
}

// ===========================================================================
// f32 -> bf16 copy (8-wide)
__global__ void k_cvt8(const float* __restrict__ src, int lds,
                       unsigned short* __restrict__ dst, int ldd,
                       int c8, size_t total)
{
    for (size_t idx = (size_t)blockIdx.x * blockDim.x + threadIdx.x;
         idx < total; idx += (size_t)gridDim.x * blockDim.x) {
        size_t r = idx / c8, c = (idx % c8) * 8;
        const float* s = src + r * lds + c;
        float4 v0 = *(const float4*)s;
        float4 v1 = *(const float4*)(s + 4);
        ushort8 o;
        o[0] = f2bf(v0.x); o[1] = f2bf(v0.y); o[2] = f2bf(v0.z); o[3] = f2bf(v0.w);
        o[4] = f2bf(v1.x); o[5] = f2bf(v1.y); o[6] = f2bf(v1.z); o[7] = f2bf(v1.w);
        *(ushort8*)(dst + r * ldd + c) = o;
    }
}

// f32 -> bf16 transpose: dst[c][r] = src[r][map(c)]; mode 1 = LSTM gate permute
__global__ void k_cvtT(const float* __restrict__ src, int R, int C, int lds,
                       unsigned short* __restrict__ dst, int ldd, int mode)
{
    __shared__ float t[32][33];
    const int bx = blockIdx.x * 32;   // over C (dst rows)
    const int by = blockIdx.y * 32;   // over R
    const int x = threadIdx.x;
    for (int y = threadIdx.y; y < 32; y += 8) {
        int r = by + y, c = bx + x;
        int scol = c;
        if (mode == 1) scol = ((c >> 4) & 3) * 512 + (c >> 6) * 16 + (c & 15);
        t[y][x] = (r < R && c < C) ? src[(size_t)r * lds + scol] : 0.f;
    }
    __syncthreads();
    for (int y = threadIdx.y; y < 32; y += 8) {
        int c = bx + y, r = by + x;
        if (c < C && r < R) dst[(size_t)c * ldd + r] = f2bf(t[x][y]);
    }
}

// Batch-invariant constants
__global__ __launch_bounds__(256) void k_const_a(
    const float* __restrict__ R0, const float* __restrict__ W_prep,
    const float* __restrict__ b_prep, const float* __restrict__ A0,
    const float* __restrict__ m0, const float* __restrict__ b_r,
    const float* __restrict__ b_w, float* __restrict__ ws)
{
    __shared__ float r0s[256];
    __shared__ float red[256];
    const int tid = threadIdx.x;
    r0s[tid] = tanhf(R0[tid]);
    __syncthreads();
    #pragma unroll
    for (int uu = 0; uu < 2; ++uu) {
        int u = tid + uu * 256;
        float acc = b_prep[u];
        for (int k = 0; k < 256; ++k)
            acc = fmaf(r0s[k], W_prep[(size_t)k * 512 + u], acc);
        ws[OFF_H0C + u] = acc;
    }
    for (int i = 0; i < 4; ++i) {
        float v = A0[i * 256 + tid];
        float mx = blk_reduce_max(v, red);
        float e = expf(v - mx);
        float s = blk_reduce_sum(e, red);
        ws[OFF_APREV + i * 256 + tid] = e / s;
    }
    float acc = 0.f;
    for (int m = 0; m < 128; ++m) {
        float t = m0[(size_t)tid * 128 + m];
        acc = fmaf(t, t, acc);
    }
    ws[OFF_MNORM + tid] = sqrtf(acc);
    for (int j = tid; j < 1152; j += 256)
        ws[OFF_BIASH + j] = (j < 268) ? b_r[j] : (j < 1048 ? b_w[j - 268] : 0.f);
}

// Split-K partials for constant LSTM gate contributions. Coalesced reads of
// W_lstm (orig column order); permutation applied at the reduce's write.
__global__ __launch_bounds__(256) void k_zc_part(
    const float* __restrict__ H0, const float* __restrict__ W_lstm,
    const float* __restrict__ ws, float* __restrict__ part)
{
    const int j  = blockIdx.x * 256 + threadIdx.x;   // orig col 0..2047
    const int up = blockIdx.y;                       // 0..7
    const int z  = blockIdx.z;                       // layer
    float acc = 0.f;
    if (z == 0) {
        const int u0 = up * 128;
        #pragma unroll 4
        for (int u = u0; u < u0 + 128; ++u) {
            float coef = (u < 512) ? ws[OFF_H0C + u] : H0[u - 512];
            acc = fmaf(coef, W_lstm[(size_t)(512 + u) * 2048 + j], acc);
        }
    } else {
        const int u0 = up * 64;
        const float* W1 = W_lstm + (size_t)1536 * 2048;
        #pragma unroll 4
        for (int u = u0; u < u0 + 64; ++u)
            acc = fmaf(H0[512 + u], W1[(size_t)(1024 + u) * 2048 + j], acc);
    }
    part[((size_t)z * 8 + up) * 2048 + j] = acc;
}

// Reduce 8 partials + bias, write gate-permuted
__global__ void k_zc_red(const float* __restrict__ part,
                         const float* __restrict__ b_lstm,
                         float* __restrict__ ws)
{
    int idx = blockIdx.x * 256 + threadIdx.x;        // 0..4095
    int z = idx >> 11, j = idx & 2047;
    float acc = b_lstm[z * 2048 + j];
    #pragma unroll
    for (int p = 0; p < 8; ++p)
        acc += part[((size_t)z * 8 + p) * 2048 + j];
    int g = j >> 9, q = (j >> 4) & 31, uu = j & 15;
    int c = q * 64 + g * 16 + uu;
    ws[(z == 0 ? OFF_Z0C : OFF_Z1C) + c] = acc;
}

// Per-(b,head): k = tanh(hd[:128]) -> KBUF bf16, knorm; write heads: erase/add
__global__ __launch_bounds__(128) void k_kprep(
    const float* __restrict__ heads, unsigned short* __restrict__ kbuf,
    float* __restrict__ knorm, float* __restrict__ era, float* __restrict__ addv)
{
    __shared__ float red[128];
    const int b = blockIdx.x, i = blockIdx.y, tid = threadIdx.x;
    const int cb = (i < 2) ? i * 134 : 268 + (i - 2) * 390;
    const float* hd = heads + (size_t)b * 1048 + cb;
    float k = tanhf(hd[tid]);
    kbuf[((size_t)b * 4 + i) * 128 + tid] = f2bf(k);
    float sq = blk_reduce_sum(k * k, red);
    if (tid == 0) knorm[b * 4 + i] = sqrtf(sq);
    if (i >= 2) {
        int ii = i - 2;
        era [((size_t)b * 2 + ii) * 128 + tid] = sigf(hd[134 + tid]);
        addv[((size_t)b * 2 + ii) * 128 + tid] = tanhf(hd[262 + tid]);
    }
}

// Addressing: read heads -> A (bf16 into HCAT); write heads -> AT f32
__global__ __launch_bounds__(256) void k_addr(
    const float* __restrict__ heads, const float* __restrict__ kmat,
    const float* __restrict__ knorm, const float* __restrict__ mnorm,
    const float* __restrict__ aprev, float* __restrict__ at,
    unsigned short* __restrict__ hcat)
{
    __shared__ float red[256];
    __shared__ float wgs[256];
    __shared__ float sc[6];
    const int b = blockIdx.x, i = blockIdx.y, tid = threadIdx.x;
    const int cb = (i < 2) ? i * 134 : 268 + (i - 2) * 390;
    const float* hd = heads + (size_t)b * 1048 + cb;
    if (tid == 0) {
        sc[0] = softplusf(hd[128]);
        sc[1] = sigf(hd[129]);
        float v0 = hd[130], v1 = hd[131], v2 = hd[132];
        float mx = fmaxf(v0, fmaxf(v1, v2));
        float e0 = expf(v0 - mx), e1 = expf(v1 - mx), e2 = expf(v2 - mx);
        float ssum = e0 + e1 + e2;
        sc[2] = e0 / ssum; sc[3] = e1 / ssum; sc[4] = e2 / ssum;
        sc[5] = softplusf(hd[133]);
    }
    __syncthreads();
    const float beta = sc[0], g = sc[1], s0 = sc[2], s1 = sc[3], s2 = sc[4],
                gamma = sc[5];
    float inner = kmat[((size_t)b * 4 + i) * 256 + tid];
    float kn = knorm[b * 4 + i];
    float K = inner / (kn * mnorm[tid] + 1e-8f);
    float x = beta * K;
    float mx = blk_reduce_max(x, red);
    float e = expf(x - mx);
    float se = blk_reduce_sum(e, red);
    float wc = e / se;
    float wg = g * wc + (1.f - g) * aprev[i * 256 + tid];
    wgs[tid] = wg;
    __syncthreads();
    float wconv = s0 * wg + s1 * wgs[(tid + 255) & 255] + s2 * wgs[(tid + 1) & 255];
    float wsh = powf(wconv, gamma);
    float ssum = blk_reduce_sum(wsh, red);
    float w = wsh / ssum;
    if (i < 2) hcat[(size_t)b * 1024 + 512 + i * 256 + tid] = f2bf(w);
    else       at[((size_t)(i - 2) * Bn + b) * 256 + tid] = w;
}

// m_t streaming update
__global__ void k_mem(const float* __restrict__ m0, const float* __restrict__ at,
                      const float* __restrict__ era, const float* __restrict__ addv,
                      float* __restrict__ outm)
{
    const size_t total = (size_t)Bn * Nn * (Mn / 4);
    for (size_t idx = (size_t)blockIdx.x * blockDim.x + threadIdx.x;
         idx < total; idx += (size_t)gridDim.x * blockDim.x) {
        int mq = (int)(idx & 31);
        int n  = (int)((idx >> 5) & 255);
        int b  = (int)(idx >> 13);
        float4 t  = reinterpret_cast<const float4*>(m0)[n * 32 + mq];
        float w0 = at[((size_t)0 * Bn + b) * 256 + n];
        float w1 = at[((size_t)1 * Bn + b) * 256 + n];
        float4 e0 = reinterpret_cast<const float4*>(era) [((size_t)b * 2 + 0) * 32 + mq];
        float4 a0 = reinterpret_cast<const float4*>(addv)[((size_t)b * 2 + 0) * 32 + mq];
        float4 e1 = reinterpret_cast<const float4*>(era) [((size_t)b * 2 + 1) * 32 + mq];
        float4 a1 = reinterpret_cast<const float4*>(addv)[((size_t)b * 2 + 1) * 32 + mq];
#define UPD(c) { t.c = t.c * (1.f - w0 * e0.c) + w0 * a0.c; \
                 t.c = t.c * (1.f - w1 * e1.c) + w1 * a1.c; }
        UPD(x) UPD(y) UPD(z) UPD(w)
#undef UPD
        reinterpret_cast<float4*>(outm)[idx] = t;
    }
}

extern "C" void kernel_launch(void* const* d_in, const int* in_sizes, int n_in,
                              void* d_out, int out_size, void* d_ws, size_t ws_size,
                              hipStream_t stream)
{
    const float* X      = (const float*)d_in[0];
    const float* m0     = (const float*)d_in[1];
    const float* H0     = (const float*)d_in[2];
    const float* C0     = (const float*)d_in[3];
    const float* R0     = (const float*)d_in[4];
    const float* A0     = (const float*)d_in[5];
    const float* W_prep = (const float*)d_in[6];
    const float* b_prep = (const float*)d_in[7];
    const float* W_lstm = (const float*)d_in[8];
    const float* b_lstm = (const float*)d_in[9];
    const float* W_r    = (const float*)d_in[10];
    const float* b_r    = (const float*)d_in[11];
    const float* W_w    = (const float*)d_in[12];
    const float* b_w    = (const float*)d_in[13];
    const float* W_ou   = (const float*)d_in[14];
    const float* b_ou   = (const float*)d_in[15];
    float* ws  = (float*)d_ws;
    float* out = (float*)d_out;

    unsigned short* XHB   = (unsigned short*)(ws + OFF_XHB);
    unsigned short* HCAT  = (unsigned short*)(ws + OFF_HCAT);
    unsigned short* W0T   = (unsigned short*)(ws + OFF_W0T);
    unsigned short* W1T   = (unsigned short*)(ws + OFF_W1T);
    unsigned short* WRWT  = (unsigned short*)(ws + OFF_WRWT);
    unsigned short* WCOMB = (unsigned short*)(ws + OFF_WCOMB);
    unsigned short* WR2T  = (unsigned short*)(ws + OFF_WR2T);
    unsigned short* M0B   = (unsigned short*)(ws + OFF_M0B);
    unsigned short* KBUF  = (unsigned short*)(ws + OFF_KBUF);

    // ---- constants & weight conversions ----
    k_const_a<<<1, 256, 0, stream>>>(R0, W_prep, b_prep, A0, m0, b_r, b_w, ws);
    k_zc_part<<<dim3(8, 8, 2), 256, 0, stream>>>(H0, W_lstm, ws, ws + OFF_ZPART);
    k_zc_red<<<16, 256, 0, stream>>>(ws + OFF_ZPART, b_lstm, ws);
    k_cvt8<<<1024, 256, 0, stream>>>(X, 512, XHB, 1024, 64, (size_t)Bn * 64);
    k_cvt8<<<32, 256, 0, stream>>>(m0, 128, M0B, 128, 16, (size_t)256 * 16);
    dim3 tb(32, 8);
    k_cvtT<<<dim3(64, 16), tb, 0, stream>>>(W_lstm, 512, 2048, 2048, W0T, 512, 1);
    k_cvtT<<<dim3(64, 32), tb, 0, stream>>>(W_lstm + (size_t)1536 * 2048, 1024, 2048, 2048, W1T, 1024, 1);
    k_cvtT<<<dim3(9, 16),  tb, 0, stream>>>(W_r, 512, 268, 268, WRWT, 512, 0);
    k_cvtT<<<dim3(25, 16), tb, 0, stream>>>(W_w, 512, 780, 780, WRWT + (size_t)268 * 512, 512, 0);
    k_cvtT<<<dim3(16, 16), tb, 0, stream>>>(W_ou, 512, 512, 512, WCOMB, 1024, 0);
    k_cvtT<<<dim3(16, 8),  tb, 0, stream>>>(W_ou + (size_t)512 * 512, 256, 512, 512, WR2T, 256, 0);

    // P_i = (W_ou read-slice)^T @ m0^T folded into combined output weight
    gemm_bf16<<<dim3(4, 2), 256, 0, stream>>>(
        WR2T, 256, M0B, 128, nullptr, nullptr, WCOMB + 512, 1024, 256, 128, 2);
    gemm_bf16<<<dim3(4, 2), 256, 0, stream>>>(
        WR2T + 128, 256, M0B, 128, nullptr, nullptr, WCOMB + 768, 1024, 256, 128, 2);

    // ---- LSTM (fused gates) ----
    gemm_lstm<<<dim3(16, 16), 256, 0, stream>>>(
        XHB, 1024, W0T, 512, ws + OFF_Z0C, C0, XHB + 512, 1024, 512, 0);
    gemm_lstm<<<dim3(16, 16), 256, 0, stream>>>(
        XHB, 1024, W1T, 1024, ws + OFF_Z1C, C0 + 512, HCAT, 1024, 1024, 1);

    // ---- heads ----
    gemm_bf16<<<dim3(16, 9), 256, 0, stream>>>(
        HCAT, 1024, WRWT, 512, ws + OFF_BIASH, ws + OFF_HEADS, nullptr, 1048, 1048, 512, 0);

    k_kprep<<<dim3(Bn, 4), 128, 0, stream>>>(
        ws + OFF_HEADS, KBUF, ws + OFF_KNORM, ws + OFF_ERA, ws + OFF_ADD);

    // inner[b,i,n] = k . m0[n]
    gemm_bf16<<<dim3(64, 2), 256, 0, stream>>>(
        KBUF, 128, M0B, 128, nullptr, ws + OFF_KMAT, nullptr, 256, 256, 128, 0);

    k_addr<<<dim3(Bn, 4), 256, 0, stream>>>(
        ws + OFF_HEADS, ws + OFF_KMAT, ws + OFF_KNORM, ws + OFF_MNORM,
        ws + OFF_APREV, ws + OFF_AT, HCAT);

    // ---- y = clip([h|A0|A1] @ WCOMB + b_ou) ----
    gemm_bf16<<<dim3(16, 4), 256, 0, stream>>>(
        HCAT, 1024, WCOMB, 1024, b_ou, out, nullptr, 512, 512, 1024, 1);

    // ---- m_t ----
    k_mem<<<2048, 256, 0, stream>>>(
        m0, ws + OFF_AT, ws + OFF_ERA, ws + OFF_ADD, out + (size_t)Bn * Un);
}

// Round 6
// 210.378 us; speedup vs baseline: 2.2633x; 1.3849x over previous
//
#include <hip/hip_runtime.h>
#include <math.h>

static constexpr int Bn = 2048;   // batch
static constexpr int Nn = 256;    // memory locations
static constexpr int Mn = 128;    // memory width
static constexpr int Un = 512;    // units

// Workspace layout (f32 offsets)
static constexpr size_t OFF_Z0C   = 512;      // 2048 (gate-permuted)
static constexpr size_t OFF_Z1C   = 2560;     // 2048 (gate-permuted)
static constexpr size_t OFF_MNORM = 4608;     // 256
static constexpr size_t OFF_APREV = 4864;     // 1024
static constexpr size_t OFF_BIASH = 5888;     // 1152
static constexpr size_t OFF_KNORM = 7040;     // 8192
static constexpr size_t OFF_KMAT  = 16384;                          // f32 [8192][256]
static constexpr size_t OFF_HEADS = OFF_KMAT + (size_t)8192 * 256;  // f32 [2048][1048]
static constexpr size_t OFF_AT    = OFF_HEADS + (size_t)2048 * 1048;// f32 [2][2048][256]
static constexpr size_t OFF_ERA   = OFF_AT + (size_t)2 * 2048 * 256;// f32 [2048][2][128]
static constexpr size_t OFF_ADD   = OFF_ERA + (size_t)2048 * 256;
static constexpr size_t OFF_XHB   = OFF_ADD + (size_t)2048 * 256;   // bf16 [2048][1024]
static constexpr size_t OFF_HCAT  = OFF_XHB + 524288;               // bf16 [2048][1024]
static constexpr size_t OFF_W0T   = OFF_HCAT + 524288;              // bf16 [2048][512]
static constexpr size_t OFF_W1T   = OFF_W0T + 524288;               // bf16 [2048][1024]
static constexpr size_t OFF_WRWT  = OFF_W1T + 1048576;              // bf16 [1152][512]
static constexpr size_t OFF_WCOMB = OFF_WRWT + 294912;              // bf16 [512][1024]
static constexpr size_t OFF_WR2T  = OFF_WCOMB + 262144;             // bf16 [512][256]
static constexpr size_t OFF_M0B   = OFF_WR2T + 65536;               // bf16 [256][128]
static constexpr size_t OFF_KBUF  = OFF_M0B + 16384;                // bf16 [8192][128]
static constexpr size_t OFF_ZPART = OFF_KBUF + 524288;              // f32 [2][8][2048]

// k_prep block-range dispatch table
static constexpr int S_X0  = 0;            // cvt8 X        (512)
static constexpr int S_M0  = 512;          // cvt8 m0       (16)
static constexpr int S_W0  = 528;          // cvtT W0 gate  (64x16)
static constexpr int S_W1  = 1552;         // cvtT W1 gate  (64x32)
static constexpr int S_WR  = 3600;         // cvtT W_r      (9x16)
static constexpr int S_WW  = 3744;         // cvtT W_w      (25x16)
static constexpr int S_WOU = 4144;         // cvtT W_ou h   (16x16)
static constexpr int S_WR2 = 4400;         // cvtT W_ou r   (16x8)
static constexpr int S_CA  = 4528;         // const-a       (1)
static constexpr int S_ZC  = 4529;         // zc partials   (128)
static constexpr int S_END = 4657;

#define DEV __device__ __forceinline__

typedef __attribute__((ext_vector_type(8))) short bf16x8;
typedef __attribute__((ext_vector_type(4))) float f32x4;
typedef __attribute__((ext_vector_type(8))) unsigned short ushort8;
typedef unsigned int u32;

DEV float sigf(float x) { return 1.0f / (1.0f + expf(-x)); }
DEV float softplusf(float x) { return x > 20.0f ? x : log1pf(expf(x)); }
DEV unsigned short f2bf(float f) {   // RNE float->bf16
    unsigned u = __float_as_uint(f);
    u = (u + 0x7FFFu + ((u >> 16) & 1u)) >> 16;
    return (unsigned short)u;
}
DEV void gload16(const unsigned short* g, unsigned short* l) {
    __builtin_amdgcn_global_load_lds(
        (const __attribute__((address_space(1))) u32*)g,
        (__attribute__((address_space(3))) u32*)l, 16, 0, 0);
}

DEV float blk_reduce_max(float v, float* red) {
    int tid = threadIdx.x;
    red[tid] = v; __syncthreads();
    for (int s = (int)blockDim.x >> 1; s > 0; s >>= 1) {
        if (tid < s) red[tid] = fmaxf(red[tid], red[tid + s]);
        __syncthreads();
    }
    float r = red[0]; __syncthreads();
    return r;
}
DEV float blk_reduce_sum(float v, float* red) {
    int tid = threadIdx.x;
    red[tid] = v; __syncthreads();
    for (int s = (int)blockDim.x >> 1; s > 0; s >>= 1) {
        if (tid < s) red[tid] += red[tid + s];
        __syncthreads();
    }
    float r = red[0]; __syncthreads();
    return r;
}

// ===========================================================================
// GEMM: 64x128 tile (M x N), 4 waves (2x2), BK=64, double-buffered LDS via
// global_load_lds (16B), XOR-swizzled via pre-swizzled source k-offset.
// 48KB LDS -> 3 blocks/CU. A bf16 [M][lda], Wt bf16 [N][ldw] (transposed).
// ===========================================================================
#define GEMM_STAGE(buf, k0)                                                     \
    {                                                                           \
        _Pragma("unroll")                                                       \
        for (int q = 0; q < 2; ++q)                                             \
            gload16(A  + (size_t)(row0 + q * 32 + (tid >> 3)) * lda + (k0) + ke,\
                    &As[buf][q * 2048 + tid * 8]);                              \
        _Pragma("unroll")                                                       \
        for (int q = 0; q < 4; ++q)                                             \
            gload16(Wt + (size_t)(col0 + q * 32 + (tid >> 3)) * ldw + (k0) + ke,\
                    &Ws[buf][q * 2048 + tid * 8]);                              \
    }

#define GEMM_PROLOG                                                             \
    __shared__ __align__(16) unsigned short As[2][64 * 64];                     \
    __shared__ __align__(16) unsigned short Ws[2][128 * 64];                    \
    const int tid  = threadIdx.x;                                               \
    const int lane = tid & 63;                                                  \
    const int wave = tid >> 6;                                                  \
    const int wr = wave >> 1, wc = wave & 1;                                    \
    const int row0 = blockIdx.x * 64;                                           \
    const int col0 = blockIdx.y * 128;                                          \
    const int ke = ((tid & 7) * 8) ^ (((tid >> 3) & 7) << 3);                   \
    const int frow = lane & 15;                                                 \
    const int fko  = (lane >> 4) * 8;                                           \
    const int fxm  = (frow & 7) << 3;                                           \
    f32x4 acc[2][4];                                                            \
    _Pragma("unroll")                                                           \
    for (int i = 0; i < 2; ++i)                                                 \
        _Pragma("unroll")                                                       \
        for (int j = 0; j < 4; ++j) acc[i][j] = (f32x4){0.f, 0.f, 0.f, 0.f};

#define GEMM_MAINLOOP(Kr)                                                       \
    {                                                                           \
        const int nt = (Kr) >> 6;                                               \
        int cur = 0;                                                            \
        GEMM_STAGE(0, 0);                                                       \
        for (int t = 0; t < nt; ++t) {                                          \
            __syncthreads();                                                    \
            if (t + 1 < nt) GEMM_STAGE(cur ^ 1, (t + 1) * 64);                  \
            const unsigned short* Ab = As[cur];                                 \
            const unsigned short* Wb = Ws[cur];                                 \
            bf16x8 af[2][2], wf[2][4];                                          \
            _Pragma("unroll")                                                   \
            for (int kk = 0; kk < 2; ++kk) {                                    \
                _Pragma("unroll")                                               \
                for (int i = 0; i < 2; ++i) {                                   \
                    int fr = wr * 32 + i * 16 + frow;                           \
                    af[kk][i] = *(const bf16x8*)&Ab[fr * 64 + ((kk * 32 + fko) ^ fxm)]; \
                }                                                               \
                _Pragma("unroll")                                               \
                for (int j = 0; j < 4; ++j) {                                   \
                    int fr = wc * 64 + j * 16 + frow;                           \
                    wf[kk][j] = *(const bf16x8*)&Wb[fr * 64 + ((kk * 32 + fko) ^ fxm)]; \
                }                                                               \
            }                                                                   \
            __builtin_amdgcn_s_setprio(1);                                      \
            _Pragma("unroll")                                                   \
            for (int kk = 0; kk < 2; ++kk)                                      \
                _Pragma("unroll")                                               \
                for (int i = 0; i < 2; ++i)                                     \
                    _Pragma("unroll")                                           \
                    for (int j = 0; j < 4; ++j)                                 \
                        acc[i][j] = __builtin_amdgcn_mfma_f32_16x16x32_bf16(    \
                            af[kk][i], wf[kk][j], acc[i][j], 0, 0, 0);          \
            __builtin_amdgcn_s_setprio(0);                                      \
            cur ^= 1;                                                           \
        }                                                                       \
    }

// Generic GEMM. epi: 0=f32 out(+bias), 1=f32+bias+clip, 2=bf16 out (Cb)
__global__ __launch_bounds__(256) void gemm_bf16(
    const unsigned short* __restrict__ A, int lda,
    const unsigned short* __restrict__ Wt, int ldw,
    const float* __restrict__ bias,
    float* __restrict__ C, unsigned short* __restrict__ Cb, int ldc,
    int Nr, int Kr, int epi)
{
    GEMM_PROLOG
    GEMM_MAINLOOP(Kr)
    #pragma unroll
    for (int i = 0; i < 2; ++i) {
        int m0r = row0 + wr * 32 + i * 16 + (lane >> 4) * 4;
        #pragma unroll
        for (int j = 0; j < 4; ++j) {
            int n = col0 + wc * 64 + j * 16 + (lane & 15);
            if (n >= Nr) continue;
            float bv = bias ? bias[n] : 0.f;
            #pragma unroll
            for (int r = 0; r < 4; ++r) {
                float v = acc[i][j][r] + bv;
                if (epi == 1) v = fminf(fmaxf(v, -20.f), 20.f);
                if (epi == 2) Cb[(size_t)(m0r + r) * ldc + n] = f2bf(v);
                else          C [(size_t)(m0r + r) * ldc + n] = v;
            }
        }
    }
}

// LSTM GEMM: W columns gate-permuted (c = 64q+16g+uu -> orig col g*512+q*16+uu).
// Each wave's 4 j-fragments are the 4 gates of one 16-unit group.
__global__ __launch_bounds__(256) void gemm_lstm(
    const unsigned short* __restrict__ A, int lda,
    const unsigned short* __restrict__ Wt, int ldw,
    const float* __restrict__ biasP, const float* __restrict__ c0,
    unsigned short* __restrict__ hout, int ldh, int Kr, int doclip)
{
    GEMM_PROLOG
    GEMM_MAINLOOP(Kr)
    const int uu = lane & 15;
    const int uq = ((col0 >> 6) + wc) * 16 + uu;     // unit index
    const float c0v = c0[uq];
    const int cb = col0 + wc * 64 + uu;
    const float bi = biasP[cb], bfv = biasP[cb + 16],
                bgv = biasP[cb + 32], bov = biasP[cb + 48];
    #pragma unroll
    for (int i = 0; i < 2; ++i) {
        int rbase = row0 + wr * 32 + i * 16 + (lane >> 4) * 4;
        #pragma unroll
        for (int r = 0; r < 4; ++r) {
            float ig = acc[i][0][r] + bi;
            float fg = acc[i][1][r] + bfv;
            float gg = acc[i][2][r] + bgv;
            float og = acc[i][3][r] + bov;
            float c = sigf(fg) * c0v + sigf(ig) * tanhf(gg);
            float h = sigf(og) * tanhf(c);
            if (doclip) h = fminf(fmaxf(h, -20.f), 20.f);
            hout[(size_t)(rbase + r) * ldh + uq] = f2bf(h);
        }
    }
}

// ===========================================================================
// k_prep: all independent prep work in ONE launch (block-range dispatch).
// ===========================================================================
DEV void dev_cvt8(const float* src, int lds, unsigned short* dst, int ldd,
                  int c8, int bloc, int tid)
{
    size_t idx = (size_t)bloc * 256 + tid;
    size_t r = idx / c8, c = (idx % c8) * 8;
    const float* s = src + r * lds + c;
    float4 v0 = *(const float4*)s;
    float4 v1 = *(const float4*)(s + 4);
    ushort8 o;
    o[0] = f2bf(v0.x); o[1] = f2bf(v0.y); o[2] = f2bf(v0.z); o[3] = f2bf(v0.w);
    o[4] = f2bf(v1.x); o[5] = f2bf(v1.y); o[6] = f2bf(v1.z); o[7] = f2bf(v1.w);
    *(ushort8*)(dst + r * ldd + c) = o;
}

DEV void dev_cvtT(const float* src, int R, int C, int lds,
                  unsigned short* dst, int ldd, int mode, int bx, int by,
                  int tid, float* t /*32x33*/)
{
    const int x = tid & 31;
    for (int y = tid >> 5; y < 32; y += 8) {
        int r = by * 32 + y, c = bx * 32 + x;
        int scol = c;
        if (mode) scol = ((c >> 4) & 3) * 512 + (c >> 6) * 16 + (c & 15);
        t[y * 33 + x] = (r < R && c < C) ? src[(size_t)r * lds + scol] : 0.f;
    }
    __syncthreads();
    for (int y = tid >> 5; y < 32; y += 8) {
        int c = bx * 32 + y, r = by * 32 + x;
        if (c < C && r < R) dst[(size_t)c * ldd + r] = f2bf(t[x * 33 + y]);
    }
}

__global__ __launch_bounds__(256) void k_prep(
    const float* __restrict__ X, const float* __restrict__ m0,
    const float* __restrict__ H0, const float* __restrict__ R0,
    const float* __restrict__ A0, const float* __restrict__ W_prep,
    const float* __restrict__ b_prep, const float* __restrict__ W_lstm,
    const float* __restrict__ W_r, const float* __restrict__ b_r,
    const float* __restrict__ W_w, const float* __restrict__ b_w,
    const float* __restrict__ W_ou, float* __restrict__ ws)
{
    __shared__ float sh[32 * 33 + 64];
    const int bid = blockIdx.x, tid = threadIdx.x;
    unsigned short* XHB   = (unsigned short*)(ws + OFF_XHB);
    unsigned short* W0T   = (unsigned short*)(ws + OFF_W0T);
    unsigned short* W1T   = (unsigned short*)(ws + OFF_W1T);
    unsigned short* WRWT  = (unsigned short*)(ws + OFF_WRWT);
    unsigned short* WCOMB = (unsigned short*)(ws + OFF_WCOMB);
    unsigned short* WR2T  = (unsigned short*)(ws + OFF_WR2T);
    unsigned short* M0B   = (unsigned short*)(ws + OFF_M0B);

    if (bid < S_M0) {
        dev_cvt8(X, 512, XHB, 1024, 64, bid - S_X0, tid);
    } else if (bid < S_W0) {
        dev_cvt8(m0, 128, M0B, 128, 16, bid - S_M0, tid);
    } else if (bid < S_W1) {
        int s = bid - S_W0;
        dev_cvtT(W_lstm, 512, 2048, 2048, W0T, 512, 1, s & 63, s >> 6, tid, sh);
    } else if (bid < S_WR) {
        int s = bid - S_W1;
        dev_cvtT(W_lstm + (size_t)1536 * 2048, 1024, 2048, 2048, W1T, 1024, 1,
                 s & 63, s >> 6, tid, sh);
    } else if (bid < S_WW) {
        int s = bid - S_WR;
        dev_cvtT(W_r, 512, 268, 268, WRWT, 512, 0, s % 9, s / 9, tid, sh);
    } else if (bid < S_WOU) {
        int s = bid - S_WW;
        dev_cvtT(W_w, 512, 780, 780, WRWT + (size_t)268 * 512, 512, 0,
                 s % 25, s / 25, tid, sh);
    } else if (bid < S_WR2) {
        int s = bid - S_WOU;
        dev_cvtT(W_ou, 512, 512, 512, WCOMB, 1024, 0, s & 15, s >> 4, tid, sh);
    } else if (bid < S_CA) {
        int s = bid - S_WR2;
        // FIX (R5 bug): 16 col-blocks x 8 row-blocks -> bx = s & 15, by = s >> 4
        dev_cvtT(W_ou + (size_t)512 * 512, 256, 512, 512, WR2T, 256, 0,
                 s & 15, s >> 4, tid, sh);
    } else if (bid < S_ZC) {
        // constants: aprev softmax, m_norm, head bias
        float* red = sh;
        for (int i = 0; i < 4; ++i) {
            float v = A0[i * 256 + tid];
            float mx = blk_reduce_max(v, red);
            float e = expf(v - mx);
            float s = blk_reduce_sum(e, red);
            ws[OFF_APREV + i * 256 + tid] = e / s;
        }
        float acc = 0.f;
        for (int m = 0; m < 128; ++m) {
            float t = m0[(size_t)tid * 128 + m];
            acc = fmaf(t, t, acc);
        }
        ws[OFF_MNORM + tid] = sqrtf(acc);
        for (int j = tid; j < 1152; j += 256)
            ws[OFF_BIASH + j] = (j < 268) ? b_r[j] : (j < 1048 ? b_w[j - 268] : 0.f);
    } else {
        // split-K partials for z0c/z1c (coalesced W_lstm rows)
        int sub = bid - S_ZC;
        int colb = sub & 7, up = (sub >> 3) & 7, z = sub >> 6;
        int j = colb * 256 + tid;
        float acc = 0.f;
        if (z == 0) {
            if (up < 4) {
                // compute h0 slice [up*128, +128) in-block
                sh[256 + tid] = tanhf(R0[tid]);
                __syncthreads();
                if (tid < 128) {
                    int u = up * 128 + tid;
                    float a = b_prep[u];
                    for (int k = 0; k < 256; ++k)
                        a = fmaf(sh[256 + k], W_prep[(size_t)k * 512 + u], a);
                    sh[tid] = a;
                }
                __syncthreads();
                const int u0 = up * 128;
                #pragma unroll 4
                for (int t = 0; t < 128; ++t)
                    acc = fmaf(sh[t], W_lstm[(size_t)(512 + u0 + t) * 2048 + j], acc);
            } else {
                const int u0 = up * 128;
                #pragma unroll 4
                for (int t = 0; t < 128; ++t)
                    acc = fmaf(H0[u0 - 512 + t],
                               W_lstm[(size_t)(512 + u0 + t) * 2048 + j], acc);
            }
        } else {
            const int u0 = up * 64;
            const float* W1 = W_lstm + (size_t)1536 * 2048;
            #pragma unroll 4
            for (int t = 0; t < 64; ++t)
                acc = fmaf(H0[512 + u0 + t], W1[(size_t)(1024 + u0 + t) * 2048 + j], acc);
        }
        (ws + OFF_ZPART)[((size_t)z * 8 + up) * 2048 + j] = acc;
    }
}

// Reduce 8 partials + bias, write gate-permuted
__global__ void k_zc_red(const float* __restrict__ part,
                         const float* __restrict__ b_lstm,
                         float* __restrict__ ws)
{
    int idx = blockIdx.x * 256 + threadIdx.x;        // 0..4095
    int z = idx >> 11, j = idx & 2047;
    float acc = b_lstm[z * 2048 + j];
    #pragma unroll
    for (int p = 0; p < 8; ++p)
        acc += part[((size_t)z * 8 + p) * 2048 + j];
    int g = j >> 9, q = (j >> 4) & 31, uu = j & 15;
    int c = q * 64 + g * 16 + uu;
    ws[(z == 0 ? OFF_Z0C : OFF_Z1C) + c] = acc;
}

// Per-(b,head): k = tanh(hd[:128]) -> KBUF bf16, knorm; write heads: erase/add
__global__ __launch_bounds__(128) void k_kprep(
    const float* __restrict__ heads, unsigned short* __restrict__ kbuf,
    float* __restrict__ knorm, float* __restrict__ era, float* __restrict__ addv)
{
    __shared__ float red[128];
    const int b = blockIdx.x, i = blockIdx.y, tid = threadIdx.x;
    const int cb = (i < 2) ? i * 134 : 268 + (i - 2) * 390;
    const float* hd = heads + (size_t)b * 1048 + cb;
    float k = tanhf(hd[tid]);
    kbuf[((size_t)b * 4 + i) * 128 + tid] = f2bf(k);
    float sq = blk_reduce_sum(k * k, red);
    if (tid == 0) knorm[b * 4 + i] = sqrtf(sq);
    if (i >= 2) {
        int ii = i - 2;
        era [((size_t)b * 2 + ii) * 128 + tid] = sigf(hd[134 + tid]);
        addv[((size_t)b * 2 + ii) * 128 + tid] = tanhf(hd[262 + tid]);
    }
}

// Addressing: read heads -> A (bf16 into HCAT); write heads -> AT f32
__global__ __launch_bounds__(256) void k_addr(
    const float* __restrict__ heads, const float* __restrict__ kmat,
    const float* __restrict__ knorm, const float* __restrict__ mnorm,
    const float* __restrict__ aprev, float* __restrict__ at,
    unsigned short* __restrict__ hcat)
{
    __shared__ float red[256];
    __shared__ float wgs[256];
    __shared__ float sc[6];
    const int b = blockIdx.x, i = blockIdx.y, tid = threadIdx.x;
    const int cb = (i < 2) ? i * 134 : 268 + (i - 2) * 390;
    const float* hd = heads + (size_t)b * 1048 + cb;
    if (tid == 0) {
        sc[0] = softplusf(hd[128]);
        sc[1] = sigf(hd[129]);
        float v0 = hd[130], v1 = hd[131], v2 = hd[132];
        float mx = fmaxf(v0, fmaxf(v1, v2));
        float e0 = expf(v0 - mx), e1 = expf(v1 - mx), e2 = expf(v2 - mx);
        float ssum = e0 + e1 + e2;
        sc[2] = e0 / ssum; sc[3] = e1 / ssum; sc[4] = e2 / ssum;
        sc[5] = softplusf(hd[133]);
    }
    __syncthreads();
    const float beta = sc[0], g = sc[1], s0 = sc[2], s1 = sc[3], s2 = sc[4],
                gamma = sc[5];
    float inner = kmat[((size_t)b * 4 + i) * 256 + tid];
    float kn = knorm[b * 4 + i];
    float K = inner / (kn * mnorm[tid] + 1e-8f);
    float x = beta * K;
    float mx = blk_reduce_max(x, red);
    float e = expf(x - mx);
    float se = blk_reduce_sum(e, red);
    float wc = e / se;
    float wg = g * wc + (1.f - g) * aprev[i * 256 + tid];
    wgs[tid] = wg;
    __syncthreads();
    float wconv = s0 * wg + s1 * wgs[(tid + 255) & 255] + s2 * wgs[(tid + 1) & 255];
    float wsh = powf(wconv, gamma);
    float ssum = blk_reduce_sum(wsh, red);
    float w = wsh / ssum;
    if (i < 2) hcat[(size_t)b * 1024 + 512 + i * 256 + tid] = f2bf(w);
    else       at[((size_t)(i - 2) * Bn + b) * 256 + tid] = w;
}

// m_t streaming update
__global__ void k_mem(const float* __restrict__ m0, const float* __restrict__ at,
                      const float* __restrict__ era, const float* __restrict__ addv,
                      float* __restrict__ outm)
{
    const size_t total = (size_t)Bn * Nn * (Mn / 4);
    for (size_t idx = (size_t)blockIdx.x * blockDim.x + threadIdx.x;
         idx < total; idx += (size_t)gridDim.x * blockDim.x) {
        int mq = (int)(idx & 31);
        int n  = (int)((idx >> 5) & 255);
        int b  = (int)(idx >> 13);
        float4 t  = reinterpret_cast<const float4*>(m0)[n * 32 + mq];
        float w0 = at[((size_t)0 * Bn + b) * 256 + n];
        float w1 = at[((size_t)1 * Bn + b) * 256 + n];
        float4 e0 = reinterpret_cast<const float4*>(era) [((size_t)b * 2 + 0) * 32 + mq];
        float4 a0 = reinterpret_cast<const float4*>(addv)[((size_t)b * 2 + 0) * 32 + mq];
        float4 e1 = reinterpret_cast<const float4*>(era) [((size_t)b * 2 + 1) * 32 + mq];
        float4 a1 = reinterpret_cast<const float4*>(addv)[((size_t)b * 2 + 1) * 32 + mq];
#define UPD(c) { t.c = t.c * (1.f - w0 * e0.c) + w0 * a0.c; \
                 t.c = t.c * (1.f - w1 * e1.c) + w1 * a1.c; }
        UPD(x) UPD(y) UPD(z) UPD(w)
#undef UPD
        reinterpret_cast<float4*>(outm)[idx] = t;
    }
}

extern "C" void kernel_launch(void* const* d_in, const int* in_sizes, int n_in,
                              void* d_out, int out_size, void* d_ws, size_t ws_size,
                              hipStream_t stream)
{
    const float* X      = (const float*)d_in[0];
    const float* m0     = (const float*)d_in[1];
    const float* H0     = (const float*)d_in[2];
    const float* C0     = (const float*)d_in[3];
    const float* R0     = (const float*)d_in[4];
    const float* A0     = (const float*)d_in[5];
    const float* W_prep = (const float*)d_in[6];
    const float* b_prep = (const float*)d_in[7];
    const float* W_lstm = (const float*)d_in[8];
    const float* b_lstm = (const float*)d_in[9];
    const float* W_r    = (const float*)d_in[10];
    const float* b_r    = (const float*)d_in[11];
    const float* W_w    = (const float*)d_in[12];
    const float* b_w    = (const float*)d_in[13];
    const float* W_ou   = (const float*)d_in[14];
    const float* b_ou   = (const float*)d_in[15];
    float* ws  = (float*)d_ws;
    float* out = (float*)d_out;

    unsigned short* XHB   = (unsigned short*)(ws + OFF_XHB);
    unsigned short* HCAT  = (unsigned short*)(ws + OFF_HCAT);
    unsigned short* W0T   = (unsigned short*)(ws + OFF_W0T);
    unsigned short* W1T   = (unsigned short*)(ws + OFF_W1T);
    unsigned short* WRWT  = (unsigned short*)(ws + OFF_WRWT);
    unsigned short* WCOMB = (unsigned short*)(ws + OFF_WCOMB);
    unsigned short* WR2T  = (unsigned short*)(ws + OFF_WR2T);
    unsigned short* M0B   = (unsigned short*)(ws + OFF_M0B);
    unsigned short* KBUF  = (unsigned short*)(ws + OFF_KBUF);

    // ---- all prep in one launch ----
    k_prep<<<S_END, 256, 0, stream>>>(
        X, m0, H0, R0, A0, W_prep, b_prep, W_lstm, W_r, b_r, W_w, b_w, W_ou, ws);
    k_zc_red<<<16, 256, 0, stream>>>(ws + OFF_ZPART, b_lstm, ws);

    // P_i = (W_ou read-slice)^T @ m0^T folded into combined output weight
    gemm_bf16<<<dim3(8, 2), 256, 0, stream>>>(
        WR2T, 256, M0B, 128, nullptr, nullptr, WCOMB + 512, 1024, 256, 128, 2);
    gemm_bf16<<<dim3(8, 2), 256, 0, stream>>>(
        WR2T + 128, 256, M0B, 128, nullptr, nullptr, WCOMB + 768, 1024, 256, 128, 2);

    // ---- LSTM (fused gates) ----
    gemm_lstm<<<dim3(32, 16), 256, 0, stream>>>(
        XHB, 1024, W0T, 512, ws + OFF_Z0C, C0, XHB + 512, 1024, 512, 0);
    gemm_lstm<<<dim3(32, 16), 256, 0, stream>>>(
        XHB, 1024, W1T, 1024, ws + OFF_Z1C, C0 + 512, HCAT, 1024, 1024, 1);

    // ---- heads ----
    gemm_bf16<<<dim3(32, 9), 256, 0, stream>>>(
        HCAT, 1024, WRWT, 512, ws + OFF_BIASH, ws + OFF_HEADS, nullptr, 1048, 1048, 512, 0);

    k_kprep<<<dim3(Bn, 4), 128, 0, stream>>>(
        ws + OFF_HEADS, KBUF, ws + OFF_KNORM, ws + OFF_ERA, ws + OFF_ADD);

    // inner[b,i,n] = k . m0[n]
    gemm_bf16<<<dim3(128, 2), 256, 0, stream>>>(
        KBUF, 128, M0B, 128, nullptr, ws + OFF_KMAT, nullptr, 256, 256, 128, 0);

    k_addr<<<dim3(Bn, 4), 256, 0, stream>>>(
        ws + OFF_HEADS, ws + OFF_KMAT, ws + OFF_KNORM, ws + OFF_MNORM,
        ws + OFF_APREV, ws + OFF_AT, HCAT);

    // ---- y = clip([h|A0|A1] @ WCOMB + b_ou) ----
    gemm_bf16<<<dim3(32, 4), 256, 0, stream>>>(
        HCAT, 1024, WCOMB, 1024, b_ou, out, nullptr, 512, 512, 1024, 1);

    // ---- m_t ----
    k_mem<<<2048, 256, 0, stream>>>(
        m0, ws + OFF_AT, ws + OFF_ERA, ws + OFF_ADD, out + (size_t)Bn * Un);
}

// Round 7
// 205.692 us; speedup vs baseline: 2.3149x; 1.0228x over previous
//
#include <hip/hip_runtime.h>
#include <math.h>

static constexpr int Bn = 2048;   // batch
static constexpr int Nn = 256;    // memory locations
static constexpr int Mn = 128;    // memory width
static constexpr int Un = 512;    // units

// Workspace layout (f32 offsets)
static constexpr size_t OFF_MNORM = 4608;     // 256
static constexpr size_t OFF_APREV = 4864;     // 1024
static constexpr size_t OFF_BIASH = 5888;     // 1152
static constexpr size_t OFF_KMAT  = 16384;                          // f32 [8192][256]
static constexpr size_t OFF_HEADS = OFF_KMAT + (size_t)8192 * 256;  // f32 [2048][1048]
static constexpr size_t OFF_AT    = OFF_HEADS + (size_t)2048 * 1048;// f32 [2][2048][256]
static constexpr size_t OFF_ERA   = OFF_AT + (size_t)2 * 2048 * 256;// f32 [2048][2][128]
static constexpr size_t OFF_ADD   = OFF_ERA + (size_t)2048 * 256;
static constexpr size_t OFF_XHB   = OFF_ADD + (size_t)2048 * 256;   // bf16 [2048][1024]
static constexpr size_t OFF_HCAT  = OFF_XHB + 524288;               // bf16 [2048][1024]
static constexpr size_t OFF_W0T   = OFF_HCAT + 524288;              // bf16 [2048][512]
static constexpr size_t OFF_W1T   = OFF_W0T + 524288;               // bf16 [2048][1024]
static constexpr size_t OFF_WRWT  = OFF_W1T + 1048576;              // bf16 [1152][512]
static constexpr size_t OFF_WCOMB = OFF_WRWT + 294912;              // bf16 [512][1024]
static constexpr size_t OFF_WR2T  = OFF_WCOMB + 262144;             // bf16 [512][256]
static constexpr size_t OFF_M0B   = OFF_WR2T + 65536;               // bf16 [256][128]
static constexpr size_t OFF_ZPART = OFF_M0B + 16384 + 524288;       // f32 [2][8][2048]

// k_prep block-range dispatch table
static constexpr int S_X0  = 0;            // cvt8 X        (512)
static constexpr int S_M0  = 512;          // cvt8 m0       (16)
static constexpr int S_W0  = 528;          // cvtT W0 gate  (64x16)
static constexpr int S_W1  = 1552;         // cvtT W1 gate  (64x32)
static constexpr int S_WR  = 3600;         // cvtT W_r      (9x16)
static constexpr int S_WW  = 3744;         // cvtT W_w      (25x16)
static constexpr int S_WOU = 4144;         // cvtT W_ou h   (16x16)
static constexpr int S_WR2 = 4400;         // cvtT W_ou r   (16x8)
static constexpr int S_CA  = 4528;         // const-a       (1)
static constexpr int S_ZC  = 4529;         // zc partials   (128)
static constexpr int S_END = 4657;

#define DEV __device__ __forceinline__

typedef __attribute__((ext_vector_type(8))) short bf16x8;
typedef __attribute__((ext_vector_type(4))) float f32x4;
typedef __attribute__((ext_vector_type(8))) unsigned short ushort8;
typedef unsigned int u32;

DEV float sigf(float x) { return 1.0f / (1.0f + expf(-x)); }
DEV float softplusf(float x) { return x > 20.0f ? x : log1pf(expf(x)); }
DEV unsigned short f2bf(float f) {   // RNE float->bf16
    unsigned u = __float_as_uint(f);
    u = (u + 0x7FFFu + ((u >> 16) & 1u)) >> 16;
    return (unsigned short)u;
}
DEV void gload16(const unsigned short* g, unsigned short* l) {
    __builtin_amdgcn_global_load_lds(
        (const __attribute__((address_space(1))) u32*)g,
        (__attribute__((address_space(3))) u32*)l, 16, 0, 0);
}

DEV float blk_reduce_max(float v, float* red) {
    int tid = threadIdx.x;
    red[tid] = v; __syncthreads();
    for (int s = (int)blockDim.x >> 1; s > 0; s >>= 1) {
        if (tid < s) red[tid] = fmaxf(red[tid], red[tid + s]);
        __syncthreads();
    }
    float r = red[0]; __syncthreads();
    return r;
}
DEV float blk_reduce_sum(float v, float* red) {
    int tid = threadIdx.x;
    red[tid] = v; __syncthreads();
    for (int s = (int)blockDim.x >> 1; s > 0; s >>= 1) {
        if (tid < s) red[tid] += red[tid + s];
        __syncthreads();
    }
    float r = red[0]; __syncthreads();
    return r;
}

// ===========================================================================
// GEMM: 64x128 tile (M x N), 4 waves (2x2), BK=64, double-buffered LDS via
// global_load_lds (16B), XOR-swizzled via pre-swizzled source k-offset.
// A bf16 [M][lda], Wt bf16 [N][ldw] (weights pre-transposed).
// ===========================================================================
#define GEMM_STAGE(buf, k0)                                                     \
    {                                                                           \
        _Pragma("unroll")                                                       \
        for (int q = 0; q < 2; ++q)                                             \
            gload16(A  + (size_t)(row0 + q * 32 + (tid >> 3)) * lda + (k0) + ke,\
                    &As[buf][q * 2048 + tid * 8]);                              \
        _Pragma("unroll")                                                       \
        for (int q = 0; q < 4; ++q)                                             \
            gload16(Wt + (size_t)(col0 + q * 32 + (tid >> 3)) * ldw + (k0) + ke,\
                    &Ws[buf][q * 2048 + tid * 8]);                              \
    }

#define GEMM_PROLOG                                                             \
    __shared__ __align__(16) unsigned short As[2][64 * 64];                     \
    __shared__ __align__(16) unsigned short Ws[2][128 * 64];                    \
    const int tid  = threadIdx.x;                                               \
    const int lane = tid & 63;                                                  \
    const int wave = tid >> 6;                                                  \
    const int wr = wave >> 1, wc = wave & 1;                                    \
    const int row0 = blockIdx.x * 64;                                           \
    const int col0 = blockIdx.y * 128;                                          \
    const int ke = ((tid & 7) * 8) ^ (((tid >> 3) & 7) << 3);                   \
    const int frow = lane & 15;                                                 \
    const int fko  = (lane >> 4) * 8;                                           \
    const int fxm  = (frow & 7) << 3;                                           \
    f32x4 acc[2][4];                                                            \
    _Pragma("unroll")                                                           \
    for (int i = 0; i < 2; ++i)                                                 \
        _Pragma("unroll")                                                       \
        for (int j = 0; j < 4; ++j) acc[i][j] = (f32x4){0.f, 0.f, 0.f, 0.f};

#define GEMM_FRAGS_AND_MFMA(Ab, Wb)                                             \
    {                                                                           \
        bf16x8 af[2][2], wf[2][4];                                              \
        _Pragma("unroll")                                                       \
        for (int kk = 0; kk < 2; ++kk) {                                        \
            _Pragma("unroll")                                                   \
            for (int i = 0; i < 2; ++i) {                                       \
                int fr = wr * 32 + i * 16 + frow;                               \
                af[kk][i] = *(const bf16x8*)&(Ab)[fr * 64 + ((kk * 32 + fko) ^ fxm)]; \
            }                                                                   \
            _Pragma("unroll")                                                   \
            for (int j = 0; j < 4; ++j) {                                       \
                int fr = wc * 64 + j * 16 + frow;                               \
                wf[kk][j] = *(const bf16x8*)&(Wb)[fr * 64 + ((kk * 32 + fko) ^ fxm)]; \
            }                                                                   \
        }                                                                       \
        __builtin_amdgcn_s_setprio(1);                                          \
        _Pragma("unroll")                                                       \
        for (int kk = 0; kk < 2; ++kk)                                          \
            _Pragma("unroll")                                                   \
            for (int i = 0; i < 2; ++i)                                         \
                _Pragma("unroll")                                               \
                for (int j = 0; j < 4; ++j)                                     \
                    acc[i][j] = __builtin_amdgcn_mfma_f32_16x16x32_bf16(        \
                        af[kk][i], wf[kk][j], acc[i][j], 0, 0, 0);              \
        __builtin_amdgcn_s_setprio(0);                                          \
    }

#define GEMM_MAINLOOP(Kr)                                                       \
    {                                                                           \
        const int nt = (Kr) >> 6;                                               \
        int cur = 0;                                                            \
        GEMM_STAGE(0, 0);                                                       \
        for (int t = 0; t < nt; ++t) {                                          \
            __syncthreads();                                                    \
            if (t + 1 < nt) GEMM_STAGE(cur ^ 1, (t + 1) * 64);                  \
            GEMM_FRAGS_AND_MFMA(As[cur], Ws[cur]);                              \
            cur ^= 1;                                                           \
        }                                                                       \
    }

// Generic GEMM. epi: 0=f32 out(+bias), 1=f32+bias+clip, 2=bf16 out (Cb)
__global__ __launch_bounds__(256) void gemm_bf16(
    const unsigned short* __restrict__ A, int lda,
    const unsigned short* __restrict__ Wt, int ldw,
    const float* __restrict__ bias,
    float* __restrict__ C, unsigned short* __restrict__ Cb, int ldc,
    int Nr, int Kr, int epi)
{
    GEMM_PROLOG
    GEMM_MAINLOOP(Kr)
    #pragma unroll
    for (int i = 0; i < 2; ++i) {
        int m0r = row0 + wr * 32 + i * 16 + (lane >> 4) * 4;
        #pragma unroll
        for (int j = 0; j < 4; ++j) {
            int n = col0 + wc * 64 + j * 16 + (lane & 15);
            if (n >= Nr) continue;
            float bv = bias ? bias[n] : 0.f;
            #pragma unroll
            for (int r = 0; r < 4; ++r) {
                float v = acc[i][j][r] + bv;
                if (epi == 1) v = fminf(fmaxf(v, -20.f), 20.f);
                if (epi == 2) Cb[(size_t)(m0r + r) * ldc + n] = f2bf(v);
                else          C [(size_t)(m0r + r) * ldc + n] = v;
            }
        }
    }
}

// P-fold GEMM: z = blockIdx.z selects read head; A = WR2T + z*128 (k slice),
// out = WCOMB cols 512 + z*256. K=128, bf16 out.
__global__ __launch_bounds__(256) void gemm_pfold(
    const unsigned short* __restrict__ WR2T,
    const unsigned short* __restrict__ M0B,
    unsigned short* __restrict__ WCOMB)
{
    const unsigned short* A  = WR2T + blockIdx.z * 128;
    const unsigned short* Wt = M0B;
    const int lda = 256, ldw = 128;
    unsigned short* Cb = WCOMB + 512 + blockIdx.z * 256;
    GEMM_PROLOG
    GEMM_MAINLOOP(128)
    #pragma unroll
    for (int i = 0; i < 2; ++i) {
        int m0r = row0 + wr * 32 + i * 16 + (lane >> 4) * 4;
        #pragma unroll
        for (int j = 0; j < 4; ++j) {
            int n = col0 + wc * 64 + j * 16 + (lane & 15);
            #pragma unroll
            for (int r = 0; r < 4; ++r)
                Cb[(size_t)(m0r + r) * 1024 + n] = f2bf(acc[i][j][r]);
        }
    }
}

// LSTM GEMM: W columns gate-permuted (c = 64q+16g+uu -> orig col g*512+q*16+uu).
// Epilogue sums the 8 split-K constant partials + bias (fused k_zc_red), then
// applies the cell nonlinearity, writes h (bf16).
__global__ __launch_bounds__(256) void gemm_lstm(
    const unsigned short* __restrict__ A, int lda,
    const unsigned short* __restrict__ Wt, int ldw,
    const float* __restrict__ zpart, const float* __restrict__ b_lstm,
    int z, const float* __restrict__ c0,
    unsigned short* __restrict__ hout, int ldh, int Kr, int doclip)
{
    GEMM_PROLOG
    GEMM_MAINLOOP(Kr)
    const int uu = lane & 15;
    const int q  = (col0 >> 6) + wc;
    const int uq = q * 16 + uu;                      // unit index
    const float c0v = c0[uq];
    float bg[4];
    #pragma unroll
    for (int g = 0; g < 4; ++g) {
        int j = g * 512 + q * 16 + uu;               // orig W_lstm column
        float a = b_lstm[z * 2048 + j];
        #pragma unroll
        for (int p = 0; p < 8; ++p)
            a += zpart[((size_t)z * 8 + p) * 2048 + j];
        bg[g] = a;
    }
    #pragma unroll
    for (int i = 0; i < 2; ++i) {
        int rbase = row0 + wr * 32 + i * 16 + (lane >> 4) * 4;
        #pragma unroll
        for (int r = 0; r < 4; ++r) {
            float ig = acc[i][0][r] + bg[0];
            float fg = acc[i][1][r] + bg[1];
            float gg = acc[i][2][r] + bg[2];
            float og = acc[i][3][r] + bg[3];
            float c = sigf(fg) * c0v + sigf(ig) * tanhf(gg);
            float h = sigf(og) * tanhf(c);
            if (doclip) h = fminf(fmaxf(h, -20.f), 20.f);
            hout[(size_t)(rbase + r) * ldh + uq] = f2bf(h);
        }
    }
}

// kmat GEMM with fused k-prep: A-operand = tanh(heads k-slices) computed
// on the fly (reg-staged f32->tanh->bf16->ds_write, same swizzled slots);
// B-operand = M0B via global_load_lds. C = inner[b,i,n] f32 [8192][256].
__global__ __launch_bounds__(256) void gemm_kmat(
    const float* __restrict__ heads,
    const unsigned short* __restrict__ M0B,
    float* __restrict__ C)
{
    __shared__ __align__(16) unsigned short As[2][64 * 64];
    __shared__ __align__(16) unsigned short Ws[2][128 * 64];
    const int tid  = threadIdx.x;
    const int lane = tid & 63;
    const int wave = tid >> 6;
    const int wr = wave >> 1, wc = wave & 1;
    const int row0 = blockIdx.x * 64;
    const int col0 = blockIdx.y * 128;
    const int ke = ((tid & 7) * 8) ^ (((tid >> 3) & 7) << 3);
    const int frow = lane & 15;
    const int fko  = (lane >> 4) * 8;
    const int fxm  = (frow & 7) << 3;
    f32x4 acc[2][4];
    #pragma unroll
    for (int i = 0; i < 2; ++i)
        #pragma unroll
        for (int j = 0; j < 4; ++j) acc[i][j] = (f32x4){0.f, 0.f, 0.f, 0.f};

#define KMAT_STAGE(buf, k0)                                                     \
    {                                                                           \
        _Pragma("unroll")                                                       \
        for (int q = 0; q < 2; ++q) {                                           \
            int R = row0 + q * 32 + (tid >> 3);                                 \
            int b = R >> 2, ih = R & 3;                                         \
            int cb = (ih < 2) ? ih * 134 : 268 + (ih - 2) * 390;                \
            const float* hp = heads + (size_t)b * 1048 + cb + (k0) + ke;        \
            ushort8 o;                                                          \
            _Pragma("unroll")                                                   \
            for (int j = 0; j < 8; ++j) o[j] = f2bf(tanhf(hp[j]));              \
            *(ushort8*)&As[buf][q * 2048 + tid * 8] = o;                        \
        }                                                                       \
        _Pragma("unroll")                                                       \
        for (int q = 0; q < 4; ++q)                                             \
            gload16(M0B + (size_t)(col0 + q * 32 + (tid >> 3)) * 128 + (k0) + ke,\
                    &Ws[buf][q * 2048 + tid * 8]);                              \
    }

    int cur = 0;
    KMAT_STAGE(0, 0);
    for (int t = 0; t < 2; ++t) {
        __syncthreads();
        if (t == 0) KMAT_STAGE(1, 64);
        GEMM_FRAGS_AND_MFMA(As[cur], Ws[cur]);
        cur ^= 1;
    }
#undef KMAT_STAGE
    #pragma unroll
    for (int i = 0; i < 2; ++i) {
        int m0r = row0 + wr * 32 + i * 16 + (lane >> 4) * 4;
        #pragma unroll
        for (int j = 0; j < 4; ++j) {
            int n = col0 + wc * 64 + j * 16 + (lane & 15);
            #pragma unroll
            for (int r = 0; r < 4; ++r)
                C[(size_t)(m0r + r) * 256 + n] = acc[i][j][r];
        }
    }
}

// ===========================================================================
// k_prep: all independent prep work in ONE launch (block-range dispatch).
// ===========================================================================
DEV void dev_cvt8(const float* src, int lds, unsigned short* dst, int ldd,
                  int c8, int bloc, int tid)
{
    size_t idx = (size_t)bloc * 256 + tid;
    size_t r = idx / c8, c = (idx % c8) * 8;
    const float* s = src + r * lds + c;
    float4 v0 = *(const float4*)s;
    float4 v1 = *(const float4*)(s + 4);
    ushort8 o;
    o[0] = f2bf(v0.x); o[1] = f2bf(v0.y); o[2] = f2bf(v0.z); o[3] = f2bf(v0.w);
    o[4] = f2bf(v1.x); o[5] = f2bf(v1.y); o[6] = f2bf(v1.z); o[7] = f2bf(v1.w);
    *(ushort8*)(dst + r * ldd + c) = o;
}

DEV void dev_cvtT(const float* src, int R, int C, int lds,
                  unsigned short* dst, int ldd, int mode, int bx, int by,
                  int tid, float* t /*32x33*/)
{
    const int x = tid & 31;
    for (int y = tid >> 5; y < 32; y += 8) {
        int r = by * 32 + y, c = bx * 32 + x;
        int scol = c;
        if (mode) scol = ((c >> 4) & 3) * 512 + (c >> 6) * 16 + (c & 15);
        t[y * 33 + x] = (r < R && c < C) ? src[(size_t)r * lds + scol] : 0.f;
    }
    __syncthreads();
    for (int y = tid >> 5; y < 32; y += 8) {
        int c = bx * 32 + y, r = by * 32 + x;
        if (c < C && r < R) dst[(size_t)c * ldd + r] = f2bf(t[x * 33 + y]);
    }
}

__global__ __launch_bounds__(256) void k_prep(
    const float* __restrict__ X, const float* __restrict__ m0,
    const float* __restrict__ H0, const float* __restrict__ R0,
    const float* __restrict__ A0, const float* __restrict__ W_prep,
    const float* __restrict__ b_prep, const float* __restrict__ W_lstm,
    const float* __restrict__ W_r, const float* __restrict__ b_r,
    const float* __restrict__ W_w, const float* __restrict__ b_w,
    const float* __restrict__ W_ou, float* __restrict__ ws)
{
    __shared__ float sh[32 * 33 + 64];
    const int bid = blockIdx.x, tid = threadIdx.x;
    unsigned short* XHB   = (unsigned short*)(ws + OFF_XHB);
    unsigned short* W0T   = (unsigned short*)(ws + OFF_W0T);
    unsigned short* W1T   = (unsigned short*)(ws + OFF_W1T);
    unsigned short* WRWT  = (unsigned short*)(ws + OFF_WRWT);
    unsigned short* WCOMB = (unsigned short*)(ws + OFF_WCOMB);
    unsigned short* WR2T  = (unsigned short*)(ws + OFF_WR2T);
    unsigned short* M0B   = (unsigned short*)(ws + OFF_M0B);

    if (bid < S_M0) {
        dev_cvt8(X, 512, XHB, 1024, 64, bid - S_X0, tid);
    } else if (bid < S_W0) {
        dev_cvt8(m0, 128, M0B, 128, 16, bid - S_M0, tid);
    } else if (bid < S_W1) {
        int s = bid - S_W0;
        dev_cvtT(W_lstm, 512, 2048, 2048, W0T, 512, 1, s & 63, s >> 6, tid, sh);
    } else if (bid < S_WR) {
        int s = bid - S_W1;
        dev_cvtT(W_lstm + (size_t)1536 * 2048, 1024, 2048, 2048, W1T, 1024, 1,
                 s & 63, s >> 6, tid, sh);
    } else if (bid < S_WW) {
        int s = bid - S_WR;
        dev_cvtT(W_r, 512, 268, 268, WRWT, 512, 0, s % 9, s / 9, tid, sh);
    } else if (bid < S_WOU) {
        int s = bid - S_WW;
        dev_cvtT(W_w, 512, 780, 780, WRWT + (size_t)268 * 512, 512, 0,
                 s % 25, s / 25, tid, sh);
    } else if (bid < S_WR2) {
        int s = bid - S_WOU;
        dev_cvtT(W_ou, 512, 512, 512, WCOMB, 1024, 0, s & 15, s >> 4, tid, sh);
    } else if (bid < S_CA) {
        int s = bid - S_WR2;
        dev_cvtT(W_ou + (size_t)512 * 512, 256, 512, 512, WR2T, 256, 0,
                 s & 15, s >> 4, tid, sh);
    } else if (bid < S_ZC) {
        // constants: aprev softmax, m_norm, head bias
        float* red = sh;
        for (int i = 0; i < 4; ++i) {
            float v = A0[i * 256 + tid];
            float mx = blk_reduce_max(v, red);
            float e = expf(v - mx);
            float s = blk_reduce_sum(e, red);
            ws[OFF_APREV + i * 256 + tid] = e / s;
        }
        float acc = 0.f;
        for (int m = 0; m < 128; ++m) {
            float t = m0[(size_t)tid * 128 + m];
            acc = fmaf(t, t, acc);
        }
        ws[OFF_MNORM + tid] = sqrtf(acc);
        for (int j = tid; j < 1152; j += 256)
            ws[OFF_BIASH + j] = (j < 268) ? b_r[j] : (j < 1048 ? b_w[j - 268] : 0.f);
    } else {
        // split-K partials for z0c/z1c (coalesced W_lstm rows, orig col order)
        int sub = bid - S_ZC;
        int colb = sub & 7, up = (sub >> 3) & 7, z = sub >> 6;
        int j = colb * 256 + tid;
        float acc = 0.f;
        if (z == 0) {
            if (up < 4) {
                sh[256 + tid] = tanhf(R0[tid]);
                __syncthreads();
                if (tid < 128) {
                    int u = up * 128 + tid;
                    float a = b_prep[u];
                    for (int k = 0; k < 256; ++k)
                        a = fmaf(sh[256 + k], W_prep[(size_t)k * 512 + u], a);
                    sh[tid] = a;
                }
                __syncthreads();
                const int u0 = up * 128;
                #pragma unroll 4
                for (int t = 0; t < 128; ++t)
                    acc = fmaf(sh[t], W_lstm[(size_t)(512 + u0 + t) * 2048 + j], acc);
            } else {
                const int u0 = up * 128;
                #pragma unroll 4
                for (int t = 0; t < 128; ++t)
                    acc = fmaf(H0[u0 - 512 + t],
                               W_lstm[(size_t)(512 + u0 + t) * 2048 + j], acc);
            }
        } else {
            const int u0 = up * 64;
            const float* W1 = W_lstm + (size_t)1536 * 2048;
            #pragma unroll 4
            for (int t = 0; t < 64; ++t)
                acc = fmaf(H0[512 + u0 + t], W1[(size_t)(1024 + u0 + t) * 2048 + j], acc);
        }
        (ws + OFF_ZPART)[((size_t)z * 8 + up) * 2048 + j] = acc;
    }
}

// Addressing (fused knorm + erase/add): read heads -> A (bf16 into HCAT);
// write heads -> AT f32 + era/add.
__global__ __launch_bounds__(256) void k_addr(
    const float* __restrict__ heads, const float* __restrict__ kmat,
    const float* __restrict__ mnorm, const float* __restrict__ aprev,
    float* __restrict__ at, unsigned short* __restrict__ hcat,
    float* __restrict__ era, float* __restrict__ addv)
{
    __shared__ float red[256];
    __shared__ float wgs[256];
    __shared__ float sc[6];
    const int b = blockIdx.x, i = blockIdx.y, tid = threadIdx.x;
    const int cb = (i < 2) ? i * 134 : 268 + (i - 2) * 390;
    const float* hd = heads + (size_t)b * 1048 + cb;
    // knorm (was k_kprep)
    float kv = (tid < 128) ? tanhf(hd[tid]) : 0.f;
    float ksq = blk_reduce_sum(kv * kv, red);
    float kn = sqrtf(ksq);
    // erase/add (was k_kprep)
    if (i >= 2 && tid < 128) {
        era [((size_t)b * 2 + (i - 2)) * 128 + tid] = sigf(hd[134 + tid]);
        addv[((size_t)b * 2 + (i - 2)) * 128 + tid] = tanhf(hd[262 + tid]);
    }
    if (tid == 0) {
        sc[0] = softplusf(hd[128]);
        sc[1] = sigf(hd[129]);
        float v0 = hd[130], v1 = hd[131], v2 = hd[132];
        float mx = fmaxf(v0, fmaxf(v1, v2));
        float e0 = expf(v0 - mx), e1 = expf(v1 - mx), e2 = expf(v2 - mx);
        float ssum = e0 + e1 + e2;
        sc[2] = e0 / ssum; sc[3] = e1 / ssum; sc[4] = e2 / ssum;
        sc[5] = softplusf(hd[133]);
    }
    __syncthreads();
    const float beta = sc[0], g = sc[1], s0 = sc[2], s1 = sc[3], s2 = sc[4],
                gamma = sc[5];
    float inner = kmat[((size_t)b * 4 + i) * 256 + tid];
    float K = inner / (kn * mnorm[tid] + 1e-8f);
    float x = beta * K;
    float mx = blk_reduce_max(x, red);
    float e = expf(x - mx);
    float se = blk_reduce_sum(e, red);
    float wc = e / se;
    float wg = g * wc + (1.f - g) * aprev[i * 256 + tid];
    wgs[tid] = wg;
    __syncthreads();
    float wconv = s0 * wg + s1 * wgs[(tid + 255) & 255] + s2 * wgs[(tid + 1) & 255];
    float wsh = powf(wconv, gamma);
    float ssum = blk_reduce_sum(wsh, red);
    float w = wsh / ssum;
    if (i < 2) hcat[(size_t)b * 1024 + 512 + i * 256 + tid] = f2bf(w);
    else       at[((size_t)(i - 2) * Bn + b) * 256 + tid] = w;
}

// m_t streaming update
__global__ void k_mem(const float* __restrict__ m0, const float* __restrict__ at,
                      const float* __restrict__ era, const float* __restrict__ addv,
                      float* __restrict__ outm)
{
    const size_t total = (size_t)Bn * Nn * (Mn / 4);
    for (size_t idx = (size_t)blockIdx.x * blockDim.x + threadIdx.x;
         idx < total; idx += (size_t)gridDim.x * blockDim.x) {
        int mq = (int)(idx & 31);
        int n  = (int)((idx >> 5) & 255);
        int b  = (int)(idx >> 13);
        float4 t  = reinterpret_cast<const float4*>(m0)[n * 32 + mq];
        float w0 = at[((size_t)0 * Bn + b) * 256 + n];
        float w1 = at[((size_t)1 * Bn + b) * 256 + n];
        float4 e0 = reinterpret_cast<const float4*>(era) [((size_t)b * 2 + 0) * 32 + mq];
        float4 a0 = reinterpret_cast<const float4*>(addv)[((size_t)b * 2 + 0) * 32 + mq];
        float4 e1 = reinterpret_cast<const float4*>(era) [((size_t)b * 2 + 1) * 32 + mq];
        float4 a1 = reinterpret_cast<const float4*>(addv)[((size_t)b * 2 + 1) * 32 + mq];
#define UPD(c) { t.c = t.c * (1.f - w0 * e0.c) + w0 * a0.c; \
                 t.c = t.c * (1.f - w1 * e1.c) + w1 * a1.c; }
        UPD(x) UPD(y) UPD(z) UPD(w)
#undef UPD
        reinterpret_cast<float4*>(outm)[idx] = t;
    }
}

extern "C" void kernel_launch(void* const* d_in, const int* in_sizes, int n_in,
                              void* d_out, int out_size, void* d_ws, size_t ws_size,
                              hipStream_t stream)
{
    const float* X      = (const float*)d_in[0];
    const float* m0     = (const float*)d_in[1];
    const float* H0     = (const float*)d_in[2];
    const float* C0     = (const float*)d_in[3];
    const float* R0     = (const float*)d_in[4];
    const float* A0     = (const float*)d_in[5];
    const float* W_prep = (const float*)d_in[6];
    const float* b_prep = (const float*)d_in[7];
    const float* W_lstm = (const float*)d_in[8];
    const float* b_lstm = (const float*)d_in[9];
    const float* W_r    = (const float*)d_in[10];
    const float* b_r    = (const float*)d_in[11];
    const float* W_w    = (const float*)d_in[12];
    const float* b_w    = (const float*)d_in[13];
    const float* W_ou   = (const float*)d_in[14];
    const float* b_ou   = (const float*)d_in[15];
    float* ws  = (float*)d_ws;
    float* out = (float*)d_out;

    unsigned short* XHB   = (unsigned short*)(ws + OFF_XHB);
    unsigned short* HCAT  = (unsigned short*)(ws + OFF_HCAT);
    unsigned short* W0T   = (unsigned short*)(ws + OFF_W0T);
    unsigned short* W1T   = (unsigned short*)(ws + OFF_W1T);
    unsigned short* WRWT  = (unsigned short*)(ws + OFF_WRWT);
    unsigned short* WCOMB = (unsigned short*)(ws + OFF_WCOMB);
    unsigned short* WR2T  = (unsigned short*)(ws + OFF_WR2T);
    unsigned short* M0B   = (unsigned short*)(ws + OFF_M0B);

    // 1. all prep in one launch
    k_prep<<<S_END, 256, 0, stream>>>(
        X, m0, H0, R0, A0, W_prep, b_prep, W_lstm, W_r, b_r, W_w, b_w, W_ou, ws);

    // 2. both P-folds in one dispatch
    gemm_pfold<<<dim3(8, 2, 2), 256, 0, stream>>>(WR2T, M0B, WCOMB);

    // 3-4. LSTM (fused gates + fused zc reduce)
    gemm_lstm<<<dim3(32, 16), 256, 0, stream>>>(
        XHB, 1024, W0T, 512, ws + OFF_ZPART, b_lstm, 0, C0, XHB + 512, 1024, 512, 0);
    gemm_lstm<<<dim3(32, 16), 256, 0, stream>>>(
        XHB, 1024, W1T, 1024, ws + OFF_ZPART, b_lstm, 1, C0 + 512, HCAT, 1024, 1024, 1);

    // 5. heads
    gemm_bf16<<<dim3(32, 9), 256, 0, stream>>>(
        HCAT, 1024, WRWT, 512, ws + OFF_BIASH, ws + OFF_HEADS, nullptr, 1048, 1048, 512, 0);

    // 6. inner[b,i,n] = tanh(k) . m0[n]  (fused k-prep)
    gemm_kmat<<<dim3(128, 2), 256, 0, stream>>>(
        ws + OFF_HEADS, M0B, ws + OFF_KMAT);

    // 7. addressing (+ knorm + erase/add)
    k_addr<<<dim3(Bn, 4), 256, 0, stream>>>(
        ws + OFF_HEADS, ws + OFF_KMAT, ws + OFF_MNORM, ws + OFF_APREV,
        ws + OFF_AT, HCAT, ws + OFF_ERA, ws + OFF_ADD);

    // 8. y = clip([h|A0|A1] @ WCOMB + b_ou)
    gemm_bf16<<<dim3(32, 4), 256, 0, stream>>>(
        HCAT, 1024, WCOMB, 1024, b_ou, out, nullptr, 512, 512, 1024, 1);

    // 9. m_t
    k_mem<<<2048, 256, 0, stream>>>(
        m0, ws + OFF_AT, ws + OFF_ERA, ws + OFF_ADD, out + (size_t)Bn * Un);
}

// Round 8
// 202.783 us; speedup vs baseline: 2.3481x; 1.0143x over previous
//
#include <hip/hip_runtime.h>
#include <math.h>

static constexpr int Bn = 2048;   // batch
static constexpr int Nn = 256;    // memory locations
static constexpr int Mn = 128;    // memory width
static constexpr int Un = 512;    // units

// Workspace layout (f32 offsets)
static constexpr size_t OFF_MNORM = 4608;     // 256
static constexpr size_t OFF_APREV = 4864;     // 1024
static constexpr size_t OFF_BIASH = 5888;     // 1152
static constexpr size_t OFF_KMAT  = 16384;                          // f32 [8192][256]
static constexpr size_t OFF_HEADS = OFF_KMAT + (size_t)8192 * 256;  // f32 [2048][1048]
static constexpr size_t OFF_XHB   = OFF_HEADS + (size_t)2048 * 1048;// bf16 [2048][1024]
static constexpr size_t OFF_HCAT  = OFF_XHB + 524288;               // bf16 [2048][1024]
static constexpr size_t OFF_W0T   = OFF_HCAT + 524288;              // bf16 [2048][512]
static constexpr size_t OFF_W1T   = OFF_W0T + 524288;               // bf16 [2048][1024]
static constexpr size_t OFF_WRWT  = OFF_W1T + 1048576;              // bf16 [1152][512]
static constexpr size_t OFF_WCOMB = OFF_WRWT + 294912;              // bf16 [512][1024]
static constexpr size_t OFF_WR2T  = OFF_WCOMB + 262144;             // bf16 [512][256]
static constexpr size_t OFF_M0B   = OFF_WR2T + 65536;               // bf16 [256][128]
static constexpr size_t OFF_ZPART = OFF_M0B + 16384 + 524288;       // f32 [2][8][2048]

// k_prep block-range dispatch table
static constexpr int S_X0  = 0;            // cvt8 X        (512)
static constexpr int S_M0  = 512;          // cvt8 m0       (16)
static constexpr int S_W0  = 528;          // cvtT W0 gate  (64x16)
static constexpr int S_W1  = 1552;         // cvtT W1 gate  (64x32)
static constexpr int S_WR  = 3600;         // cvtT W_r      (9x16)
static constexpr int S_WW  = 3744;         // cvtT W_w      (25x16)
static constexpr int S_WOU = 4144;         // cvtT W_ou h   (16x16)
static constexpr int S_WR2 = 4400;         // cvtT W_ou r   (16x8)
static constexpr int S_CA  = 4528;         // const-a       (1)
static constexpr int S_ZC  = 4529;         // zc partials   (128)
static constexpr int S_END = 4657;

#define DEV __device__ __forceinline__

typedef __attribute__((ext_vector_type(8))) short bf16x8;
typedef __attribute__((ext_vector_type(4))) float f32x4;
typedef __attribute__((ext_vector_type(8))) unsigned short ushort8;
typedef unsigned int u32;

DEV float sigf(float x) { return 1.0f / (1.0f + expf(-x)); }
DEV float softplusf(float x) { return x > 20.0f ? x : log1pf(expf(x)); }
DEV unsigned short f2bf(float f) {   // RNE float->bf16
    unsigned u = __float_as_uint(f);
    u = (u + 0x7FFFu + ((u >> 16) & 1u)) >> 16;
    return (unsigned short)u;
}
DEV void gload16(const unsigned short* g, unsigned short* l) {
    __builtin_amdgcn_global_load_lds(
        (const __attribute__((address_space(1))) u32*)g,
        (__attribute__((address_space(3))) u32*)l, 16, 0, 0);
}

DEV float blk_reduce_max(float v, float* red) {
    int tid = threadIdx.x;
    red[tid] = v; __syncthreads();
    for (int s = (int)blockDim.x >> 1; s > 0; s >>= 1) {
        if (tid < s) red[tid] = fmaxf(red[tid], red[tid + s]);
        __syncthreads();
    }
    float r = red[0]; __syncthreads();
    return r;
}
DEV float blk_reduce_sum(float v, float* red) {
    int tid = threadIdx.x;
    red[tid] = v; __syncthreads();
    for (int s = (int)blockDim.x >> 1; s > 0; s >>= 1) {
        if (tid < s) red[tid] += red[tid + s];
        __syncthreads();
    }
    float r = red[0]; __syncthreads();
    return r;
}

// ===========================================================================
// GEMM: 64x128 tile (M x N), 4 waves (2x2), BK=64, double-buffered LDS via
// global_load_lds (16B), XOR-swizzled via pre-swizzled source k-offset.
// T4 mainloop: counted vmcnt (never drain in-loop) + raw s_barrier pair.
// A bf16 [M][lda], Wt bf16 [N][ldw] (weights pre-transposed).
// ===========================================================================
#define GEMM_STAGE(buf, k0)                                                     \
    {                                                                           \
        _Pragma("unroll")                                                       \
        for (int q = 0; q < 2; ++q)                                             \
            gload16(A  + (size_t)(row0 + q * 32 + (tid >> 3)) * lda + (k0) + ke,\
                    &As[buf][q * 2048 + tid * 8]);                              \
        _Pragma("unroll")                                                       \
        for (int q = 0; q < 4; ++q)                                             \
            gload16(Wt + (size_t)(col0 + q * 32 + (tid >> 3)) * ldw + (k0) + ke,\
                    &Ws[buf][q * 2048 + tid * 8]);                              \
    }

#define GEMM_PROLOG                                                             \
    __shared__ __align__(16) unsigned short As[2][64 * 64];                     \
    __shared__ __align__(16) unsigned short Ws[2][128 * 64];                    \
    const int tid  = threadIdx.x;                                               \
    const int lane = tid & 63;                                                  \
    const int wave = tid >> 6;                                                  \
    const int wr = wave >> 1, wc = wave & 1;                                    \
    const int row0 = blockIdx.x * 64;                                           \
    const int col0 = blockIdx.y * 128;                                          \
    const int ke = ((tid & 7) * 8) ^ (((tid >> 3) & 7) << 3);                   \
    const int frow = lane & 15;                                                 \
    const int fko  = (lane >> 4) * 8;                                           \
    const int fxm  = (frow & 7) << 3;                                           \
    f32x4 acc[2][4];                                                            \
    _Pragma("unroll")                                                           \
    for (int i = 0; i < 2; ++i)                                                 \
        _Pragma("unroll")                                                       \
        for (int j = 0; j < 4; ++j) acc[i][j] = (f32x4){0.f, 0.f, 0.f, 0.f};

#define GEMM_FRAGS_AND_MFMA(Ab, Wb)                                             \
    {                                                                           \
        bf16x8 af[2][2], wf[2][4];                                              \
        _Pragma("unroll")                                                       \
        for (int kk = 0; kk < 2; ++kk) {                                        \
            _Pragma("unroll")                                                   \
            for (int i = 0; i < 2; ++i) {                                       \
                int fr = wr * 32 + i * 16 + frow;                               \
                af[kk][i] = *(const bf16x8*)&(Ab)[fr * 64 + ((kk * 32 + fko) ^ fxm)]; \
            }                                                                   \
            _Pragma("unroll")                                                   \
            for (int j = 0; j < 4; ++j) {                                       \
                int fr = wc * 64 + j * 16 + frow;                               \
                wf[kk][j] = *(const bf16x8*)&(Wb)[fr * 64 + ((kk * 32 + fko) ^ fxm)]; \
            }                                                                   \
        }                                                                       \
        __builtin_amdgcn_s_setprio(1);                                          \
        _Pragma("unroll")                                                       \
        for (int kk = 0; kk < 2; ++kk)                                          \
            _Pragma("unroll")                                                   \
            for (int i = 0; i < 2; ++i)                                         \
                _Pragma("unroll")                                               \
                for (int j = 0; j < 4; ++j)                                     \
                    acc[i][j] = __builtin_amdgcn_mfma_f32_16x16x32_bf16(        \
                        af[kk][i], wf[kk][j], acc[i][j], 0, 0, 0);              \
        __builtin_amdgcn_s_setprio(0);                                          \
    }

// T4: issue next-tile stage, wait only for the CURRENT tile's 6 loads
// (vmcnt(6) leaves the 6 newer in flight), raw barrier, compute, barrier.
#define GEMM_MAINLOOP(Kr)                                                       \
    {                                                                           \
        const int nt = (Kr) >> 6;                                               \
        int cur = 0;                                                            \
        GEMM_STAGE(0, 0);                                                       \
        for (int t = 0; t < nt; ++t) {                                          \
            if (t + 1 < nt) {                                                   \
                GEMM_STAGE(cur ^ 1, (t + 1) * 64);                              \
                asm volatile("s_waitcnt vmcnt(6)" ::: "memory");                \
            } else {                                                            \
                asm volatile("s_waitcnt vmcnt(0)" ::: "memory");                \
            }                                                                   \
            __builtin_amdgcn_sched_barrier(0);                                  \
            __builtin_amdgcn_s_barrier();                                       \
            __builtin_amdgcn_sched_barrier(0);                                  \
            GEMM_FRAGS_AND_MFMA(As[cur], Ws[cur]);                              \
            __builtin_amdgcn_sched_barrier(0);                                  \
            __builtin_amdgcn_s_barrier();                                       \
            cur ^= 1;                                                           \
        }                                                                       \
    }

// Generic GEMM. epi: 0=f32 out(+bias), 1=f32+bias+clip, 2=bf16 out (Cb)
__global__ __launch_bounds__(256) void gemm_bf16(
    const unsigned short* __restrict__ A, int lda,
    const unsigned short* __restrict__ Wt, int ldw,
    const float* __restrict__ bias,
    float* __restrict__ C, unsigned short* __restrict__ Cb, int ldc,
    int Nr, int Kr, int epi)
{
    GEMM_PROLOG
    GEMM_MAINLOOP(Kr)
    #pragma unroll
    for (int i = 0; i < 2; ++i) {
        int m0r = row0 + wr * 32 + i * 16 + (lane >> 4) * 4;
        #pragma unroll
        for (int j = 0; j < 4; ++j) {
            int n = col0 + wc * 64 + j * 16 + (lane & 15);
            if (n >= Nr) continue;
            float bv = bias ? bias[n] : 0.f;
            #pragma unroll
            for (int r = 0; r < 4; ++r) {
                float v = acc[i][j][r] + bv;
                if (epi == 1) v = fminf(fmaxf(v, -20.f), 20.f);
                if (epi == 2) Cb[(size_t)(m0r + r) * ldc + n] = f2bf(v);
                else          C [(size_t)(m0r + r) * ldc + n] = v;
            }
        }
    }
}

// P-fold GEMM: z = blockIdx.z selects read head; A = WR2T + z*128 (k slice),
// out = WCOMB cols 512 + z*256. K=128, bf16 out.
__global__ __launch_bounds__(256) void gemm_pfold(
    const unsigned short* __restrict__ WR2T,
    const unsigned short* __restrict__ M0B,
    unsigned short* __restrict__ WCOMB)
{
    const unsigned short* A  = WR2T + blockIdx.z * 128;
    const unsigned short* Wt = M0B;
    const int lda = 256, ldw = 128;
    unsigned short* Cb = WCOMB + 512 + blockIdx.z * 256;
    GEMM_PROLOG
    GEMM_MAINLOOP(128)
    #pragma unroll
    for (int i = 0; i < 2; ++i) {
        int m0r = row0 + wr * 32 + i * 16 + (lane >> 4) * 4;
        #pragma unroll
        for (int j = 0; j < 4; ++j) {
            int n = col0 + wc * 64 + j * 16 + (lane & 15);
            #pragma unroll
            for (int r = 0; r < 4; ++r)
                Cb[(size_t)(m0r + r) * 1024 + n] = f2bf(acc[i][j][r]);
        }
    }
}

// LSTM GEMM: W columns gate-permuted (c = 64q+16g+uu -> orig col g*512+q*16+uu).
// Epilogue sums the 8 split-K constant partials + bias (fused zc reduce), then
// applies the cell nonlinearity, writes h (bf16).
__global__ __launch_bounds__(256) void gemm_lstm(
    const unsigned short* __restrict__ A, int lda,
    const unsigned short* __restrict__ Wt, int ldw,
    const float* __restrict__ zpart, const float* __restrict__ b_lstm,
    int z, const float* __restrict__ c0,
    unsigned short* __restrict__ hout, int ldh, int Kr, int doclip)
{
    GEMM_PROLOG
    GEMM_MAINLOOP(Kr)
    const int uu = lane & 15;
    const int q  = (col0 >> 6) + wc;
    const int uq = q * 16 + uu;                      // unit index
    const float c0v = c0[uq];
    float bg[4];
    #pragma unroll
    for (int g = 0; g < 4; ++g) {
        int j = g * 512 + q * 16 + uu;               // orig W_lstm column
        float a = b_lstm[z * 2048 + j];
        #pragma unroll
        for (int p = 0; p < 8; ++p)
            a += zpart[((size_t)z * 8 + p) * 2048 + j];
        bg[g] = a;
    }
    #pragma unroll
    for (int i = 0; i < 2; ++i) {
        int rbase = row0 + wr * 32 + i * 16 + (lane >> 4) * 4;
        #pragma unroll
        for (int r = 0; r < 4; ++r) {
            float ig = acc[i][0][r] + bg[0];
            float fg = acc[i][1][r] + bg[1];
            float gg = acc[i][2][r] + bg[2];
            float og = acc[i][3][r] + bg[3];
            float c = sigf(fg) * c0v + sigf(ig) * tanhf(gg);
            float h = sigf(og) * tanhf(c);
            if (doclip) h = fminf(fmaxf(h, -20.f), 20.f);
            hout[(size_t)(rbase + r) * ldh + uq] = f2bf(h);
        }
    }
}

// kmat GEMM with fused k-prep: A-operand = tanh(heads k-slices) computed
// on the fly; B-operand = M0B via global_load_lds. C = inner[b,i,n] f32.
__global__ __launch_bounds__(256) void gemm_kmat(
    const float* __restrict__ heads,
    const unsigned short* __restrict__ M0B,
    float* __restrict__ C)
{
    __shared__ __align__(16) unsigned short As[2][64 * 64];
    __shared__ __align__(16) unsigned short Ws[2][128 * 64];
    const int tid  = threadIdx.x;
    const int lane = tid & 63;
    const int wave = tid >> 6;
    const int wr = wave >> 1, wc = wave & 1;
    const int row0 = blockIdx.x * 64;
    const int col0 = blockIdx.y * 128;
    const int ke = ((tid & 7) * 8) ^ (((tid >> 3) & 7) << 3);
    const int frow = lane & 15;
    const int fko  = (lane >> 4) * 8;
    const int fxm  = (frow & 7) << 3;
    f32x4 acc[2][4];
    #pragma unroll
    for (int i = 0; i < 2; ++i)
        #pragma unroll
        for (int j = 0; j < 4; ++j) acc[i][j] = (f32x4){0.f, 0.f, 0.f, 0.f};

#define KMAT_STAGE(buf, k0)                                                     \
    {                                                                           \
        _Pragma("unroll")                                                       \
        for (int q = 0; q < 2; ++q) {                                           \
            int R = row0 + q * 32 + (tid >> 3);                                 \
            int b = R >> 2, ih = R & 3;                                         \
            int cb = (ih < 2) ? ih * 134 : 268 + (ih - 2) * 390;                \
            const float* hp = heads + (size_t)b * 1048 + cb + (k0) + ke;        \
            ushort8 o;                                                          \
            _Pragma("unroll")                                                   \
            for (int j = 0; j < 8; ++j) o[j] = f2bf(tanhf(hp[j]));              \
            *(ushort8*)&As[buf][q * 2048 + tid * 8] = o;                        \
        }                                                                       \
        _Pragma("unroll")                                                       \
        for (int q = 0; q < 4; ++q)                                             \
            gload16(M0B + (size_t)(col0 + q * 32 + (tid >> 3)) * 128 + (k0) + ke,\
                    &Ws[buf][q * 2048 + tid * 8]);                              \
    }

    int cur = 0;
    KMAT_STAGE(0, 0);
    for (int t = 0; t < 2; ++t) {
        __syncthreads();
        if (t == 0) KMAT_STAGE(1, 64);
        GEMM_FRAGS_AND_MFMA(As[cur], Ws[cur]);
        cur ^= 1;
    }
#undef KMAT_STAGE
    #pragma unroll
    for (int i = 0; i < 2; ++i) {
        int m0r = row0 + wr * 32 + i * 16 + (lane >> 4) * 4;
        #pragma unroll
        for (int j = 0; j < 4; ++j) {
            int n = col0 + wc * 64 + j * 16 + (lane & 15);
            #pragma unroll
            for (int r = 0; r < 4; ++r)
                C[(size_t)(m0r + r) * 256 + n] = acc[i][j][r];
        }
    }
}

// ===========================================================================
// k_prep: all independent prep work in ONE launch (block-range dispatch).
// ===========================================================================
DEV void dev_cvt8(const float* src, int lds, unsigned short* dst, int ldd,
                  int c8, int bloc, int tid)
{
    size_t idx = (size_t)bloc * 256 + tid;
    size_t r = idx / c8, c = (idx % c8) * 8;
    const float* s = src + r * lds + c;
    float4 v0 = *(const float4*)s;
    float4 v1 = *(const float4*)(s + 4);
    ushort8 o;
    o[0] = f2bf(v0.x); o[1] = f2bf(v0.y); o[2] = f2bf(v0.z); o[3] = f2bf(v0.w);
    o[4] = f2bf(v1.x); o[5] = f2bf(v1.y); o[6] = f2bf(v1.z); o[7] = f2bf(v1.w);
    *(ushort8*)(dst + r * ldd + c) = o;
}

DEV void dev_cvtT(const float* src, int R, int C, int lds,
                  unsigned short* dst, int ldd, int mode, int bx, int by,
                  int tid, float* t /*32x33*/)
{
    const int x = tid & 31;
    for (int y = tid >> 5; y < 32; y += 8) {
        int r = by * 32 + y, c = bx * 32 + x;
        int scol = c;
        if (mode) scol = ((c >> 4) & 3) * 512 + (c >> 6) * 16 + (c & 15);
        t[y * 33 + x] = (r < R && c < C) ? src[(size_t)r * lds + scol] : 0.f;
    }
    __syncthreads();
    for (int y = tid >> 5; y < 32; y += 8) {
        int c = bx * 32 + y, r = by * 32 + x;
        if (c < C && r < R) dst[(size_t)c * ldd + r] = f2bf(t[x * 33 + y]);
    }
}

__global__ __launch_bounds__(256) void k_prep(
    const float* __restrict__ X, const float* __restrict__ m0,
    const float* __restrict__ H0, const float* __restrict__ R0,
    const float* __restrict__ A0, const float* __restrict__ W_prep,
    const float* __restrict__ b_prep, const float* __restrict__ W_lstm,
    const float* __restrict__ W_r, const float* __restrict__ b_r,
    const float* __restrict__ W_w, const float* __restrict__ b_w,
    const float* __restrict__ W_ou, float* __restrict__ ws)
{
    __shared__ float sh[32 * 33 + 64];
    const int bid = blockIdx.x, tid = threadIdx.x;
    unsigned short* XHB   = (unsigned short*)(ws + OFF_XHB);
    unsigned short* W0T   = (unsigned short*)(ws + OFF_W0T);
    unsigned short* W1T   = (unsigned short*)(ws + OFF_W1T);
    unsigned short* WRWT  = (unsigned short*)(ws + OFF_WRWT);
    unsigned short* WCOMB = (unsigned short*)(ws + OFF_WCOMB);
    unsigned short* WR2T  = (unsigned short*)(ws + OFF_WR2T);
    unsigned short* M0B   = (unsigned short*)(ws + OFF_M0B);

    if (bid < S_M0) {
        dev_cvt8(X, 512, XHB, 1024, 64, bid - S_X0, tid);
    } else if (bid < S_W0) {
        dev_cvt8(m0, 128, M0B, 128, 16, bid - S_M0, tid);
    } else if (bid < S_W1) {
        int s = bid - S_W0;
        dev_cvtT(W_lstm, 512, 2048, 2048, W0T, 512, 1, s & 63, s >> 6, tid, sh);
    } else if (bid < S_WR) {
        int s = bid - S_W1;
        dev_cvtT(W_lstm + (size_t)1536 * 2048, 1024, 2048, 2048, W1T, 1024, 1,
                 s & 63, s >> 6, tid, sh);
    } else if (bid < S_WW) {
        int s = bid - S_WR;
        dev_cvtT(W_r, 512, 268, 268, WRWT, 512, 0, s % 9, s / 9, tid, sh);
    } else if (bid < S_WOU) {
        int s = bid - S_WW;
        dev_cvtT(W_w, 512, 780, 780, WRWT + (size_t)268 * 512, 512, 0,
                 s % 25, s / 25, tid, sh);
    } else if (bid < S_WR2) {
        int s = bid - S_WOU;
        dev_cvtT(W_ou, 512, 512, 512, WCOMB, 1024, 0, s & 15, s >> 4, tid, sh);
    } else if (bid < S_CA) {
        int s = bid - S_WR2;
        dev_cvtT(W_ou + (size_t)512 * 512, 256, 512, 512, WR2T, 256, 0,
                 s & 15, s >> 4, tid, sh);
    } else if (bid < S_ZC) {
        // constants: aprev softmax, m_norm, head bias
        float* red = sh;
        for (int i = 0; i < 4; ++i) {
            float v = A0[i * 256 + tid];
            float mx = blk_reduce_max(v, red);
            float e = expf(v - mx);
            float s = blk_reduce_sum(e, red);
            ws[OFF_APREV + i * 256 + tid] = e / s;
        }
        float acc = 0.f;
        for (int m = 0; m < 128; ++m) {
            float t = m0[(size_t)tid * 128 + m];
            acc = fmaf(t, t, acc);
        }
        ws[OFF_MNORM + tid] = sqrtf(acc);
        for (int j = tid; j < 1152; j += 256)
            ws[OFF_BIASH + j] = (j < 268) ? b_r[j] : (j < 1048 ? b_w[j - 268] : 0.f);
    } else {
        // split-K partials for z0c/z1c (coalesced W_lstm rows, orig col order)
        int sub = bid - S_ZC;
        int colb = sub & 7, up = (sub >> 3) & 7, z = sub >> 6;
        int j = colb * 256 + tid;
        float acc = 0.f;
        if (z == 0) {
            if (up < 4) {
                sh[256 + tid] = tanhf(R0[tid]);
                __syncthreads();
                if (tid < 128) {
                    int u = up * 128 + tid;
                    float a = b_prep[u];
                    for (int k = 0; k < 256; ++k)
                        a = fmaf(sh[256 + k], W_prep[(size_t)k * 512 + u], a);
                    sh[tid] = a;
                }
                __syncthreads();
                const int u0 = up * 128;
                #pragma unroll 4
                for (int t = 0; t < 128; ++t)
                    acc = fmaf(sh[t], W_lstm[(size_t)(512 + u0 + t) * 2048 + j], acc);
            } else {
                const int u0 = up * 128;
                #pragma unroll 4
                for (int t = 0; t < 128; ++t)
                    acc = fmaf(H0[u0 - 512 + t],
                               W_lstm[(size_t)(512 + u0 + t) * 2048 + j], acc);
            }
        } else {
            const int u0 = up * 64;
            const float* W1 = W_lstm + (size_t)1536 * 2048;
            #pragma unroll 4
            for (int t = 0; t < 64; ++t)
                acc = fmaf(H0[512 + u0 + t], W1[(size_t)(1024 + u0 + t) * 2048 + j], acc);
        }
        (ws + OFF_ZPART)[((size_t)z * 8 + up) * 2048 + j] = acc;
    }
}

// Addressing for READ heads only -> A (bf16 into HCAT). grid (Bn, 2).
__global__ __launch_bounds__(256) void k_addr(
    const float* __restrict__ heads, const float* __restrict__ kmat,
    const float* __restrict__ mnorm, const float* __restrict__ aprev,
    unsigned short* __restrict__ hcat)
{
    __shared__ float red[256];
    __shared__ float wgs[256];
    __shared__ float sc[6];
    const int b = blockIdx.x, i = blockIdx.y, tid = threadIdx.x;
    const float* hd = heads + (size_t)b * 1048 + i * 134;
    float kv = (tid < 128) ? tanhf(hd[tid]) : 0.f;
    float kn = sqrtf(blk_reduce_sum(kv * kv, red));
    if (tid == 0) {
        sc[0] = softplusf(hd[128]);
        sc[1] = sigf(hd[129]);
        float v0 = hd[130], v1 = hd[131], v2 = hd[132];
        float mx = fmaxf(v0, fmaxf(v1, v2));
        float e0 = expf(v0 - mx), e1 = expf(v1 - mx), e2 = expf(v2 - mx);
        float ssum = e0 + e1 + e2;
        sc[2] = e0 / ssum; sc[3] = e1 / ssum; sc[4] = e2 / ssum;
        sc[5] = softplusf(hd[133]);
    }
    __syncthreads();
    const float beta = sc[0], g = sc[1], s0 = sc[2], s1 = sc[3], s2 = sc[4],
                gamma = sc[5];
    float inner = kmat[((size_t)b * 4 + i) * 256 + tid];
    float K = inner / (kn * mnorm[tid] + 1e-8f);
    float x = beta * K;
    float mx = blk_reduce_max(x, red);
    float e = expf(x - mx);
    float se = blk_reduce_sum(e, red);
    float wc = e / se;
    float wg = g * wc + (1.f - g) * aprev[i * 256 + tid];
    wgs[tid] = wg;
    __syncthreads();
    float wconv = s0 * wg + s1 * wgs[(tid + 255) & 255] + s2 * wgs[(tid + 1) & 255];
    float wsh = powf(wconv, gamma);
    float ssum = blk_reduce_sum(wsh, red);
    hcat[(size_t)b * 1024 + 512 + i * 256 + tid] = f2bf(wsh / ssum);
}

// m_t: per-block b, compute WRITE-head addressing + erase/add in LDS, then
// stream the 256x128 memory update for this batch row. Fuses old k_addr(i>=2).
__global__ __launch_bounds__(256) void k_mem(
    const float* __restrict__ m0, const float* __restrict__ heads,
    const float* __restrict__ kmat, const float* __restrict__ mnorm,
    const float* __restrict__ aprev, float* __restrict__ outm)
{
    __shared__ float red[256];
    __shared__ float wgs[256];
    __shared__ float sc[6];
    __shared__ __align__(16) float at_s[2][256];
    __shared__ __align__(16) float er_s[2][128];
    __shared__ __align__(16) float ad_s[2][128];
    const int b = blockIdx.x, tid = threadIdx.x;

    for (int ii = 0; ii < 2; ++ii) {
        const int i = 2 + ii;
        const float* hd = heads + (size_t)b * 1048 + 268 + ii * 390;
        float kv = (tid < 128) ? tanhf(hd[tid]) : 0.f;
        float kn = sqrtf(blk_reduce_sum(kv * kv, red));
        if (tid < 128) {
            er_s[ii][tid] = sigf(hd[134 + tid]);
            ad_s[ii][tid] = tanhf(hd[262 + tid]);
        }
        if (tid == 0) {
            sc[0] = softplusf(hd[128]);
            sc[1] = sigf(hd[129]);
            float v0 = hd[130], v1 = hd[131], v2 = hd[132];
            float mx = fmaxf(v0, fmaxf(v1, v2));
            float e0 = expf(v0 - mx), e1 = expf(v1 - mx), e2 = expf(v2 - mx);
            float ssum = e0 + e1 + e2;
            sc[2] = e0 / ssum; sc[3] = e1 / ssum; sc[4] = e2 / ssum;
            sc[5] = softplusf(hd[133]);
        }
        __syncthreads();
        const float beta = sc[0], g = sc[1], s0 = sc[2], s1 = sc[3],
                    s2 = sc[4], gamma = sc[5];
        float inner = kmat[((size_t)b * 4 + i) * 256 + tid];
        float K = inner / (kn * mnorm[tid] + 1e-8f);
        float x = beta * K;
        float mx = blk_reduce_max(x, red);
        float e = expf(x - mx);
        float se = blk_reduce_sum(e, red);
        float wc = e / se;
        float wg = g * wc + (1.f - g) * aprev[i * 256 + tid];
        wgs[tid] = wg;
        __syncthreads();
        float wconv = s0 * wg + s1 * wgs[(tid + 255) & 255] + s2 * wgs[(tid + 1) & 255];
        float wsh = powf(wconv, gamma);
        float ssum = blk_reduce_sum(wsh, red);
        at_s[ii][tid] = wsh / ssum;
        __syncthreads();
    }

    // streaming update for batch b
    const float4* m0v = (const float4*)m0;
    float4* outv = (float4*)outm + (size_t)b * 8192;
    for (int idx = tid; idx < 8192; idx += 256) {
        int mq = idx & 31, n = idx >> 5;
        float4 t = m0v[n * 32 + mq];
        float w0 = at_s[0][n], w1 = at_s[1][n];
        float4 e0 = *(const float4*)&er_s[0][mq * 4];
        float4 a0 = *(const float4*)&ad_s[0][mq * 4];
        float4 e1 = *(const float4*)&er_s[1][mq * 4];
        float4 a1 = *(const float4*)&ad_s[1][mq * 4];
#define UPD(c) { t.c = t.c * (1.f - w0 * e0.c) + w0 * a0.c; \
                 t.c = t.c * (1.f - w1 * e1.c) + w1 * a1.c; }
        UPD(x) UPD(y) UPD(z) UPD(w)
#undef UPD
        outv[idx] = t;
    }
}

extern "C" void kernel_launch(void* const* d_in, const int* in_sizes, int n_in,
                              void* d_out, int out_size, void* d_ws, size_t ws_size,
                              hipStream_t stream)
{
    const float* X      = (const float*)d_in[0];
    const float* m0     = (const float*)d_in[1];
    const float* H0     = (const float*)d_in[2];
    const float* C0     = (const float*)d_in[3];
    const float* R0     = (const float*)d_in[4];
    const float* A0     = (const float*)d_in[5];
    const float* W_prep = (const float*)d_in[6];
    const float* b_prep = (const float*)d_in[7];
    const float* W_lstm = (const float*)d_in[8];
    const float* b_lstm = (const float*)d_in[9];
    const float* W_r    = (const float*)d_in[10];
    const float* b_r    = (const float*)d_in[11];
    const float* W_w    = (const float*)d_in[12];
    const float* b_w    = (const float*)d_in[13];
    const float* W_ou   = (const float*)d_in[14];
    const float* b_ou   = (const float*)d_in[15];
    float* ws  = (float*)d_ws;
    float* out = (float*)d_out;

    unsigned short* XHB   = (unsigned short*)(ws + OFF_XHB);
    unsigned short* HCAT  = (unsigned short*)(ws + OFF_HCAT);
    unsigned short* W0T   = (unsigned short*)(ws + OFF_W0T);
    unsigned short* W1T   = (unsigned short*)(ws + OFF_W1T);
    unsigned short* WRWT  = (unsigned short*)(ws + OFF_WRWT);
    unsigned short* WCOMB = (unsigned short*)(ws + OFF_WCOMB);
    unsigned short* WR2T  = (unsigned short*)(ws + OFF_WR2T);
    unsigned short* M0B   = (unsigned short*)(ws + OFF_M0B);

    // 1. all prep in one launch
    k_prep<<<S_END, 256, 0, stream>>>(
        X, m0, H0, R0, A0, W_prep, b_prep, W_lstm, W_r, b_r, W_w, b_w, W_ou, ws);

    // 2. both P-folds in one dispatch
    gemm_pfold<<<dim3(8, 2, 2), 256, 0, stream>>>(WR2T, M0B, WCOMB);

    // 3-4. LSTM (fused gates + fused zc reduce)
    gemm_lstm<<<dim3(32, 16), 256, 0, stream>>>(
        XHB, 1024, W0T, 512, ws + OFF_ZPART, b_lstm, 0, C0, XHB + 512, 1024, 512, 0);
    gemm_lstm<<<dim3(32, 16), 256, 0, stream>>>(
        XHB, 1024, W1T, 1024, ws + OFF_ZPART, b_lstm, 1, C0 + 512, HCAT, 1024, 1024, 1);

    // 5. heads
    gemm_bf16<<<dim3(32, 9), 256, 0, stream>>>(
        HCAT, 1024, WRWT, 512, ws + OFF_BIASH, ws + OFF_HEADS, nullptr, 1048, 1048, 512, 0);

    // 6. inner[b,i,n] = tanh(k) . m0[n]  (fused k-prep)
    gemm_kmat<<<dim3(128, 2), 256, 0, stream>>>(
        ws + OFF_HEADS, M0B, ws + OFF_KMAT);

    // 7. addressing for read heads -> HCAT
    k_addr<<<dim3(Bn, 2), 256, 0, stream>>>(
        ws + OFF_HEADS, ws + OFF_KMAT, ws + OFF_MNORM, ws + OFF_APREV, HCAT);

    // 8. y = clip([h|A0|A1] @ WCOMB + b_ou)
    gemm_bf16<<<dim3(32, 4), 256, 0, stream>>>(
        HCAT, 1024, WCOMB, 1024, b_ou, out, nullptr, 512, 512, 1024, 1);

    // 9. m_t (fused write-head addressing + erase/add + streaming update)
    k_mem<<<Bn, 256, 0, stream>>>(
        m0, ws + OFF_HEADS, ws + OFF_KMAT, ws + OFF_MNORM, ws + OFF_APREV,
        out + (size_t)Bn * Un);
}

// Round 9
// 185.259 us; speedup vs baseline: 2.5702x; 1.0946x over previous
//
#include <hip/hip_runtime.h>
#include <math.h>

static constexpr int Bn = 2048;   // batch
static constexpr int Nn = 256;    // memory locations
static constexpr int Mn = 128;    // memory width
static constexpr int Un = 512;    // units

// Workspace layout (f32 offsets)
static constexpr size_t OFF_MNORM = 4608;     // 256
static constexpr size_t OFF_APREV = 4864;     // 1024
static constexpr size_t OFF_BIASH = 5888;     // 1152
static constexpr size_t OFF_KMAT  = 16384;                           // f32 [8192][256]
static constexpr size_t OFF_HEADS = OFF_KMAT + (size_t)8192 * 256;   // f32 [2048][1048]
static constexpr size_t OFF_AT    = OFF_HEADS + (size_t)2048 * 1048; // f32 [2][2048][256]
static constexpr size_t OFF_ERA   = OFF_AT + (size_t)2 * 2048 * 256; // f32 [2048][2][128]
static constexpr size_t OFF_ADD   = OFF_ERA + (size_t)2048 * 256;
static constexpr size_t OFF_XHB   = OFF_ADD + (size_t)2048 * 256;    // bf16 [2048][1024]
static constexpr size_t OFF_HCAT  = OFF_XHB + 524288;                // bf16 [2048][1024]
static constexpr size_t OFF_W0T   = OFF_HCAT + 524288;               // bf16 [2048][512]
static constexpr size_t OFF_W1T   = OFF_W0T + 524288;                // bf16 [2048][1024]
static constexpr size_t OFF_WRWT  = OFF_W1T + 1048576;               // bf16 [1152][512]
static constexpr size_t OFF_WCOMB = OFF_WRWT + 294912;               // bf16 [512][1024]
static constexpr size_t OFF_WR2T  = OFF_WCOMB + 262144;              // bf16 [512][256]
static constexpr size_t OFF_M0B   = OFF_WR2T + 65536;                // bf16 [256][128]
static constexpr size_t OFF_ZPART = OFF_M0B + 16384 + 524288;        // f32 [2][8][2048]

// k_prep block-range dispatch table
static constexpr int S_X0  = 0;            // cvt8 X        (512)
static constexpr int S_M0  = 512;          // cvt8 m0       (16)
static constexpr int S_W0  = 528;          // cvtT W0 gate  (64x16)
static constexpr int S_W1  = 1552;         // cvtT W1 gate  (64x32)
static constexpr int S_WR  = 3600;         // cvtT W_r      (9x16)
static constexpr int S_WW  = 3744;         // cvtT W_w      (25x16)
static constexpr int S_WOU = 4144;         // cvtT W_ou h   (16x16)
static constexpr int S_WR2 = 4400;         // cvtT W_ou r   (16x8)
static constexpr int S_CA  = 4528;         // const-a       (1)
static constexpr int S_ZC  = 4529;         // zc partials   (128)
static constexpr int S_END = 4657;

#define DEV __device__ __forceinline__

typedef __attribute__((ext_vector_type(8))) short bf16x8;
typedef __attribute__((ext_vector_type(4))) float f32x4;
typedef __attribute__((ext_vector_type(8))) unsigned short ushort8;
typedef unsigned int u32;

DEV float sigf(float x) { return 1.0f / (1.0f + expf(-x)); }
DEV float softplusf(float x) { return x > 20.0f ? x : log1pf(expf(x)); }
DEV unsigned short f2bf(float f) {   // RNE float->bf16
    unsigned u = __float_as_uint(f);
    u = (u + 0x7FFFu + ((u >> 16) & 1u)) >> 16;
    return (unsigned short)u;
}
DEV void gload16(const unsigned short* g, unsigned short* l) {
    __builtin_amdgcn_global_load_lds(
        (const __attribute__((address_space(1))) u32*)g,
        (__attribute__((address_space(3))) u32*)l, 16, 0, 0);
}

// tree reductions (used in k_prep only)
DEV float blk_reduce_max(float v, float* red) {
    int tid = threadIdx.x;
    red[tid] = v; __syncthreads();
    for (int s = (int)blockDim.x >> 1; s > 0; s >>= 1) {
        if (tid < s) red[tid] = fmaxf(red[tid], red[tid + s]);
        __syncthreads();
    }
    float r = red[0]; __syncthreads();
    return r;
}
DEV float blk_reduce_sum(float v, float* red) {
    int tid = threadIdx.x;
    red[tid] = v; __syncthreads();
    for (int s = (int)blockDim.x >> 1; s > 0; s >>= 1) {
        if (tid < s) red[tid] += red[tid + s];
        __syncthreads();
    }
    float r = red[0]; __syncthreads();
    return r;
}

// wave-shuffle reductions for 256-thread blocks (4 waves, 2 barriers)
DEV float wv_sum(float v) {
    #pragma unroll
    for (int off = 32; off; off >>= 1) v += __shfl_xor(v, off);
    return v;
}
DEV float wv_max(float v) {
    #pragma unroll
    for (int off = 32; off; off >>= 1) v = fmaxf(v, __shfl_xor(v, off));
    return v;
}
DEV float blk_sum4(float v, float* red4) {
    v = wv_sum(v);
    int w = threadIdx.x >> 6;
    if ((threadIdx.x & 63) == 0) red4[w] = v;
    __syncthreads();
    float r = red4[0] + red4[1] + red4[2] + red4[3];
    __syncthreads();
    return r;
}
DEV float blk_max4(float v, float* red4) {
    v = wv_max(v);
    int w = threadIdx.x >> 6;
    if ((threadIdx.x & 63) == 0) red4[w] = v;
    __syncthreads();
    float r = fmaxf(fmaxf(red4[0], red4[1]), fmaxf(red4[2], red4[3]));
    __syncthreads();
    return r;
}

// ===========================================================================
// GEMM: 64x128 tile (M x N), 4 waves (2x2), BK=64, double-buffered LDS via
// global_load_lds (16B), XOR-swizzled via pre-swizzled source k-offset.
// T4 mainloop: counted vmcnt + raw s_barrier pair.
// ===========================================================================
#define GEMM_STAGE(buf, k0)                                                     \
    {                                                                           \
        _Pragma("unroll")                                                       \
        for (int q = 0; q < 2; ++q)                                             \
            gload16(A  + (size_t)(row0 + q * 32 + (tid >> 3)) * lda + (k0) + ke,\
                    &As[buf][q * 2048 + tid * 8]);                              \
        _Pragma("unroll")                                                       \
        for (int q = 0; q < 4; ++q)                                             \
            gload16(Wt + (size_t)(col0 + q * 32 + (tid >> 3)) * ldw + (k0) + ke,\
                    &Ws[buf][q * 2048 + tid * 8]);                              \
    }

#define GEMM_PROLOG_CORE                                                        \
    __shared__ __align__(16) unsigned short As[2][64 * 64];                     \
    __shared__ __align__(16) unsigned short Ws[2][128 * 64];                    \
    const int tid  = threadIdx.x;                                               \
    const int lane = tid & 63;                                                  \
    const int wave = tid >> 6;                                                  \
    const int wr = wave >> 1, wc = wave & 1;                                    \
    const int ke = ((tid & 7) * 8) ^ (((tid >> 3) & 7) << 3);                   \
    const int frow = lane & 15;                                                 \
    const int fko  = (lane >> 4) * 8;                                           \
    const int fxm  = (frow & 7) << 3;                                           \
    f32x4 acc[2][4];                                                            \
    _Pragma("unroll")                                                           \
    for (int i = 0; i < 2; ++i)                                                 \
        _Pragma("unroll")                                                       \
        for (int j = 0; j < 4; ++j) acc[i][j] = (f32x4){0.f, 0.f, 0.f, 0.f};

#define GEMM_PROLOG                                                             \
    GEMM_PROLOG_CORE                                                            \
    const int row0 = blockIdx.x * 64;                                           \
    const int col0 = blockIdx.y * 128;

#define GEMM_FRAGS_AND_MFMA(Ab, Wb)                                             \
    {                                                                           \
        bf16x8 af[2][2], wf[2][4];                                              \
        _Pragma("unroll")                                                       \
        for (int kk = 0; kk < 2; ++kk) {                                        \
            _Pragma("unroll")                                                   \
            for (int i = 0; i < 2; ++i) {                                       \
                int fr = wr * 32 + i * 16 + frow;                               \
                af[kk][i] = *(const bf16x8*)&(Ab)[fr * 64 + ((kk * 32 + fko) ^ fxm)]; \
            }                                                                   \
            _Pragma("unroll")                                                   \
            for (int j = 0; j < 4; ++j) {                                       \
                int fr = wc * 64 + j * 16 + frow;                               \
                wf[kk][j] = *(const bf16x8*)&(Wb)[fr * 64 + ((kk * 32 + fko) ^ fxm)]; \
            }                                                                   \
        }                                                                       \
        __builtin_amdgcn_s_setprio(1);                                          \
        _Pragma("unroll")                                                       \
        for (int kk = 0; kk < 2; ++kk)                                          \
            _Pragma("unroll")                                                   \
            for (int i = 0; i < 2; ++i)                                         \
                _Pragma("unroll")                                               \
                for (int j = 0; j < 4; ++j)                                     \
                    acc[i][j] = __builtin_amdgcn_mfma_f32_16x16x32_bf16(        \
                        af[kk][i], wf[kk][j], acc[i][j], 0, 0, 0);              \
        __builtin_amdgcn_s_setprio(0);                                          \
    }

#define GEMM_MAINLOOP(Kr)                                                       \
    {                                                                           \
        const int nt = (Kr) >> 6;                                               \
        int cur = 0;                                                            \
        GEMM_STAGE(0, 0);                                                       \
        for (int t = 0; t < nt; ++t) {                                          \
            if (t + 1 < nt) {                                                   \
                GEMM_STAGE(cur ^ 1, (t + 1) * 64);                              \
                asm volatile("s_waitcnt vmcnt(6)" ::: "memory");                \
            } else {                                                            \
                asm volatile("s_waitcnt vmcnt(0)" ::: "memory");                \
            }                                                                   \
            __builtin_amdgcn_sched_barrier(0);                                  \
            __builtin_amdgcn_s_barrier();                                       \
            __builtin_amdgcn_sched_barrier(0);                                  \
            GEMM_FRAGS_AND_MFMA(As[cur], Ws[cur]);                              \
            __builtin_amdgcn_sched_barrier(0);                                  \
            __builtin_amdgcn_s_barrier();                                       \
            cur ^= 1;                                                           \
        }                                                                       \
    }

// Generic GEMM. epi: 0=f32 out(+bias), 1=f32+bias+clip, 2=bf16 out (Cb)
__global__ __launch_bounds__(256) void gemm_bf16(
    const unsigned short* __restrict__ A, int lda,
    const unsigned short* __restrict__ Wt, int ldw,
    const float* __restrict__ bias,
    float* __restrict__ C, unsigned short* __restrict__ Cb, int ldc,
    int Nr, int Kr, int epi)
{
    GEMM_PROLOG
    GEMM_MAINLOOP(Kr)
    #pragma unroll
    for (int i = 0; i < 2; ++i) {
        int m0r = row0 + wr * 32 + i * 16 + (lane >> 4) * 4;
        #pragma unroll
        for (int j = 0; j < 4; ++j) {
            int n = col0 + wc * 64 + j * 16 + (lane & 15);
            if (n >= Nr) continue;
            float bv = bias ? bias[n] : 0.f;
            #pragma unroll
            for (int r = 0; r < 4; ++r) {
                float v = acc[i][j][r] + bv;
                if (epi == 1) v = fminf(fmaxf(v, -20.f), 20.f);
                if (epi == 2) Cb[(size_t)(m0r + r) * ldc + n] = f2bf(v);
                else          C [(size_t)(m0r + r) * ldc + n] = v;
            }
        }
    }
}

// LSTM layer-1 GEMM (gate-permuted W cols; fused zc reduce + cell nonlin).
__global__ __launch_bounds__(256) void gemm_lstm(
    const unsigned short* __restrict__ A, int lda,
    const unsigned short* __restrict__ Wt, int ldw,
    const float* __restrict__ zpart, const float* __restrict__ b_lstm,
    int z, const float* __restrict__ c0,
    unsigned short* __restrict__ hout, int ldh, int Kr, int doclip)
{
    GEMM_PROLOG
    GEMM_MAINLOOP(Kr)
    const int uu = lane & 15;
    const int q  = (col0 >> 6) + wc;
    const int uq = q * 16 + uu;
    const float c0v = c0[uq];
    float bg[4];
    #pragma unroll
    for (int g = 0; g < 4; ++g) {
        int j = g * 512 + q * 16 + uu;
        float a = b_lstm[z * 2048 + j];
        #pragma unroll
        for (int p = 0; p < 8; ++p)
            a += zpart[((size_t)z * 8 + p) * 2048 + j];
        bg[g] = a;
    }
    #pragma unroll
    for (int i = 0; i < 2; ++i) {
        int rbase = row0 + wr * 32 + i * 16 + (lane >> 4) * 4;
        #pragma unroll
        for (int r = 0; r < 4; ++r) {
            float ig = acc[i][0][r] + bg[0];
            float fg = acc[i][1][r] + bg[1];
            float gg = acc[i][2][r] + bg[2];
            float og = acc[i][3][r] + bg[3];
            float c = sigf(fg) * c0v + sigf(ig) * tanhf(gg);
            float h = sigf(og) * tanhf(c);
            if (doclip) h = fminf(fmaxf(h, -20.f), 20.f);
            hout[(size_t)(rbase + r) * ldh + uq] = f2bf(h);
        }
    }
}

// Merged LSTM layer-0 + P-fold dispatch. grid (32, 17):
//   y<16  : LSTM0 (A=XHB[:,0:512], W0T, K=512, z=0) -> h1 into XHB[:,512:]
//   y==16 : pfold, x decomposed (px=x&7, py=(x>>3)&1, pz=x>>4)
__global__ __launch_bounds__(256) void gemm_l0p(
    const unsigned short* __restrict__ XHB,
    const unsigned short* __restrict__ W0T,
    const unsigned short* __restrict__ WR2T,
    const unsigned short* __restrict__ M0B,
    const float* __restrict__ zpart, const float* __restrict__ b_lstm,
    const float* __restrict__ c0, unsigned short* __restrict__ hout,
    unsigned short* __restrict__ WCOMB)
{
    const int by = blockIdx.y, bx = blockIdx.x;
    const unsigned short *A, *Wt;
    int lda, ldw, row0, col0, Kr;
    unsigned short* pCb = nullptr;
    if (by < 16) {
        A = XHB;  lda = 1024; Wt = W0T; ldw = 512;
        row0 = bx * 64; col0 = by * 128; Kr = 512;
    } else {
        int pz = bx >> 4, py = (bx >> 3) & 1, px = bx & 7;
        A = WR2T + pz * 128; lda = 256; Wt = M0B; ldw = 128;
        row0 = px * 64; col0 = py * 128; Kr = 128;
        pCb = WCOMB + 512 + pz * 256;
    }
    GEMM_PROLOG_CORE
    GEMM_MAINLOOP(Kr)
    if (by < 16) {
        const int uu = lane & 15;
        const int q  = (col0 >> 6) + wc;
        const int uq = q * 16 + uu;
        const float c0v = c0[uq];
        float bg[4];
        #pragma unroll
        for (int g = 0; g < 4; ++g) {
            int j = g * 512 + q * 16 + uu;
            float a = b_lstm[j];
            #pragma unroll
            for (int p = 0; p < 8; ++p)
                a += zpart[(size_t)p * 2048 + j];
            bg[g] = a;
        }
        #pragma unroll
        for (int i = 0; i < 2; ++i) {
            int rbase = row0 + wr * 32 + i * 16 + (lane >> 4) * 4;
            #pragma unroll
            for (int r = 0; r < 4; ++r) {
                float ig = acc[i][0][r] + bg[0];
                float fg = acc[i][1][r] + bg[1];
                float gg = acc[i][2][r] + bg[2];
                float og = acc[i][3][r] + bg[3];
                float c = sigf(fg) * c0v + sigf(ig) * tanhf(gg);
                float h = sigf(og) * tanhf(c);
                hout[(size_t)(rbase + r) * 1024 + uq] = f2bf(h);
            }
        }
    } else {
        #pragma unroll
        for (int i = 0; i < 2; ++i) {
            int m0r = row0 + wr * 32 + i * 16 + (lane >> 4) * 4;
            #pragma unroll
            for (int j = 0; j < 4; ++j) {
                int n = col0 + wc * 64 + j * 16 + (lane & 15);
                #pragma unroll
                for (int r = 0; r < 4; ++r)
                    pCb[(size_t)(m0r + r) * 1024 + n] = f2bf(acc[i][j][r]);
            }
        }
    }
}

// kmat GEMM with fused k-prep (tanh on the fly)
__global__ __launch_bounds__(256) void gemm_kmat(
    const float* __restrict__ heads,
    const unsigned short* __restrict__ M0B,
    float* __restrict__ C)
{
    GEMM_PROLOG_CORE
    const int row0 = blockIdx.x * 64;
    const int col0 = blockIdx.y * 128;

#define KMAT_STAGE(buf, k0)                                                     \
    {                                                                           \
        _Pragma("unroll")                                                       \
        for (int q = 0; q < 2; ++q) {                                           \
            int R = row0 + q * 32 + (tid >> 3);                                 \
            int b = R >> 2, ih = R & 3;                                         \
            int cb = (ih < 2) ? ih * 134 : 268 + (ih - 2) * 390;                \
            const float* hp = heads + (size_t)b * 1048 + cb + (k0) + ke;        \
            ushort8 o;                                                          \
            _Pragma("unroll")                                                   \
            for (int j = 0; j < 8; ++j) o[j] = f2bf(tanhf(hp[j]));              \
            *(ushort8*)&As[buf][q * 2048 + tid * 8] = o;                        \
        }                                                                       \
        _Pragma("unroll")                                                       \
        for (int q = 0; q < 4; ++q)                                             \
            gload16(M0B + (size_t)(col0 + q * 32 + (tid >> 3)) * 128 + (k0) + ke,\
                    &Ws[buf][q * 2048 + tid * 8]);                              \
    }

    int cur = 0;
    KMAT_STAGE(0, 0);
    for (int t = 0; t < 2; ++t) {
        __syncthreads();
        if (t == 0) KMAT_STAGE(1, 64);
        GEMM_FRAGS_AND_MFMA(As[cur], Ws[cur]);
        cur ^= 1;
    }
#undef KMAT_STAGE
    #pragma unroll
    for (int i = 0; i < 2; ++i) {
        int m0r = row0 + wr * 32 + i * 16 + (lane >> 4) * 4;
        #pragma unroll
        for (int j = 0; j < 4; ++j) {
            int n = col0 + wc * 64 + j * 16 + (lane & 15);
            #pragma unroll
            for (int r = 0; r < 4; ++r)
                C[(size_t)(m0r + r) * 256 + n] = acc[i][j][r];
        }
    }
}

// ===========================================================================
// k_prep: all independent prep work in ONE launch (block-range dispatch).
// ===========================================================================
DEV void dev_cvt8(const float* src, int lds, unsigned short* dst, int ldd,
                  int c8, int bloc, int tid)
{
    size_t idx = (size_t)bloc * 256 + tid;
    size_t r = idx / c8, c = (idx % c8) * 8;
    const float* s = src + r * lds + c;
    float4 v0 = *(const float4*)s;
    float4 v1 = *(const float4*)(s + 4);
    ushort8 o;
    o[0] = f2bf(v0.x); o[1] = f2bf(v0.y); o[2] = f2bf(v0.z); o[3] = f2bf(v0.w);
    o[4] = f2bf(v1.x); o[5] = f2bf(v1.y); o[6] = f2bf(v1.z); o[7] = f2bf(v1.w);
    *(ushort8*)(dst + r * ldd + c) = o;
}

DEV void dev_cvtT(const float* src, int R, int C, int lds,
                  unsigned short* dst, int ldd, int mode, int bx, int by,
                  int tid, float* t /*32x33*/)
{
    const int x = tid & 31;
    for (int y = tid >> 5; y < 32; y += 8) {
        int r = by * 32 + y, c = bx * 32 + x;
        int scol = c;
        if (mode) scol = ((c >> 4) & 3) * 512 + (c >> 6) * 16 + (c & 15);
        t[y * 33 + x] = (r < R && c < C) ? src[(size_t)r * lds + scol] : 0.f;
    }
    __syncthreads();
    for (int y = tid >> 5; y < 32; y += 8) {
        int c = bx * 32 + y, r = by * 32 + x;
        if (c < C && r < R) dst[(size_t)c * ldd + r] = f2bf(t[x * 33 + y]);
    }
}

__global__ __launch_bounds__(256) void k_prep(
    const float* __restrict__ X, const float* __restrict__ m0,
    const float* __restrict__ H0, const float* __restrict__ R0,
    const float* __restrict__ A0, const float* __restrict__ W_prep,
    const float* __restrict__ b_prep, const float* __restrict__ W_lstm,
    const float* __restrict__ W_r, const float* __restrict__ b_r,
    const float* __restrict__ W_w, const float* __restrict__ b_w,
    const float* __restrict__ W_ou, float* __restrict__ ws)
{
    __shared__ float sh[32 * 33 + 64];
    const int bid = blockIdx.x, tid = threadIdx.x;
    unsigned short* XHB   = (unsigned short*)(ws + OFF_XHB);
    unsigned short* W0T   = (unsigned short*)(ws + OFF_W0T);
    unsigned short* W1T   = (unsigned short*)(ws + OFF_W1T);
    unsigned short* WRWT  = (unsigned short*)(ws + OFF_WRWT);
    unsigned short* WCOMB = (unsigned short*)(ws + OFF_WCOMB);
    unsigned short* WR2T  = (unsigned short*)(ws + OFF_WR2T);
    unsigned short* M0B   = (unsigned short*)(ws + OFF_M0B);

    if (bid < S_M0) {
        dev_cvt8(X, 512, XHB, 1024, 64, bid - S_X0, tid);
    } else if (bid < S_W0) {
        dev_cvt8(m0, 128, M0B, 128, 16, bid - S_M0, tid);
    } else if (bid < S_W1) {
        int s = bid - S_W0;
        dev_cvtT(W_lstm, 512, 2048, 2048, W0T, 512, 1, s & 63, s >> 6, tid, sh);
    } else if (bid < S_WR) {
        int s = bid - S_W1;
        dev_cvtT(W_lstm + (size_t)1536 * 2048, 1024, 2048, 2048, W1T, 1024, 1,
                 s & 63, s >> 6, tid, sh);
    } else if (bid < S_WW) {
        int s = bid - S_WR;
        dev_cvtT(W_r, 512, 268, 268, WRWT, 512, 0, s % 9, s / 9, tid, sh);
    } else if (bid < S_WOU) {
        int s = bid - S_WW;
        dev_cvtT(W_w, 512, 780, 780, WRWT + (size_t)268 * 512, 512, 0,
                 s % 25, s / 25, tid, sh);
    } else if (bid < S_WR2) {
        int s = bid - S_WOU;
        dev_cvtT(W_ou, 512, 512, 512, WCOMB, 1024, 0, s & 15, s >> 4, tid, sh);
    } else if (bid < S_CA) {
        int s = bid - S_WR2;
        dev_cvtT(W_ou + (size_t)512 * 512, 256, 512, 512, WR2T, 256, 0,
                 s & 15, s >> 4, tid, sh);
    } else if (bid < S_ZC) {
        float* red = sh;
        for (int i = 0; i < 4; ++i) {
            float v = A0[i * 256 + tid];
            float mx = blk_reduce_max(v, red);
            float e = expf(v - mx);
            float s = blk_reduce_sum(e, red);
            ws[OFF_APREV + i * 256 + tid] = e / s;
        }
        float acc = 0.f;
        for (int m = 0; m < 128; ++m) {
            float t = m0[(size_t)tid * 128 + m];
            acc = fmaf(t, t, acc);
        }
        ws[OFF_MNORM + tid] = sqrtf(acc);
        for (int j = tid; j < 1152; j += 256)
            ws[OFF_BIASH + j] = (j < 268) ? b_r[j] : (j < 1048 ? b_w[j - 268] : 0.f);
    } else {
        int sub = bid - S_ZC;
        int colb = sub & 7, up = (sub >> 3) & 7, z = sub >> 6;
        int j = colb * 256 + tid;
        float acc = 0.f;
        if (z == 0) {
            if (up < 4) {
                sh[256 + tid] = tanhf(R0[tid]);
                __syncthreads();
                if (tid < 128) {
                    int u = up * 128 + tid;
                    float a = b_prep[u];
                    for (int k = 0; k < 256; ++k)
                        a = fmaf(sh[256 + k], W_prep[(size_t)k * 512 + u], a);
                    sh[tid] = a;
                }
                __syncthreads();
                const int u0 = up * 128;
                #pragma unroll 4
                for (int t = 0; t < 128; ++t)
                    acc = fmaf(sh[t], W_lstm[(size_t)(512 + u0 + t) * 2048 + j], acc);
            } else {
                const int u0 = up * 128;
                #pragma unroll 4
                for (int t = 0; t < 128; ++t)
                    acc = fmaf(H0[u0 - 512 + t],
                               W_lstm[(size_t)(512 + u0 + t) * 2048 + j], acc);
            }
        } else {
            const int u0 = up * 64;
            const float* W1 = W_lstm + (size_t)1536 * 2048;
            #pragma unroll 4
            for (int t = 0; t < 64; ++t)
                acc = fmaf(H0[512 + u0 + t], W1[(size_t)(1024 + u0 + t) * 2048 + j], acc);
        }
        (ws + OFF_ZPART)[((size_t)z * 8 + up) * 2048 + j] = acc;
    }
}

// Addressing for all 4 heads (shuffle reductions). Read heads -> HCAT bf16;
// write heads -> at/era/add global.
__global__ __launch_bounds__(256) void k_addr(
    const float* __restrict__ heads, const float* __restrict__ kmat,
    const float* __restrict__ mnorm, const float* __restrict__ aprev,
    float* __restrict__ at, unsigned short* __restrict__ hcat,
    float* __restrict__ era, float* __restrict__ addv)
{
    __shared__ float red4[4];
    __shared__ float wgs[256];
    __shared__ float sc[6];
    const int b = blockIdx.x, i = blockIdx.y, tid = threadIdx.x;
    const int cb = (i < 2) ? i * 134 : 268 + (i - 2) * 390;
    const float* hd = heads + (size_t)b * 1048 + cb;
    float kv = (tid < 128) ? tanhf(hd[tid]) : 0.f;
    float kn = sqrtf(blk_sum4(kv * kv, red4));
    if (i >= 2 && tid < 128) {
        era [((size_t)b * 2 + (i - 2)) * 128 + tid] = sigf(hd[134 + tid]);
        addv[((size_t)b * 2 + (i - 2)) * 128 + tid] = tanhf(hd[262 + tid]);
    }
    if (tid == 0) {
        sc[0] = softplusf(hd[128]);
        sc[1] = sigf(hd[129]);
        float v0 = hd[130], v1 = hd[131], v2 = hd[132];
        float mx = fmaxf(v0, fmaxf(v1, v2));
        float e0 = expf(v0 - mx), e1 = expf(v1 - mx), e2 = expf(v2 - mx);
        float ssum = e0 + e1 + e2;
        sc[2] = e0 / ssum; sc[3] = e1 / ssum; sc[4] = e2 / ssum;
        sc[5] = softplusf(hd[133]);
    }
    __syncthreads();
    const float beta = sc[0], g = sc[1], s0 = sc[2], s1 = sc[3], s2 = sc[4],
                gamma = sc[5];
    float inner = kmat[((size_t)b * 4 + i) * 256 + tid];
    float K = inner / (kn * mnorm[tid] + 1e-8f);
    float x = beta * K;
    float mx = blk_max4(x, red4);
    float e = expf(x - mx);
    float se = blk_sum4(e, red4);
    float wc = e / se;
    float wg = g * wc + (1.f - g) * aprev[i * 256 + tid];
    wgs[tid] = wg;
    __syncthreads();
    float wconv = s0 * wg + s1 * wgs[(tid + 255) & 255] + s2 * wgs[(tid + 1) & 255];
    float wsh = powf(wconv, gamma);
    float ssum = blk_sum4(wsh, red4);
    float w = wsh / ssum;
    if (i < 2) hcat[(size_t)b * 1024 + 512 + i * 256 + tid] = f2bf(w);
    else       at[((size_t)(i - 2) * Bn + b) * 256 + tid] = w;
}

// m_t: 8 batch rows per block; m0 loaded once per position, reused 8x.
// grid 256 blocks x 512 threads. Nontemporal streaming stores.
__global__ __launch_bounds__(512) void k_memt(
    const float* __restrict__ m0, const float* __restrict__ at,
    const float* __restrict__ era, const float* __restrict__ addv,
    float* __restrict__ outm)
{
    __shared__ __align__(16) float at_s[2][8][256];
    __shared__ __align__(16) float er_s[2][8][128];
    __shared__ __align__(16) float ad_s[2][8][128];
    const int tid = threadIdx.x;
    const int b0 = blockIdx.x * 8;
    for (int t = tid; t < 1024; t += 512) {        // 1024 float4 = at
        int i = t >> 9, rem = t & 511;
        int bb = rem >> 6, n4 = rem & 63;
        ((float4*)&at_s[i][bb][0])[n4] =
            ((const float4*)(at + ((size_t)i * Bn + b0 + bb) * 256))[n4];
    }
    {
        int t = tid;
        if (t < 512) {                             // 512 float4 each era/add
            int i = t >> 8, rem = t & 255;
            int bb = rem >> 5, m4 = rem & 31;
            ((float4*)&er_s[i][bb][0])[m4] =
                ((const float4*)(era + ((size_t)(b0 + bb) * 2 + i) * 128))[m4];
            ((float4*)&ad_s[i][bb][0])[m4] =
                ((const float4*)(addv + ((size_t)(b0 + bb) * 2 + i) * 128))[m4];
        }
    }
    __syncthreads();
    const float4* m0v = (const float4*)m0;
    float4* outv = (float4*)outm;
    for (int pos = tid; pos < 8192; pos += 512) {
        int mq = pos & 31, n = pos >> 5;
        float4 t0 = m0v[pos];
        #pragma unroll
        for (int bb = 0; bb < 8; ++bb) {
            float w0 = at_s[0][bb][n], w1 = at_s[1][bb][n];
            float4 e0 = *(const float4*)&er_s[0][bb][mq * 4];
            float4 a0 = *(const float4*)&ad_s[0][bb][mq * 4];
            float4 e1 = *(const float4*)&er_s[1][bb][mq * 4];
            float4 a1 = *(const float4*)&ad_s[1][bb][mq * 4];
            float4 t = t0;
#define UPD(c) { t.c = t.c * (1.f - w0 * e0.c) + w0 * a0.c; \
                 t.c = t.c * (1.f - w1 * e1.c) + w1 * a1.c; }
            UPD(x) UPD(y) UPD(z) UPD(w)
#undef UPD
            __builtin_nontemporal_store(*(f32x4*)&t,
                (f32x4*)&outv[(size_t)(b0 + bb) * 8192 + pos]);
        }
    }
}

extern "C" void kernel_launch(void* const* d_in, const int* in_sizes, int n_in,
                              void* d_out, int out_size, void* d_ws, size_t ws_size,
                              hipStream_t stream)
{
    const float* X      = (const float*)d_in[0];
    const float* m0     = (const float*)d_in[1];
    const float* H0     = (const float*)d_in[2];
    const float* C0     = (const float*)d_in[3];
    const float* R0     = (const float*)d_in[4];
    const float* A0     = (const float*)d_in[5];
    const float* W_prep = (const float*)d_in[6];
    const float* b_prep = (const float*)d_in[7];
    const float* W_lstm = (const float*)d_in[8];
    const float* b_lstm = (const float*)d_in[9];
    const float* W_r    = (const float*)d_in[10];
    const float* b_r    = (const float*)d_in[11];
    const float* W_w    = (const float*)d_in[12];
    const float* b_w    = (const float*)d_in[13];
    const float* W_ou   = (const float*)d_in[14];
    const float* b_ou   = (const float*)d_in[15];
    float* ws  = (float*)d_ws;
    float* out = (float*)d_out;

    unsigned short* XHB   = (unsigned short*)(ws + OFF_XHB);
    unsigned short* HCAT  = (unsigned short*)(ws + OFF_HCAT);
    unsigned short* W0T   = (unsigned short*)(ws + OFF_W0T);
    unsigned short* W1T   = (unsigned short*)(ws + OFF_W1T);
    unsigned short* WRWT  = (unsigned short*)(ws + OFF_WRWT);
    unsigned short* WCOMB = (unsigned short*)(ws + OFF_WCOMB);
    unsigned short* WR2T  = (unsigned short*)(ws + OFF_WR2T);
    unsigned short* M0B   = (unsigned short*)(ws + OFF_M0B);

    // 1. all prep
    k_prep<<<S_END, 256, 0, stream>>>(
        X, m0, H0, R0, A0, W_prep, b_prep, W_lstm, W_r, b_r, W_w, b_w, W_ou, ws);

    // 2. LSTM layer 0 + both P-folds in one dispatch
    gemm_l0p<<<dim3(32, 17), 256, 0, stream>>>(
        XHB, W0T, WR2T, M0B, ws + OFF_ZPART, b_lstm, C0, XHB + 512, WCOMB);

    // 3. LSTM layer 1
    gemm_lstm<<<dim3(32, 16), 256, 0, stream>>>(
        XHB, 1024, W1T, 1024, ws + OFF_ZPART, b_lstm, 1, C0 + 512, HCAT, 1024, 1024, 1);

    // 4. heads
    gemm_bf16<<<dim3(32, 9), 256, 0, stream>>>(
        HCAT, 1024, WRWT, 512, ws + OFF_BIASH, ws + OFF_HEADS, nullptr, 1048, 1048, 512, 0);

    // 5. kmat (fused tanh)
    gemm_kmat<<<dim3(128, 2), 256, 0, stream>>>(
        ws + OFF_HEADS, M0B, ws + OFF_KMAT);

    // 6. addressing (4 heads)
    k_addr<<<dim3(Bn, 4), 256, 0, stream>>>(
        ws + OFF_HEADS, ws + OFF_KMAT, ws + OFF_MNORM, ws + OFF_APREV,
        ws + OFF_AT, HCAT, ws + OFF_ERA, ws + OFF_ADD);

    // 7. y = clip([h|A0|A1] @ WCOMB + b_ou)
    gemm_bf16<<<dim3(32, 4), 256, 0, stream>>>(
        HCAT, 1024, WCOMB, 1024, b_ou, out, nullptr, 512, 512, 1024, 1);

    // 8. m_t tiled (8 b / block)
    k_memt<<<256, 512, 0, stream>>>(
        m0, ws + OFF_AT, ws + OFF_ERA, ws + OFF_ADD, out + (size_t)Bn * Un);
}

// Round 10
// 175.669 us; speedup vs baseline: 2.7105x; 1.0546x over previous
//
#include <hip/hip_runtime.h>
#include <math.h>

static constexpr int Bn = 2048;   // batch
static constexpr int Nn = 256;    // memory locations
static constexpr int Mn = 128;    // memory width
static constexpr int Un = 512;    // units

// Workspace layout (f32 offsets)
static constexpr size_t OFF_MNORM = 4608;     // 256
static constexpr size_t OFF_APREV = 4864;     // 1024
static constexpr size_t OFF_BIASH = 5888;     // 1152
static constexpr size_t OFF_KMAT  = 16384;                           // f32 [8192][256]
static constexpr size_t OFF_HEADS = OFF_KMAT + (size_t)8192 * 256;   // f32 [2048][1048]
static constexpr size_t OFF_AT    = OFF_HEADS + (size_t)2048 * 1048; // f32 [2][2048][256]
static constexpr size_t OFF_ERA   = OFF_AT + (size_t)2 * 2048 * 256; // f32 [2048][2][128]
static constexpr size_t OFF_ADD   = OFF_ERA + (size_t)2048 * 256;
static constexpr size_t OFF_XHB   = OFF_ADD + (size_t)2048 * 256;    // bf16 [2048][1024]
static constexpr size_t OFF_HCAT  = OFF_XHB + 524288;                // bf16 [2048][1024]
static constexpr size_t OFF_W0T   = OFF_HCAT + 524288;               // bf16 [2048][512]
static constexpr size_t OFF_W1T   = OFF_W0T + 524288;                // bf16 [2048][1024]
static constexpr size_t OFF_WRWT  = OFF_W1T + 1048576;               // bf16 [1152][512]
static constexpr size_t OFF_WCOMB = OFF_WRWT + 294912;               // bf16 [512][1024]
static constexpr size_t OFF_WR2T  = OFF_WCOMB + 262144;              // bf16 [512][256]
static constexpr size_t OFF_M0B   = OFF_WR2T + 65536;                // bf16 [256][128]
static constexpr size_t OFF_ZPART = OFF_M0B + 16384 + 524288;        // f32 [2][8][2048]

// k_prep (dispatch 1, critical path) block table
static constexpr int P_X0  = 0;            // cvt8 X        (512)
static constexpr int P_M0  = 512;          // cvt8 m0       (16)
static constexpr int P_W0  = 528;          // cvtT W0 gate  (64x16)
static constexpr int P_WR2 = 1552;         // cvtT W_ou r   (16x8)
static constexpr int P_CA  = 1680;         // const-a       (1)
static constexpr int P_ZC  = 1681;         // zpart L0      (64)
static constexpr int P_END = 1745;

// k_mid (dispatch 2: LSTM0 + pfold + late prep) block table
static constexpr int M_L0  = 0;            // LSTM0         (512 = 32x16)
static constexpr int M_PF  = 512;          // pfold         (32)
static constexpr int M_W1  = 544;          // cvtT W1 gate  (64x32)
static constexpr int M_WRr = 2592;         // cvtT W_r      (9x16)
static constexpr int M_WRw = 2736;         // cvtT W_w      (25x16)
static constexpr int M_WOU = 3136;         // cvtT W_ou h   (16x16)
static constexpr int M_ZC1 = 3392;         // zpart L1      (64)
static constexpr int M_END = 3456;

// k_tail (dispatch 7: out GEMM + memt) block table
static constexpr int T_OUT = 0;            // out GEMM      (128 = 32x4)
static constexpr int T_MEM = 128;          // memt          (256)
static constexpr int T_END = 384;

#define DEV __device__ __forceinline__

typedef __attribute__((ext_vector_type(8))) short bf16x8;
typedef __attribute__((ext_vector_type(4))) float f32x4;
typedef __attribute__((ext_vector_type(8))) unsigned short ushort8;
typedef unsigned int u32;

DEV float sigf(float x) { return 1.0f / (1.0f + expf(-x)); }
DEV float softplusf(float x) { return x > 20.0f ? x : log1pf(expf(x)); }
DEV unsigned short f2bf(float f) {   // RNE float->bf16
    unsigned u = __float_as_uint(f);
    u = (u + 0x7FFFu + ((u >> 16) & 1u)) >> 16;
    return (unsigned short)u;
}
DEV void gload16(const unsigned short* g, unsigned short* l) {
    __builtin_amdgcn_global_load_lds(
        (const __attribute__((address_space(1))) u32*)g,
        (__attribute__((address_space(3))) u32*)l, 16, 0, 0);
}

// tree reductions (k_prep const block only)
DEV float blk_reduce_max(float v, float* red) {
    int tid = threadIdx.x;
    red[tid] = v; __syncthreads();
    for (int s = (int)blockDim.x >> 1; s > 0; s >>= 1) {
        if (tid < s) red[tid] = fmaxf(red[tid], red[tid + s]);
        __syncthreads();
    }
    float r = red[0]; __syncthreads();
    return r;
}
DEV float blk_reduce_sum(float v, float* red) {
    int tid = threadIdx.x;
    red[tid] = v; __syncthreads();
    for (int s = (int)blockDim.x >> 1; s > 0; s >>= 1) {
        if (tid < s) red[tid] += red[tid + s];
        __syncthreads();
    }
    float r = red[0]; __syncthreads();
    return r;
}

// wave-shuffle reductions for 256-thread blocks
DEV float wv_sum(float v) {
    #pragma unroll
    for (int off = 32; off; off >>= 1) v += __shfl_xor(v, off);
    return v;
}
DEV float wv_max(float v) {
    #pragma unroll
    for (int off = 32; off; off >>= 1) v = fmaxf(v, __shfl_xor(v, off));
    return v;
}
DEV float blk_sum4(float v, float* red4) {
    v = wv_sum(v);
    int w = threadIdx.x >> 6;
    if ((threadIdx.x & 63) == 0) red4[w] = v;
    __syncthreads();
    float r = red4[0] + red4[1] + red4[2] + red4[3];
    __syncthreads();
    return r;
}
DEV float blk_max4(float v, float* red4) {
    v = wv_max(v);
    int w = threadIdx.x >> 6;
    if ((threadIdx.x & 63) == 0) red4[w] = v;
    __syncthreads();
    float r = fmaxf(fmaxf(red4[0], red4[1]), fmaxf(red4[2], red4[3]));
    __syncthreads();
    return r;
}

// ===========================================================================
// GEMM machinery: 64x128 tile, 4 waves (2x2), BK=64, dbuf LDS via
// global_load_lds (16B), XOR-swizzle via pre-swizzled source k-offset,
// T4 counted-vmcnt mainloop.
// ===========================================================================
#define GEMM_SHARED                                                             \
    __shared__ __align__(16) unsigned short As[2][64 * 64];                     \
    __shared__ __align__(16) unsigned short Ws[2][128 * 64];

#define GEMM_REGS                                                               \
    const int tid  = threadIdx.x;                                               \
    const int lane = tid & 63;                                                  \
    const int wave = tid >> 6;                                                  \
    const int wr = wave >> 1, wc = wave & 1;                                    \
    const int ke = ((tid & 7) * 8) ^ (((tid >> 3) & 7) << 3);                   \
    const int frow = lane & 15;                                                 \
    const int fko  = (lane >> 4) * 8;                                           \
    const int fxm  = (frow & 7) << 3;                                           \
    f32x4 acc[2][4];                                                            \
    _Pragma("unroll")                                                           \
    for (int i = 0; i < 2; ++i)                                                 \
        _Pragma("unroll")                                                       \
        for (int j = 0; j < 4; ++j) acc[i][j] = (f32x4){0.f, 0.f, 0.f, 0.f};

#define GEMM_STAGE(buf, k0)                                                     \
    {                                                                           \
        _Pragma("unroll")                                                       \
        for (int q = 0; q < 2; ++q)                                             \
            gload16(A  + (size_t)(row0 + q * 32 + (tid >> 3)) * lda + (k0) + ke,\
                    &As[buf][q * 2048 + tid * 8]);                              \
        _Pragma("unroll")                                                       \
        for (int q = 0; q < 4; ++q)                                             \
            gload16(Wt + (size_t)(col0 + q * 32 + (tid >> 3)) * ldw + (k0) + ke,\
                    &Ws[buf][q * 2048 + tid * 8]);                              \
    }

#define GEMM_FRAGS_AND_MFMA(Ab, Wb)                                             \
    {                                                                           \
        bf16x8 af[2][2], wf[2][4];                                              \
        _Pragma("unroll")                                                       \
        for (int kk = 0; kk < 2; ++kk) {                                        \
            _Pragma("unroll")                                                   \
            for (int i = 0; i < 2; ++i) {                                       \
                int fr = wr * 32 + i * 16 + frow;                               \
                af[kk][i] = *(const bf16x8*)&(Ab)[fr * 64 + ((kk * 32 + fko) ^ fxm)]; \
            }                                                                   \
            _Pragma("unroll")                                                   \
            for (int j = 0; j < 4; ++j) {                                       \
                int fr = wc * 64 + j * 16 + frow;                               \
                wf[kk][j] = *(const bf16x8*)&(Wb)[fr * 64 + ((kk * 32 + fko) ^ fxm)]; \
            }                                                                   \
        }                                                                       \
        __builtin_amdgcn_s_setprio(1);                                          \
        _Pragma("unroll")                                                       \
        for (int kk = 0; kk < 2; ++kk)                                          \
            _Pragma("unroll")                                                   \
            for (int i = 0; i < 2; ++i)                                         \
                _Pragma("unroll")                                               \
                for (int j = 0; j < 4; ++j)                                     \
                    acc[i][j] = __builtin_amdgcn_mfma_f32_16x16x32_bf16(        \
                        af[kk][i], wf[kk][j], acc[i][j], 0, 0, 0);              \
        __builtin_amdgcn_s_setprio(0);                                          \
    }

#define GEMM_MAINLOOP(Kr)                                                       \
    {                                                                           \
        const int nt = (Kr) >> 6;                                               \
        int cur = 0;                                                            \
        GEMM_STAGE(0, 0);                                                       \
        for (int t = 0; t < nt; ++t) {                                          \
            if (t + 1 < nt) {                                                   \
                GEMM_STAGE(cur ^ 1, (t + 1) * 64);                              \
                asm volatile("s_waitcnt vmcnt(6)" ::: "memory");                \
            } else {                                                            \
                asm volatile("s_waitcnt vmcnt(0)" ::: "memory");                \
            }                                                                   \
            __builtin_amdgcn_sched_barrier(0);                                  \
            __builtin_amdgcn_s_barrier();                                       \
            __builtin_amdgcn_sched_barrier(0);                                  \
            GEMM_FRAGS_AND_MFMA(As[cur], Ws[cur]);                              \
            __builtin_amdgcn_sched_barrier(0);                                  \
            __builtin_amdgcn_s_barrier();                                       \
            cur ^= 1;                                                           \
        }                                                                       \
    }

// LSTM epilogue (shared by L0 in k_mid and L1 kernel): gate-permuted cols,
// fused split-K zc reduce + cell nonlinearity.
#define LSTM_EPILOGUE(zc, doclip, houtp, ldhv)                                  \
    {                                                                           \
        const int uu = lane & 15;                                               \
        const int q  = (col0 >> 6) + wc;                                        \
        const int uq = q * 16 + uu;                                             \
        const float c0v = c0[(zc) * 512 + uq];                                  \
        float bg[4];                                                            \
        _Pragma("unroll")                                                       \
        for (int g = 0; g < 4; ++g) {                                           \
            int j = g * 512 + q * 16 + uu;                                      \
            float a = b_lstm[(zc) * 2048 + j];                                  \
            _Pragma("unroll")                                                   \
            for (int p = 0; p < 8; ++p)                                         \
                a += zpart[((size_t)(zc) * 8 + p) * 2048 + j];                  \
            bg[g] = a;                                                          \
        }                                                                       \
        _Pragma("unroll")                                                       \
        for (int i = 0; i < 2; ++i) {                                           \
            int rbase = row0 + wr * 32 + i * 16 + (lane >> 4) * 4;              \
            _Pragma("unroll")                                                   \
            for (int r = 0; r < 4; ++r) {                                       \
                float ig = acc[i][0][r] + bg[0];                                \
                float fg = acc[i][1][r] + bg[1];                                \
                float gg = acc[i][2][r] + bg[2];                                \
                float og = acc[i][3][r] + bg[3];                                \
                float c = sigf(fg) * c0v + sigf(ig) * tanhf(gg);                \
                float h = sigf(og) * tanhf(c);                                  \
                if (doclip) h = fminf(fmaxf(h, -20.f), 20.f);                   \
                (houtp)[(size_t)(rbase + r) * (ldhv) + uq] = f2bf(h);           \
            }                                                                   \
        }                                                                       \
    }

// ---------------------------------------------------------------------------
// prep device helpers
DEV void dev_cvt8(const float* src, int lds, unsigned short* dst, int ldd,
                  int c8, int bloc, int tid)
{
    size_t idx = (size_t)bloc * 256 + tid;
    size_t r = idx / c8, c = (idx % c8) * 8;
    const float* s = src + r * lds + c;
    float4 v0 = *(const float4*)s;
    float4 v1 = *(const float4*)(s + 4);
    ushort8 o;
    o[0] = f2bf(v0.x); o[1] = f2bf(v0.y); o[2] = f2bf(v0.z); o[3] = f2bf(v0.w);
    o[4] = f2bf(v1.x); o[5] = f2bf(v1.y); o[6] = f2bf(v1.z); o[7] = f2bf(v1.w);
    *(ushort8*)(dst + r * ldd + c) = o;
}

DEV void dev_cvtT(const float* src, int R, int C, int lds,
                  unsigned short* dst, int ldd, int mode, int bx, int by,
                  int tid, float* t /*32x33*/)
{
    const int x = tid & 31;
    for (int y = tid >> 5; y < 32; y += 8) {
        int r = by * 32 + y, c = bx * 32 + x;
        int scol = c;
        if (mode) scol = ((c >> 4) & 3) * 512 + (c >> 6) * 16 + (c & 15);
        t[y * 33 + x] = (r < R && c < C) ? src[(size_t)r * lds + scol] : 0.f;
    }
    __syncthreads();
    for (int y = tid >> 5; y < 32; y += 8) {
        int c = bx * 32 + y, r = by * 32 + x;
        if (c < C && r < R) dst[(size_t)c * ldd + r] = f2bf(t[x * 33 + y]);
    }
}

// ===========================================================================
// Dispatch 1 — k_prep (critical path only)
// ===========================================================================
__global__ __launch_bounds__(256) void k_prep(
    const float* __restrict__ X, const float* __restrict__ m0,
    const float* __restrict__ H0, const float* __restrict__ R0,
    const float* __restrict__ A0, const float* __restrict__ W_prep,
    const float* __restrict__ b_prep, const float* __restrict__ W_lstm,
    const float* __restrict__ b_r, const float* __restrict__ b_w,
    const float* __restrict__ W_ou, float* __restrict__ ws)
{
    __shared__ float sh[32 * 33 + 64];
    const int bid = blockIdx.x, tid = threadIdx.x;
    unsigned short* XHB  = (unsigned short*)(ws + OFF_XHB);
    unsigned short* W0T  = (unsigned short*)(ws + OFF_W0T);
    unsigned short* WR2T = (unsigned short*)(ws + OFF_WR2T);
    unsigned short* M0B  = (unsigned short*)(ws + OFF_M0B);

    if (bid < P_M0) {
        dev_cvt8(X, 512, XHB, 1024, 64, bid - P_X0, tid);
    } else if (bid < P_W0) {
        dev_cvt8(m0, 128, M0B, 128, 16, bid - P_M0, tid);
    } else if (bid < P_WR2) {
        int s = bid - P_W0;
        dev_cvtT(W_lstm, 512, 2048, 2048, W0T, 512, 1, s & 63, s >> 6, tid, sh);
    } else if (bid < P_CA) {
        int s = bid - P_WR2;
        dev_cvtT(W_ou + (size_t)512 * 512, 256, 512, 512, WR2T, 256, 0,
                 s & 15, s >> 4, tid, sh);
    } else if (bid < P_ZC) {
        float* red = sh;
        for (int i = 0; i < 4; ++i) {
            float v = A0[i * 256 + tid];
            float mx = blk_reduce_max(v, red);
            float e = expf(v - mx);
            float s = blk_reduce_sum(e, red);
            ws[OFF_APREV + i * 256 + tid] = e / s;
        }
        float acc = 0.f;
        for (int m = 0; m < 128; ++m) {
            float t = m0[(size_t)tid * 128 + m];
            acc = fmaf(t, t, acc);
        }
        ws[OFF_MNORM + tid] = sqrtf(acc);
        for (int j = tid; j < 1152; j += 256)
            ws[OFF_BIASH + j] = (j < 268) ? b_r[j] : (j < 1048 ? b_w[j - 268] : 0.f);
    } else {
        // zpart layer 0 (split-K, coalesced W_lstm rows, orig col order)
        int sub = bid - P_ZC;
        int colb = sub & 7, up = sub >> 3;
        int j = colb * 256 + tid;
        float acc = 0.f;
        if (up < 4) {
            sh[256 + tid] = tanhf(R0[tid]);
            __syncthreads();
            if (tid < 128) {
                int u = up * 128 + tid;
                float a = b_prep[u];
                for (int k = 0; k < 256; ++k)
                    a = fmaf(sh[256 + k], W_prep[(size_t)k * 512 + u], a);
                sh[tid] = a;
            }
            __syncthreads();
            const int u0 = up * 128;
            #pragma unroll 4
            for (int t = 0; t < 128; ++t)
                acc = fmaf(sh[t], W_lstm[(size_t)(512 + u0 + t) * 2048 + j], acc);
        } else {
            const int u0 = up * 128;
            #pragma unroll 4
            for (int t = 0; t < 128; ++t)
                acc = fmaf(H0[u0 - 512 + t],
                           W_lstm[(size_t)(512 + u0 + t) * 2048 + j], acc);
        }
        (ws + OFF_ZPART)[(size_t)up * 2048 + j] = acc;
    }
}

// ===========================================================================
// Dispatch 2 — k_mid: LSTM0 GEMM + pfold GEMM + late prep (all concurrent)
// ===========================================================================
__global__ __launch_bounds__(256) void k_mid(
    const float* __restrict__ W_lstm, const float* __restrict__ W_r,
    const float* __restrict__ W_w, const float* __restrict__ W_ou,
    const float* __restrict__ H0, const float* __restrict__ b_lstm,
    const float* __restrict__ c0, float* __restrict__ ws)
{
    GEMM_SHARED
    const int s = blockIdx.x;
    float* sh = (float*)&As[0][0];   // alias for cvtT scratch (4.4 KB << 16 KB)
    unsigned short* XHB   = (unsigned short*)(ws + OFF_XHB);
    unsigned short* W0T   = (unsigned short*)(ws + OFF_W0T);
    unsigned short* W1T   = (unsigned short*)(ws + OFF_W1T);
    unsigned short* WRWT  = (unsigned short*)(ws + OFF_WRWT);
    unsigned short* WCOMB = (unsigned short*)(ws + OFF_WCOMB);
    unsigned short* WR2T  = (unsigned short*)(ws + OFF_WR2T);
    unsigned short* M0B   = (unsigned short*)(ws + OFF_M0B);
    const float* zpart    = ws + OFF_ZPART;

    if (s < M_W1) {
        // ---- GEMM paths: LSTM0 (s<512) or pfold (512<=s<544) ----
        const unsigned short *A, *Wt;
        int lda, ldw, row0, col0, Kr;
        unsigned short* pCb = nullptr;
        const bool lstm0 = (s < M_PF);
        if (lstm0) {
            A = XHB;  lda = 1024; Wt = W0T; ldw = 512;
            row0 = (s & 31) * 64; col0 = (s >> 5) * 128; Kr = 512;
        } else {
            int p = s - M_PF;
            int pz = p >> 4, py = (p >> 3) & 1, px = p & 7;
            A = WR2T + pz * 128; lda = 256; Wt = M0B; ldw = 128;
            row0 = px * 64; col0 = py * 128; Kr = 128;
            pCb = WCOMB + 512 + pz * 256;
        }
        GEMM_REGS
        GEMM_MAINLOOP(Kr)
        if (lstm0) {
            unsigned short* hout = XHB + 512;
            LSTM_EPILOGUE(0, 0, hout, 1024)
        } else {
            #pragma unroll
            for (int i = 0; i < 2; ++i) {
                int m0r = row0 + wr * 32 + i * 16 + (lane >> 4) * 4;
                #pragma unroll
                for (int j = 0; j < 4; ++j) {
                    int n = col0 + wc * 64 + j * 16 + (lane & 15);
                    #pragma unroll
                    for (int r = 0; r < 4; ++r)
                        pCb[(size_t)(m0r + r) * 1024 + n] = f2bf(acc[i][j][r]);
                }
            }
        }
    } else if (s < M_WRr) {
        int s1 = s - M_W1;
        dev_cvtT(W_lstm + (size_t)1536 * 2048, 1024, 2048, 2048, W1T, 1024, 1,
                 s1 & 63, s1 >> 6, threadIdx.x, sh);
    } else if (s < M_WRw) {
        int s2 = s - M_WRr;
        dev_cvtT(W_r, 512, 268, 268, WRWT, 512, 0, s2 % 9, s2 / 9, threadIdx.x, sh);
    } else if (s < M_WOU) {
        int s3 = s - M_WRw;
        dev_cvtT(W_w, 512, 780, 780, WRWT + (size_t)268 * 512, 512, 0,
                 s3 % 25, s3 / 25, threadIdx.x, sh);
    } else if (s < M_ZC1) {
        int s4 = s - M_WOU;
        dev_cvtT(W_ou, 512, 512, 512, WCOMB, 1024, 0, s4 & 15, s4 >> 4,
                 threadIdx.x, sh);
    } else {
        // zpart layer 1
        int s5 = s - M_ZC1;
        int colb = s5 & 7, up = s5 >> 3;
        int j = colb * 256 + threadIdx.x;
        const int u0 = up * 64;
        const float* W1 = W_lstm + (size_t)1536 * 2048;
        float acc = 0.f;
        #pragma unroll 4
        for (int t = 0; t < 64; ++t)
            acc = fmaf(H0[512 + u0 + t], W1[(size_t)(1024 + u0 + t) * 2048 + j], acc);
        (ws + OFF_ZPART)[((size_t)8 + up) * 2048 + j] = acc;
    }
}

// ===========================================================================
// Dispatch 3 — LSTM layer 1
// ===========================================================================
__global__ __launch_bounds__(256) void gemm_lstm(
    const unsigned short* __restrict__ A, int lda,
    const unsigned short* __restrict__ Wt, int ldw,
    const float* __restrict__ zpart, const float* __restrict__ b_lstm,
    const float* __restrict__ c0, unsigned short* __restrict__ hout)
{
    GEMM_SHARED
    const int row0 = blockIdx.x * 64;
    const int col0 = blockIdx.y * 128;
    GEMM_REGS
    GEMM_MAINLOOP(1024)
    LSTM_EPILOGUE(1, 1, hout, 1024)
}

// ===========================================================================
// Dispatch 4 — generic GEMM (heads). epi0: f32 out + bias.
// ===========================================================================
__global__ __launch_bounds__(256) void gemm_bf16(
    const unsigned short* __restrict__ A, int lda,
    const unsigned short* __restrict__ Wt, int ldw,
    const float* __restrict__ bias, float* __restrict__ C, int ldc,
    int Nr, int Kr)
{
    GEMM_SHARED
    const int row0 = blockIdx.x * 64;
    const int col0 = blockIdx.y * 128;
    GEMM_REGS
    GEMM_MAINLOOP(Kr)
    #pragma unroll
    for (int i = 0; i < 2; ++i) {
        int m0r = row0 + wr * 32 + i * 16 + (lane >> 4) * 4;
        #pragma unroll
        for (int j = 0; j < 4; ++j) {
            int n = col0 + wc * 64 + j * 16 + (lane & 15);
            if (n >= Nr) continue;
            float bv = bias ? bias[n] : 0.f;
            #pragma unroll
            for (int r = 0; r < 4; ++r)
                C[(size_t)(m0r + r) * ldc + n] = acc[i][j][r] + bv;
        }
    }
}

// ===========================================================================
// Dispatch 5 — kmat GEMM with fused tanh k-prep
// ===========================================================================
__global__ __launch_bounds__(256) void gemm_kmat(
    const float* __restrict__ heads,
    const unsigned short* __restrict__ M0B,
    float* __restrict__ C)
{
    GEMM_SHARED
    const int row0 = blockIdx.x * 64;
    const int col0 = blockIdx.y * 128;
    GEMM_REGS

#define KMAT_STAGE(buf, k0)                                                     \
    {                                                                           \
        _Pragma("unroll")                                                       \
        for (int q = 0; q < 2; ++q) {                                           \
            int R = row0 + q * 32 + (tid >> 3);                                 \
            int b = R >> 2, ih = R & 3;                                         \
            int cb = (ih < 2) ? ih * 134 : 268 + (ih - 2) * 390;                \
            const float* hp = heads + (size_t)b * 1048 + cb + (k0) + ke;        \
            ushort8 o;                                                          \
            _Pragma("unroll")                                                   \
            for (int j = 0; j < 8; ++j) o[j] = f2bf(tanhf(hp[j]));              \
            *(ushort8*)&As[buf][q * 2048 + tid * 8] = o;                        \
        }                                                                       \
        _Pragma("unroll")                                                       \
        for (int q = 0; q < 4; ++q)                                             \
            gload16(M0B + (size_t)(col0 + q * 32 + (tid >> 3)) * 128 + (k0) + ke,\
                    &Ws[buf][q * 2048 + tid * 8]);                              \
    }

    int cur = 0;
    KMAT_STAGE(0, 0);
    for (int t = 0; t < 2; ++t) {
        __syncthreads();
        if (t == 0) KMAT_STAGE(1, 64);
        GEMM_FRAGS_AND_MFMA(As[cur], Ws[cur]);
        cur ^= 1;
    }
#undef KMAT_STAGE
    #pragma unroll
    for (int i = 0; i < 2; ++i) {
        int m0r = row0 + wr * 32 + i * 16 + (lane >> 4) * 4;
        #pragma unroll
        for (int j = 0; j < 4; ++j) {
            int n = col0 + wc * 64 + j * 16 + (lane & 15);
            #pragma unroll
            for (int r = 0; r < 4; ++r)
                C[(size_t)(m0r + r) * 256 + n] = acc[i][j][r];
        }
    }
}

// ===========================================================================
// Dispatch 6 — addressing (4 heads, shuffle reductions)
// ===========================================================================
__global__ __launch_bounds__(256) void k_addr(
    const float* __restrict__ heads, const float* __restrict__ kmat,
    const float* __restrict__ mnorm, const float* __restrict__ aprev,
    float* __restrict__ at, unsigned short* __restrict__ hcat,
    float* __restrict__ era, float* __restrict__ addv)
{
    __shared__ float red4[4];
    __shared__ float wgs[256];
    __shared__ float sc[6];
    const int b = blockIdx.x, i = blockIdx.y, tid = threadIdx.x;
    const int cb = (i < 2) ? i * 134 : 268 + (i - 2) * 390;
    const float* hd = heads + (size_t)b * 1048 + cb;
    float kv = (tid < 128) ? tanhf(hd[tid]) : 0.f;
    float kn = sqrtf(blk_sum4(kv * kv, red4));
    if (i >= 2 && tid < 128) {
        era [((size_t)b * 2 + (i - 2)) * 128 + tid] = sigf(hd[134 + tid]);
        addv[((size_t)b * 2 + (i - 2)) * 128 + tid] = tanhf(hd[262 + tid]);
    }
    if (tid == 0) {
        sc[0] = softplusf(hd[128]);
        sc[1] = sigf(hd[129]);
        float v0 = hd[130], v1 = hd[131], v2 = hd[132];
        float mx = fmaxf(v0, fmaxf(v1, v2));
        float e0 = expf(v0 - mx), e1 = expf(v1 - mx), e2 = expf(v2 - mx);
        float ssum = e0 + e1 + e2;
        sc[2] = e0 / ssum; sc[3] = e1 / ssum; sc[4] = e2 / ssum;
        sc[5] = softplusf(hd[133]);
    }
    __syncthreads();
    const float beta = sc[0], g = sc[1], s0 = sc[2], s1 = sc[3], s2 = sc[4],
                gamma = sc[5];
    float inner = kmat[((size_t)b * 4 + i) * 256 + tid];
    float K = inner / (kn * mnorm[tid] + 1e-8f);
    float x = beta * K;
    float mx = blk_max4(x, red4);
    float e = expf(x - mx);
    float se = blk_sum4(e, red4);
    float wc = e / se;
    float wg = g * wc + (1.f - g) * aprev[i * 256 + tid];
    wgs[tid] = wg;
    __syncthreads();
    float wconv = s0 * wg + s1 * wgs[(tid + 255) & 255] + s2 * wgs[(tid + 1) & 255];
    float wsh = powf(wconv, gamma);
    float ssum = blk_sum4(wsh, red4);
    float w = wsh / ssum;
    if (i < 2) hcat[(size_t)b * 1024 + 512 + i * 256 + tid] = f2bf(w);
    else       at[((size_t)(i - 2) * Bn + b) * 256 + tid] = w;
}

// ===========================================================================
// Dispatch 7 — k_tail: out GEMM (clip) + memt, overlapped in one dispatch.
// ===========================================================================
__global__ __launch_bounds__(256) void k_tail(
    const unsigned short* __restrict__ HCAT,
    const unsigned short* __restrict__ WCOMB,
    const float* __restrict__ b_ou,
    const float* __restrict__ m0, const float* __restrict__ at,
    const float* __restrict__ era, const float* __restrict__ addv,
    float* __restrict__ out)
{
    GEMM_SHARED
    const int s = blockIdx.x;
    if (s < T_MEM) {
        // ---- out GEMM: y = clip([h|A0|A1] @ WCOMB + b_ou) ----
        const unsigned short* A  = HCAT;  const int lda = 1024;
        const unsigned short* Wt = WCOMB; const int ldw = 1024;
        const int row0 = (s & 31) * 64;
        const int col0 = (s >> 5) * 128;
        GEMM_REGS
        GEMM_MAINLOOP(1024)
        #pragma unroll
        for (int i = 0; i < 2; ++i) {
            int m0r = row0 + wr * 32 + i * 16 + (lane >> 4) * 4;
            #pragma unroll
            for (int j = 0; j < 4; ++j) {
                int n = col0 + wc * 64 + j * 16 + (lane & 15);
                if (n >= 512) continue;
                float bv = b_ou[n];
                #pragma unroll
                for (int r = 0; r < 4; ++r) {
                    float v = acc[i][j][r] + bv;
                    out[(size_t)(m0r + r) * 512 + n] = fminf(fmaxf(v, -20.f), 20.f);
                }
            }
        }
    } else {
        // ---- memt: 8 batch rows per block, m0 reused 8x, NT stores ----
        const int tid = threadIdx.x;
        const int b0 = (s - T_MEM) * 8;
        float (*at_s)[8][256] = (float(*)[8][256])(&As[0][0]);     // 16 KB
        float (*er_s)[8][128] = (float(*)[8][128])(&Ws[0][0]);     // 8 KB
        float (*ad_s)[8][128] = (float(*)[8][128])(&Ws[0][4096]);  // 8 KB
        for (int t = tid; t < 1024; t += 256) {
            int i = t >> 9, rem = t & 511;
            int bb = rem >> 6, n4 = rem & 63;
            ((float4*)&at_s[i][bb][0])[n4] =
                ((const float4*)(at + ((size_t)i * Bn + b0 + bb) * 256))[n4];
        }
        for (int t = tid; t < 512; t += 256) {
            int i = t >> 8, rem = t & 255;
            int bb = rem >> 5, m4 = rem & 31;
            ((float4*)&er_s[i][bb][0])[m4] =
                ((const float4*)(era + ((size_t)(b0 + bb) * 2 + i) * 128))[m4];
            ((float4*)&ad_s[i][bb][0])[m4] =
                ((const float4*)(addv + ((size_t)(b0 + bb) * 2 + i) * 128))[m4];
        }
        __syncthreads();
        const float4* m0v = (const float4*)m0;
        float4* outv = (float4*)(out + (size_t)Bn * Un);
        for (int pos = tid; pos < 8192; pos += 256) {
            int mq = pos & 31, n = pos >> 5;
            float4 t0 = m0v[pos];
            #pragma unroll
            for (int bb = 0; bb < 8; ++bb) {
                float w0 = at_s[0][bb][n], w1 = at_s[1][bb][n];
                float4 e0 = *(const float4*)&er_s[0][bb][mq * 4];
                float4 a0 = *(const float4*)&ad_s[0][bb][mq * 4];
                float4 e1 = *(const float4*)&er_s[1][bb][mq * 4];
                float4 a1 = *(const float4*)&ad_s[1][bb][mq * 4];
                float4 t = t0;
#define UPD(c) { t.c = t.c * (1.f - w0 * e0.c) + w0 * a0.c; \
                 t.c = t.c * (1.f - w1 * e1.c) + w1 * a1.c; }
                UPD(x) UPD(y) UPD(z) UPD(w)
#undef UPD
                __builtin_nontemporal_store(*(f32x4*)&t,
                    (f32x4*)&outv[(size_t)(b0 + bb) * 8192 + pos]);
            }
        }
    }
}

extern "C" void kernel_launch(void* const* d_in, const int* in_sizes, int n_in,
                              void* d_out, int out_size, void* d_ws, size_t ws_size,
                              hipStream_t stream)
{
    const float* X      = (const float*)d_in[0];
    const float* m0     = (const float*)d_in[1];
    const float* H0     = (const float*)d_in[2];
    const float* C0     = (const float*)d_in[3];
    const float* R0     = (const float*)d_in[4];
    const float* A0     = (const float*)d_in[5];
    const float* W_prep = (const float*)d_in[6];
    const float* b_prep = (const float*)d_in[7];
    const float* W_lstm = (const float*)d_in[8];
    const float* b_lstm = (const float*)d_in[9];
    const float* W_r    = (const float*)d_in[10];
    const float* b_r    = (const float*)d_in[11];
    const float* W_w    = (const float*)d_in[12];
    const float* b_w    = (const float*)d_in[13];
    const float* W_ou   = (const float*)d_in[14];
    const float* b_ou   = (const float*)d_in[15];
    float* ws  = (float*)d_ws;
    float* out = (float*)d_out;

    unsigned short* XHB   = (unsigned short*)(ws + OFF_XHB);
    unsigned short* HCAT  = (unsigned short*)(ws + OFF_HCAT);
    unsigned short* W1T   = (unsigned short*)(ws + OFF_W1T);
    unsigned short* WRWT  = (unsigned short*)(ws + OFF_WRWT);
    unsigned short* WCOMB = (unsigned short*)(ws + OFF_WCOMB);
    unsigned short* M0B   = (unsigned short*)(ws + OFF_M0B);

    // 1. critical prep
    k_prep<<<P_END, 256, 0, stream>>>(
        X, m0, H0, R0, A0, W_prep, b_prep, W_lstm, b_r, b_w, W_ou, ws);

    // 2. LSTM0 + pfold + late prep (concurrent)
    k_mid<<<M_END, 256, 0, stream>>>(
        W_lstm, W_r, W_w, W_ou, H0, b_lstm, C0, ws);

    // 3. LSTM layer 1
    gemm_lstm<<<dim3(32, 16), 256, 0, stream>>>(
        XHB, 1024, W1T, 1024, ws + OFF_ZPART, b_lstm, C0, HCAT);

    // 4. heads
    gemm_bf16<<<dim3(32, 9), 256, 0, stream>>>(
        HCAT, 1024, WRWT, 512, ws + OFF_BIASH, ws + OFF_HEADS, 1048, 1048, 512);

    // 5. kmat (fused tanh)
    gemm_kmat<<<dim3(128, 2), 256, 0, stream>>>(
        ws + OFF_HEADS, M0B, ws + OFF_KMAT);

    // 6. addressing
    k_addr<<<dim3(Bn, 4), 256, 0, stream>>>(
        ws + OFF_HEADS, ws + OFF_KMAT, ws + OFF_MNORM, ws + OFF_APREV,
        ws + OFF_AT, HCAT, ws + OFF_ERA, ws + OFF_ADD);

    // 7. out GEMM + memt (overlapped)
    k_tail<<<T_END, 256, 0, stream>>>(
        HCAT, WCOMB, b_ou, m0, ws + OFF_AT, ws + OFF_ERA, ws + OFF_ADD, out);
}

// Round 11
// 173.482 us; speedup vs baseline: 2.7447x; 1.0126x over previous
//
#include <hip/hip_runtime.h>
#include <math.h>

static constexpr int Bn = 2048;   // batch
static constexpr int Nn = 256;    // memory locations
static constexpr int Mn = 128;    // memory width
static constexpr int Un = 512;    // units

// Workspace layout (f32 offsets) — FIXED: XHB/HCAT true sizes (R4-R10 had
// them half-sized; XHB rows 1024+ aliased HCAT, HCAT rows 1024+ aliased W0T)
static constexpr size_t OFF_MNORM = 4608;     // 256
static constexpr size_t OFF_APREV = 4864;     // 1024
static constexpr size_t OFF_BIASH = 5888;     // 1152
static constexpr size_t OFF_KMAT  = 16384;                           // f32 [8192][256]; doubles as ZX bf16 [2048][2048]
static constexpr size_t OFF_HEADS = OFF_KMAT + 2097152;              // f32 [2048][1048]
static constexpr size_t OFF_AT    = OFF_HEADS + 2146304;             // f32 [2][2048][256]
static constexpr size_t OFF_ERA   = OFF_AT + 1048576;                // f32 [2048][2][128]
static constexpr size_t OFF_ADD   = OFF_ERA + 524288;
static constexpr size_t OFF_XHB   = OFF_ADD + 524288;                // bf16 [2048][1024] = 1048576 f32
static constexpr size_t OFF_HCAT  = OFF_XHB + 1048576;               // bf16 [2048][1024] = 1048576 f32
static constexpr size_t OFF_W0T   = OFF_HCAT + 1048576;              // bf16 [2048][512]
static constexpr size_t OFF_W1T   = OFF_W0T + 524288;                // bf16 [2048][1024]
static constexpr size_t OFF_WRWT  = OFF_W1T + 1048576;               // bf16 [1152][512]
static constexpr size_t OFF_WCOMB = OFF_WRWT + 294912;               // bf16 [512][1024]
static constexpr size_t OFF_WR2T  = OFF_WCOMB + 262144;              // bf16 [512][256]
static constexpr size_t OFF_M0B   = OFF_WR2T + 65536;                // bf16 [256][128]
static constexpr size_t OFF_ZPART = OFF_M0B + 16384;                 // f32 [2][8][2048]
static constexpr size_t OFF_YH    = OFF_ZPART + 32768;               // f32 [2048][512]

// k_prep (dispatch 1) block table
static constexpr int P_X0  = 0;            // cvt8 X        (512)
static constexpr int P_M0  = 512;          // cvt8 m0       (16)
static constexpr int P_W0  = 528;          // cvtT W0 gate  (64x16)
static constexpr int P_W1  = 1552;         // cvtT W1 gate  (64x32)
static constexpr int P_WR2 = 3600;         // cvtT W_ou r   (16x8)
static constexpr int P_CA  = 3728;         // const-a       (1)
static constexpr int P_ZC  = 3729;         // zpart L0      (64)
static constexpr int P_END = 3793;

// k_mid (dispatch 2) block table
static constexpr int M_L0  = 0;            // LSTM0 GEMM    (512)
static constexpr int M_ZX  = 512;          // ZX GEMM       (512)
static constexpr int M_PF  = 1024;         // pfold         (32)
static constexpr int M_WRr = 1056;         // cvtT W_r      (144)
static constexpr int M_WRw = 1200;         // cvtT W_w      (400)
static constexpr int M_WOU = 1600;         // cvtT W_ou h   (256)
static constexpr int M_ZC1 = 1856;         // zpart L1      (64)
static constexpr int M_END = 1920;

// k_heads (dispatch 4) block table
static constexpr int H_HD  = 0;            // heads GEMM    (288)
static constexpr int H_YH  = 288;          // yh GEMM       (128)
static constexpr int H_END = 416;

// k_tail (dispatch 7) block table
static constexpr int T_OUT = 0;            // out GEMM K=512 (128)
static constexpr int T_MEM = 128;          // memt          (256)
static constexpr int T_END = 384;

#define DEV __device__ __forceinline__

typedef __attribute__((ext_vector_type(8))) short bf16x8;
typedef __attribute__((ext_vector_type(4))) float f32x4;
typedef __attribute__((ext_vector_type(8))) unsigned short ushort8;
typedef unsigned int u32;

DEV float sigf(float x) { return 1.0f / (1.0f + expf(-x)); }
DEV float softplusf(float x) { return x > 20.0f ? x : log1pf(expf(x)); }
DEV unsigned short f2bf(float f) {   // RNE float->bf16
    unsigned u = __float_as_uint(f);
    u = (u + 0x7FFFu + ((u >> 16) & 1u)) >> 16;
    return (unsigned short)u;
}
DEV float b2f(unsigned short u) { return __uint_as_float((u32)u << 16); }
DEV void gload16(const unsigned short* g, unsigned short* l) {
    __builtin_amdgcn_global_load_lds(
        (const __attribute__((address_space(1))) u32*)g,
        (__attribute__((address_space(3))) u32*)l, 16, 0, 0);
}

// tree reductions (k_prep const block only)
DEV float blk_reduce_max(float v, float* red) {
    int tid = threadIdx.x;
    red[tid] = v; __syncthreads();
    for (int s = (int)blockDim.x >> 1; s > 0; s >>= 1) {
        if (tid < s) red[tid] = fmaxf(red[tid], red[tid + s]);
        __syncthreads();
    }
    float r = red[0]; __syncthreads();
    return r;
}
DEV float blk_reduce_sum(float v, float* red) {
    int tid = threadIdx.x;
    red[tid] = v; __syncthreads();
    for (int s = (int)blockDim.x >> 1; s > 0; s >>= 1) {
        if (tid < s) red[tid] += red[tid + s];
        __syncthreads();
    }
    float r = red[0]; __syncthreads();
    return r;
}

// wave-shuffle reductions for 256-thread blocks
DEV float wv_sum(float v) {
    #pragma unroll
    for (int off = 32; off; off >>= 1) v += __shfl_xor(v, off);
    return v;
}
DEV float wv_max(float v) {
    #pragma unroll
    for (int off = 32; off; off >>= 1) v = fmaxf(v, __shfl_xor(v, off));
    return v;
}
DEV float blk_sum4(float v, float* red4) {
    v = wv_sum(v);
    int w = threadIdx.x >> 6;
    if ((threadIdx.x & 63) == 0) red4[w] = v;
    __syncthreads();
    float r = red4[0] + red4[1] + red4[2] + red4[3];
    __syncthreads();
    return r;
}
DEV float blk_max4(float v, float* red4) {
    v = wv_max(v);
    int w = threadIdx.x >> 6;
    if ((threadIdx.x & 63) == 0) red4[w] = v;
    __syncthreads();
    float r = fmaxf(fmaxf(red4[0], red4[1]), fmaxf(red4[2], red4[3]));
    __syncthreads();
    return r;
}

// ===========================================================================
// GEMM machinery: 64x128 tile, 4 waves (2x2), BK=64, dbuf LDS via
// global_load_lds (16B), XOR-swizzle via pre-swizzled source k-offset,
// T4 counted-vmcnt mainloop.
// ===========================================================================
#define GEMM_SHARED                                                             \
    __shared__ __align__(16) unsigned short As[2][64 * 64];                     \
    __shared__ __align__(16) unsigned short Ws[2][128 * 64];

#define GEMM_REGS                                                               \
    const int tid  = threadIdx.x;                                               \
    const int lane = tid & 63;                                                  \
    const int wave = tid >> 6;                                                  \
    const int wr = wave >> 1, wc = wave & 1;                                    \
    const int ke = ((tid & 7) * 8) ^ (((tid >> 3) & 7) << 3);                   \
    const int frow = lane & 15;                                                 \
    const int fko  = (lane >> 4) * 8;                                           \
    const int fxm  = (frow & 7) << 3;                                           \
    f32x4 acc[2][4];                                                            \
    _Pragma("unroll")                                                           \
    for (int i = 0; i < 2; ++i)                                                 \
        _Pragma("unroll")                                                       \
        for (int j = 0; j < 4; ++j) acc[i][j] = (f32x4){0.f, 0.f, 0.f, 0.f};

#define GEMM_STAGE(buf, k0)                                                     \
    {                                                                           \
        _Pragma("unroll")                                                       \
        for (int q = 0; q < 2; ++q)                                             \
            gload16(A  + (size_t)(row0 + q * 32 + (tid >> 3)) * lda + (k0) + ke,\
                    &As[buf][q * 2048 + tid * 8]);                              \
        _Pragma("unroll")                                                       \
        for (int q = 0; q < 4; ++q)                                             \
            gload16(Wt + (size_t)(col0 + q * 32 + (tid >> 3)) * ldw + (k0) + ke,\
                    &Ws[buf][q * 2048 + tid * 8]);                              \
    }

#define GEMM_FRAGS_AND_MFMA(Ab, Wb)                                             \
    {                                                                           \
        bf16x8 af[2][2], wf[2][4];                                              \
        _Pragma("unroll")                                                       \
        for (int kk = 0; kk < 2; ++kk) {                                        \
            _Pragma("unroll")                                                   \
            for (int i = 0; i < 2; ++i) {                                       \
                int fr = wr * 32 + i * 16 + frow;                               \
                af[kk][i] = *(const bf16x8*)&(Ab)[fr * 64 + ((kk * 32 + fko) ^ fxm)]; \
            }                                                                   \
            _Pragma("unroll")                                                   \
            for (int j = 0; j < 4; ++j) {                                       \
                int fr = wc * 64 + j * 16 + frow;                               \
                wf[kk][j] = *(const bf16x8*)&(Wb)[fr * 64 + ((kk * 32 + fko) ^ fxm)]; \
            }                                                                   \
        }                                                                       \
        __builtin_amdgcn_s_setprio(1);                                          \
        _Pragma("unroll")                                                       \
        for (int kk = 0; kk < 2; ++kk)                                          \
            _Pragma("unroll")                                                   \
            for (int i = 0; i < 2; ++i)                                         \
                _Pragma("unroll")                                               \
                for (int j = 0; j < 4; ++j)                                     \
                    acc[i][j] = __builtin_amdgcn_mfma_f32_16x16x32_bf16(        \
                        af[kk][i], wf[kk][j], acc[i][j], 0, 0, 0);              \
        __builtin_amdgcn_s_setprio(0);                                          \
    }

#define GEMM_MAINLOOP(Kr)                                                       \
    {                                                                           \
        const int nt = (Kr) >> 6;                                               \
        int cur = 0;                                                            \
        GEMM_STAGE(0, 0);                                                       \
        for (int t = 0; t < nt; ++t) {                                          \
            if (t + 1 < nt) {                                                   \
                GEMM_STAGE(cur ^ 1, (t + 1) * 64);                              \
                asm volatile("s_waitcnt vmcnt(6)" ::: "memory");                \
            } else {                                                            \
                asm volatile("s_waitcnt vmcnt(0)" ::: "memory");                \
            }                                                                   \
            __builtin_amdgcn_sched_barrier(0);                                  \
            __builtin_amdgcn_s_barrier();                                       \
            __builtin_amdgcn_sched_barrier(0);                                  \
            GEMM_FRAGS_AND_MFMA(As[cur], Ws[cur]);                              \
            __builtin_amdgcn_sched_barrier(0);                                  \
            __builtin_amdgcn_s_barrier();                                       \
            cur ^= 1;                                                           \
        }                                                                       \
    }

// LSTM epilogue: gate-permuted cols, fused split-K zc reduce + optional ZX
// (bf16 [row][2048 permuted cols]) + cell nonlinearity.
#define LSTM_EPILOGUE(zc, doclip, houtp, ldhv, ZXP)                             \
    {                                                                           \
        const int uu = lane & 15;                                               \
        const int q  = (col0 >> 6) + wc;                                        \
        const int uq = q * 16 + uu;                                             \
        const float c0v = c0[(zc) * 512 + uq];                                  \
        float bg[4];                                                            \
        _Pragma("unroll")                                                       \
        for (int g = 0; g < 4; ++g) {                                           \
            int j = g * 512 + q * 16 + uu;                                      \
            float a = b_lstm[(zc) * 2048 + j];                                  \
            _Pragma("unroll")                                                   \
            for (int p = 0; p < 8; ++p)                                         \
                a += zpart[((size_t)(zc) * 8 + p) * 2048 + j];                  \
            bg[g] = a;                                                          \
        }                                                                       \
        _Pragma("unroll")                                                       \
        for (int i = 0; i < 2; ++i) {                                           \
            int rbase = row0 + wr * 32 + i * 16 + (lane >> 4) * 4;              \
            _Pragma("unroll")                                                   \
            for (int r = 0; r < 4; ++r) {                                       \
                float z0 = 0.f, z1 = 0.f, z2 = 0.f, z3 = 0.f;                   \
                if (ZXP) {                                                      \
                    const unsigned short* zr = (ZXP) +                          \
                        (size_t)(rbase + r) * 2048 + q * 64 + uu;               \
                    z0 = b2f(zr[0]);  z1 = b2f(zr[16]);                         \
                    z2 = b2f(zr[32]); z3 = b2f(zr[48]);                         \
                }                                                               \
                float ig = acc[i][0][r] + bg[0] + z0;                           \
                float fg = acc[i][1][r] + bg[1] + z1;                           \
                float gg = acc[i][2][r] + bg[2] + z2;                           \
                float og = acc[i][3][r] + bg[3] + z3;                           \
                float c = sigf(fg) * c0v + sigf(ig) * tanhf(gg);                \
                float h = sigf(og) * tanhf(c);                                  \
                if (doclip) h = fminf(fmaxf(h, -20.f), 20.f);                   \
                (houtp)[(size_t)(rbase + r) * (ldhv) + uq] = f2bf(h);           \
            }                                                                   \
        }                                                                       \
    }

// ---------------------------------------------------------------------------
// prep device helpers
DEV void dev_cvt8(const float* src, int lds, unsigned short* dst, int ldd,
                  int c8, int bloc, int tid)
{
    size_t idx = (size_t)bloc * 256 + tid;
    size_t r = idx / c8, c = (idx % c8) * 8;
    const float* s = src + r * lds + c;
    float4 v0 = *(const float4*)s;
    float4 v1 = *(const float4*)(s + 4);
    ushort8 o;
    o[0] = f2bf(v0.x); o[1] = f2bf(v0.y); o[2] = f2bf(v0.z); o[3] = f2bf(v0.w);
    o[4] = f2bf(v1.x); o[5] = f2bf(v1.y); o[6] = f2bf(v1.z); o[7] = f2bf(v1.w);
    *(ushort8*)(dst + r * ldd + c) = o;
}

DEV void dev_cvtT(const float* src, int R, int C, int lds,
                  unsigned short* dst, int ldd, int mode, int bx, int by,
                  int tid, float* t /*32x33*/)
{
    const int x = tid & 31;
    for (int y = tid >> 5; y < 32; y += 8) {
        int r = by * 32 + y, c = bx * 32 + x;
        int scol = c;
        if (mode) scol = ((c >> 4) & 3) * 512 + (c >> 6) * 16 + (c & 15);
        t[y * 33 + x] = (r < R && c < C) ? src[(size_t)r * lds + scol] : 0.f;
    }
    __syncthreads();
    for (int y = tid >> 5; y < 32; y += 8) {
        int c = bx * 32 + y, r = by * 32 + x;
        if (c < C && r < R) dst[(size_t)c * ldd + r] = f2bf(t[x * 33 + y]);
    }
}

// ===========================================================================
// Dispatch 1 — k_prep (critical path: XHB, M0B, W0T, W1T, WR2T, consts, zc0)
// ===========================================================================
__global__ __launch_bounds__(256) void k_prep(
    const float* __restrict__ X, const float* __restrict__ m0,
    const float* __restrict__ H0, const float* __restrict__ R0,
    const float* __restrict__ A0, const float* __restrict__ W_prep,
    const float* __restrict__ b_prep, const float* __restrict__ W_lstm,
    const float* __restrict__ b_r, const float* __restrict__ b_w,
    const float* __restrict__ W_ou, float* __restrict__ ws)
{
    __shared__ float sh[32 * 33 + 64];
    const int bid = blockIdx.x, tid = threadIdx.x;
    unsigned short* XHB  = (unsigned short*)(ws + OFF_XHB);
    unsigned short* W0T  = (unsigned short*)(ws + OFF_W0T);
    unsigned short* W1T  = (unsigned short*)(ws + OFF_W1T);
    unsigned short* WR2T = (unsigned short*)(ws + OFF_WR2T);
    unsigned short* M0B  = (unsigned short*)(ws + OFF_M0B);

    if (bid < P_M0) {
        dev_cvt8(X, 512, XHB, 1024, 64, bid - P_X0, tid);
    } else if (bid < P_W0) {
        dev_cvt8(m0, 128, M0B, 128, 16, bid - P_M0, tid);
    } else if (bid < P_W1) {
        int s = bid - P_W0;
        dev_cvtT(W_lstm, 512, 2048, 2048, W0T, 512, 1, s & 63, s >> 6, tid, sh);
    } else if (bid < P_WR2) {
        int s = bid - P_W1;
        dev_cvtT(W_lstm + (size_t)1536 * 2048, 1024, 2048, 2048, W1T, 1024, 1,
                 s & 63, s >> 6, tid, sh);
    } else if (bid < P_CA) {
        int s = bid - P_WR2;
        dev_cvtT(W_ou + (size_t)512 * 512, 256, 512, 512, WR2T, 256, 0,
                 s & 15, s >> 4, tid, sh);
    } else if (bid < P_ZC) {
        float* red = sh;
        for (int i = 0; i < 4; ++i) {
            float v = A0[i * 256 + tid];
            float mx = blk_reduce_max(v, red);
            float e = expf(v - mx);
            float s = blk_reduce_sum(e, red);
            ws[OFF_APREV + i * 256 + tid] = e / s;
        }
        float acc = 0.f;
        for (int m = 0; m < 128; ++m) {
            float t = m0[(size_t)tid * 128 + m];
            acc = fmaf(t, t, acc);
        }
        ws[OFF_MNORM + tid] = sqrtf(acc);
        for (int j = tid; j < 1152; j += 256)
            ws[OFF_BIASH + j] = (j < 268) ? b_r[j] : (j < 1048 ? b_w[j - 268] : 0.f);
    } else {
        // zpart layer 0 (split-K, coalesced W_lstm rows, orig col order)
        int sub = bid - P_ZC;
        int colb = sub & 7, up = sub >> 3;
        int j = colb * 256 + tid;
        float acc = 0.f;
        if (up < 4) {
            sh[256 + tid] = tanhf(R0[tid]);
            __syncthreads();
            if (tid < 128) {
                int u = up * 128 + tid;
                float a = b_prep[u];
                for (int k = 0; k < 256; ++k)
                    a = fmaf(sh[256 + k], W_prep[(size_t)k * 512 + u], a);
                sh[tid] = a;
            }
            __syncthreads();
            const int u0 = up * 128;
            #pragma unroll 4
            for (int t = 0; t < 128; ++t)
                acc = fmaf(sh[t], W_lstm[(size_t)(512 + u0 + t) * 2048 + j], acc);
        } else {
            const int u0 = up * 128;
            #pragma unroll 4
            for (int t = 0; t < 128; ++t)
                acc = fmaf(H0[u0 - 512 + t],
                           W_lstm[(size_t)(512 + u0 + t) * 2048 + j], acc);
        }
        (ws + OFF_ZPART)[(size_t)up * 2048 + j] = acc;
    }
}

// ===========================================================================
// Dispatch 2 — k_mid: LSTM0 GEMM + ZX GEMM (L1 X-part) + pfold + late prep
// ===========================================================================
__global__ __launch_bounds__(256) void k_mid(
    const float* __restrict__ W_lstm, const float* __restrict__ W_r,
    const float* __restrict__ W_w, const float* __restrict__ W_ou,
    const float* __restrict__ H0, const float* __restrict__ b_lstm,
    const float* __restrict__ c0, float* __restrict__ ws)
{
    GEMM_SHARED
    const int s = blockIdx.x;
    float* sh = (float*)&As[0][0];   // alias for cvtT scratch
    unsigned short* XHB   = (unsigned short*)(ws + OFF_XHB);
    unsigned short* W0T   = (unsigned short*)(ws + OFF_W0T);
    unsigned short* W1T   = (unsigned short*)(ws + OFF_W1T);
    unsigned short* WRWT  = (unsigned short*)(ws + OFF_WRWT);
    unsigned short* WCOMB = (unsigned short*)(ws + OFF_WCOMB);
    unsigned short* WR2T  = (unsigned short*)(ws + OFF_WR2T);
    unsigned short* M0B   = (unsigned short*)(ws + OFF_M0B);
    unsigned short* ZX    = (unsigned short*)(ws + OFF_KMAT);
    const float* zpart    = ws + OFF_ZPART;

    if (s < M_WRr) {
        // ---- GEMM paths: LSTM0 / ZX / pfold ----
        const unsigned short *A, *Wt;
        int lda, ldw, row0, col0, Kr, mode;
        unsigned short* pCb = nullptr;
        if (s < M_ZX) {
            mode = 0;
            A = XHB;  lda = 1024; Wt = W0T; ldw = 512;
            row0 = (s & 31) * 64; col0 = (s >> 5) * 128; Kr = 512;
        } else if (s < M_PF) {
            int p = s - M_ZX;
            mode = 1;
            A = XHB;  lda = 1024; Wt = W1T; ldw = 1024;   // k 0..511 = X part
            row0 = (p & 31) * 64; col0 = (p >> 5) * 128; Kr = 512;
        } else {
            int p = s - M_PF;
            mode = 2;
            int pz = p >> 4, py = (p >> 3) & 1, px = p & 7;
            A = WR2T + pz * 128; lda = 256; Wt = M0B; ldw = 128;
            row0 = px * 64; col0 = py * 128; Kr = 128;
            pCb = WCOMB + 512 + pz * 256;
        }
        GEMM_REGS
        GEMM_MAINLOOP(Kr)
        if (mode == 0) {
            unsigned short* hout = XHB + 512;
            const unsigned short* zxn = nullptr;
            LSTM_EPILOGUE(0, 0, hout, 1024, zxn)
        } else if (mode == 1) {
            // ZX bf16 [2048][2048 permuted cols]
            #pragma unroll
            for (int i = 0; i < 2; ++i) {
                int m0r = row0 + wr * 32 + i * 16 + (lane >> 4) * 4;
                #pragma unroll
                for (int j = 0; j < 4; ++j) {
                    int n = col0 + wc * 64 + j * 16 + (lane & 15);
                    #pragma unroll
                    for (int r = 0; r < 4; ++r)
                        ZX[(size_t)(m0r + r) * 2048 + n] = f2bf(acc[i][j][r]);
                }
            }
        } else {
            #pragma unroll
            for (int i = 0; i < 2; ++i) {
                int m0r = row0 + wr * 32 + i * 16 + (lane >> 4) * 4;
                #pragma unroll
                for (int j = 0; j < 4; ++j) {
                    int n = col0 + wc * 64 + j * 16 + (lane & 15);
                    #pragma unroll
                    for (int r = 0; r < 4; ++r)
                        pCb[(size_t)(m0r + r) * 1024 + n] = f2bf(acc[i][j][r]);
                }
            }
        }
    } else if (s < M_WRw) {
        int s2 = s - M_WRr;
        dev_cvtT(W_r, 512, 268, 268, WRWT, 512, 0, s2 % 9, s2 / 9, threadIdx.x, sh);
    } else if (s < M_WOU) {
        int s3 = s - M_WRw;
        dev_cvtT(W_w, 512, 780, 780, WRWT + (size_t)268 * 512, 512, 0,
                 s3 % 25, s3 / 25, threadIdx.x, sh);
    } else if (s < M_ZC1) {
        int s4 = s - M_WOU;
        dev_cvtT(W_ou, 512, 512, 512, WCOMB, 1024, 0, s4 & 15, s4 >> 4,
                 threadIdx.x, sh);
    } else {
        // zpart layer 1 (H0 part only)
        int s5 = s - M_ZC1;
        int colb = s5 & 7, up = s5 >> 3;
        int j = colb * 256 + threadIdx.x;
        const int u0 = up * 64;
        const float* W1 = W_lstm + (size_t)1536 * 2048;
        float acc = 0.f;
        #pragma unroll 4
        for (int t = 0; t < 64; ++t)
            acc = fmaf(H0[512 + u0 + t], W1[(size_t)(1024 + u0 + t) * 2048 + j], acc);
        (ws + OFF_ZPART)[((size_t)8 + up) * 2048 + j] = acc;
    }
}

// ===========================================================================
// Dispatch 3 — LSTM layer 1: K=512 (h1 part) + ZX (X part) in epilogue
// ===========================================================================
__global__ __launch_bounds__(256) void gemm_lstm(
    const unsigned short* __restrict__ A, int lda,
    const unsigned short* __restrict__ Wt, int ldw,
    const float* __restrict__ zpart, const float* __restrict__ b_lstm,
    const float* __restrict__ c0, const unsigned short* __restrict__ ZXP,
    unsigned short* __restrict__ hout)
{
    GEMM_SHARED
    const int row0 = blockIdx.x * 64;
    const int col0 = blockIdx.y * 128;
    GEMM_REGS
    GEMM_MAINLOOP(512)
    LSTM_EPILOGUE(1, 1, hout, 1024, ZXP)
}

// ===========================================================================
// Dispatch 4 — k_heads: heads GEMM (f32+bias) + yh GEMM (out h-part, f32)
// ===========================================================================
__global__ __launch_bounds__(256) void k_heads(
    const unsigned short* __restrict__ HCAT,
    const unsigned short* __restrict__ WRWT,
    const unsigned short* __restrict__ WCOMB,
    const float* __restrict__ biash,
    float* __restrict__ heads, float* __restrict__ yh)
{
    GEMM_SHARED
    const int s = blockIdx.x;
    const unsigned short* A = HCAT;  const int lda = 1024;
    const unsigned short* Wt;
    int ldw, row0, col0;
    if (s < H_YH) {
        Wt = WRWT; ldw = 512;
        row0 = (s & 31) * 64; col0 = (s >> 5) * 128;
    } else {
        int p = s - H_YH;
        Wt = WCOMB; ldw = 1024;
        row0 = (p & 31) * 64; col0 = (p >> 5) * 128;
    }
    GEMM_REGS
    GEMM_MAINLOOP(512)
    if (s < H_YH) {
        #pragma unroll
        for (int i = 0; i < 2; ++i) {
            int m0r = row0 + wr * 32 + i * 16 + (lane >> 4) * 4;
            #pragma unroll
            for (int j = 0; j < 4; ++j) {
                int n = col0 + wc * 64 + j * 16 + (lane & 15);
                if (n >= 1048) continue;
                float bv = biash[n];
                #pragma unroll
                for (int r = 0; r < 4; ++r)
                    heads[(size_t)(m0r + r) * 1048 + n] = acc[i][j][r] + bv;
            }
        }
    } else {
        #pragma unroll
        for (int i = 0; i < 2; ++i) {
            int m0r = row0 + wr * 32 + i * 16 + (lane >> 4) * 4;
            #pragma unroll
            for (int j = 0; j < 4; ++j) {
                int n = col0 + wc * 64 + j * 16 + (lane & 15);
                #pragma unroll
                for (int r = 0; r < 4; ++r)
                    yh[(size_t)(m0r + r) * 512 + n] = acc[i][j][r];
            }
        }
    }
}

// ===========================================================================
// Dispatch 5 — kmat GEMM with fused tanh k-prep
// ===========================================================================
__global__ __launch_bounds__(256) void gemm_kmat(
    const float* __restrict__ heads,
    const unsigned short* __restrict__ M0B,
    float* __restrict__ C)
{
    GEMM_SHARED
    const int row0 = blockIdx.x * 64;
    const int col0 = blockIdx.y * 128;
    GEMM_REGS

#define KMAT_STAGE(buf, k0)                                                     \
    {                                                                           \
        _Pragma("unroll")                                                       \
        for (int q = 0; q < 2; ++q) {                                           \
            int R = row0 + q * 32 + (tid >> 3);                                 \
            int b = R >> 2, ih = R & 3;                                         \
            int cb = (ih < 2) ? ih * 134 : 268 + (ih - 2) * 390;                \
            const float* hp = heads + (size_t)b * 1048 + cb + (k0) + ke;        \
            ushort8 o;                                                          \
            _Pragma("unroll")                                                   \
            for (int j = 0; j < 8; ++j) o[j] = f2bf(tanhf(hp[j]));              \
            *(ushort8*)&As[buf][q * 2048 + tid * 8] = o;                        \
        }                                                                       \
        _Pragma("unroll")                                                       \
        for (int q = 0; q < 4; ++q)                                             \
            gload16(M0B + (size_t)(col0 + q * 32 + (tid >> 3)) * 128 + (k0) + ke,\
                    &Ws[buf][q * 2048 + tid * 8]);                              \
    }

    int cur = 0;
    KMAT_STAGE(0, 0);
    for (int t = 0; t < 2; ++t) {
        __syncthreads();
        if (t == 0) KMAT_STAGE(1, 64);
        GEMM_FRAGS_AND_MFMA(As[cur], Ws[cur]);
        cur ^= 1;
    }
#undef KMAT_STAGE
    #pragma unroll
    for (int i = 0; i < 2; ++i) {
        int m0r = row0 + wr * 32 + i * 16 + (lane >> 4) * 4;
        #pragma unroll
        for (int j = 0; j < 4; ++j) {
            int n = col0 + wc * 64 + j * 16 + (lane & 15);
            #pragma unroll
            for (int r = 0; r < 4; ++r)
                C[(size_t)(m0r + r) * 256 + n] = acc[i][j][r];
        }
    }
}

// ===========================================================================
// Dispatch 6 — addressing (4 heads, shuffle reductions)
// ===========================================================================
__global__ __launch_bounds__(256) void k_addr(
    const float* __restrict__ heads, const float* __restrict__ kmat,
    const float* __restrict__ mnorm, const float* __restrict__ aprev,
    float* __restrict__ at, unsigned short* __restrict__ hcat,
    float* __restrict__ era, float* __restrict__ addv)
{
    __shared__ float red4[4];
    __shared__ float wgs[256];
    __shared__ float sc[6];
    const int b = blockIdx.x, i = blockIdx.y, tid = threadIdx.x;
    const int cb = (i < 2) ? i * 134 : 268 + (i - 2) * 390;
    const float* hd = heads + (size_t)b * 1048 + cb;
    float kv = (tid < 128) ? tanhf(hd[tid]) : 0.f;
    float kn = sqrtf(blk_sum4(kv * kv, red4));
    if (i >= 2 && tid < 128) {
        era [((size_t)b * 2 + (i - 2)) * 128 + tid] = sigf(hd[134 + tid]);
        addv[((size_t)b * 2 + (i - 2)) * 128 + tid] = tanhf(hd[262 + tid]);
    }
    if (tid == 0) {
        sc[0] = softplusf(hd[128]);
        sc[1] = sigf(hd[129]);
        float v0 = hd[130], v1 = hd[131], v2 = hd[132];
        float mx = fmaxf(v0, fmaxf(v1, v2));
        float e0 = expf(v0 - mx), e1 = expf(v1 - mx), e2 = expf(v2 - mx);
        float ssum = e0 + e1 + e2;
        sc[2] = e0 / ssum; sc[3] = e1 / ssum; sc[4] = e2 / ssum;
        sc[5] = softplusf(hd[133]);
    }
    __syncthreads();
    const float beta = sc[0], g = sc[1], s0 = sc[2], s1 = sc[3], s2 = sc[4],
                gamma = sc[5];
    float inner = kmat[((size_t)b * 4 + i) * 256 + tid];
    float K = inner / (kn * mnorm[tid] + 1e-8f);
    float x = beta * K;
    float mx = blk_max4(x, red4);
    float e = expf(x - mx);
    float se = blk_sum4(e, red4);
    float wc = e / se;
    float wg = g * wc + (1.f - g) * aprev[i * 256 + tid];
    wgs[tid] = wg;
    __syncthreads();
    float wconv = s0 * wg + s1 * wgs[(tid + 255) & 255] + s2 * wgs[(tid + 1) & 255];
    float wsh = powf(wconv, gamma);
    float ssum = blk_sum4(wsh, red4);
    float w = wsh / ssum;
    if (i < 2) hcat[(size_t)b * 1024 + 512 + i * 256 + tid] = f2bf(w);
    else       at[((size_t)(i - 2) * Bn + b) * 256 + tid] = w;
}

// ===========================================================================
// Dispatch 7 — k_tail: out GEMM (K=512 A-part + yh base + clip) + memt.
// ===========================================================================
__global__ __launch_bounds__(256) void k_tail(
    const unsigned short* __restrict__ HCAT,
    const unsigned short* __restrict__ WCOMB,
    const float* __restrict__ yh, const float* __restrict__ b_ou,
    const float* __restrict__ m0, const float* __restrict__ at,
    const float* __restrict__ era, const float* __restrict__ addv,
    float* __restrict__ out)
{
    GEMM_SHARED
    const int s = blockIdx.x;
    if (s < T_MEM) {
        // ---- out GEMM: y = clip(yh + A-cols @ WCOMB[k 512:] + b_ou) ----
        const unsigned short* A  = HCAT + 512;        const int lda = 1024;
        const unsigned short* Wt = WCOMB + 512;       const int ldw = 1024;
        const int row0 = (s & 31) * 64;
        const int col0 = (s >> 5) * 128;
        GEMM_REGS
        GEMM_MAINLOOP(512)
        #pragma unroll
        for (int i = 0; i < 2; ++i) {
            int m0r = row0 + wr * 32 + i * 16 + (lane >> 4) * 4;
            #pragma unroll
            for (int j = 0; j < 4; ++j) {
                int n = col0 + wc * 64 + j * 16 + (lane & 15);
                if (n >= 512) continue;
                float bv = b_ou[n];
                #pragma unroll
                for (int r = 0; r < 4; ++r) {
                    float v = acc[i][j][r] + bv + yh[(size_t)(m0r + r) * 512 + n];
                    out[(size_t)(m0r + r) * 512 + n] = fminf(fmaxf(v, -20.f), 20.f);
                }
            }
        }
    } else {
        // ---- memt: 8 batch rows per block, m0 reused 8x, NT stores ----
        const int tid = threadIdx.x;
        const int b0 = (s - T_MEM) * 8;
        float (*at_s)[8][256] = (float(*)[8][256])(&As[0][0]);     // 16 KB
        float (*er_s)[8][128] = (float(*)[8][128])(&Ws[0][0]);     // 8 KB
        float (*ad_s)[8][128] = (float(*)[8][128])(&Ws[0][4096]);  // 8 KB
        for (int t = tid; t < 1024; t += 256) {
            int i = t >> 9, rem = t & 511;
            int bb = rem >> 6, n4 = rem & 63;
            ((float4*)&at_s[i][bb][0])[n4] =
                ((const float4*)(at + ((size_t)i * Bn + b0 + bb) * 256))[n4];
        }
        for (int t = tid; t < 512; t += 256) {
            int i = t >> 8, rem = t & 255;
            int bb = rem >> 5, m4 = rem & 31;
            ((float4*)&er_s[i][bb][0])[m4] =
                ((const float4*)(era + ((size_t)(b0 + bb) * 2 + i) * 128))[m4];
            ((float4*)&ad_s[i][bb][0])[m4] =
                ((const float4*)(addv + ((size_t)(b0 + bb) * 2 + i) * 128))[m4];
        }
        __syncthreads();
        const float4* m0v = (const float4*)m0;
        float4* outv = (float4*)(out + (size_t)Bn * Un);
        for (int pos = tid; pos < 8192; pos += 256) {
            int mq = pos & 31, n = pos >> 5;
            float4 t0 = m0v[pos];
            #pragma unroll
            for (int bb = 0; bb < 8; ++bb) {
                float w0 = at_s[0][bb][n], w1 = at_s[1][bb][n];
                float4 e0 = *(const float4*)&er_s[0][bb][mq * 4];
                float4 a0 = *(const float4*)&ad_s[0][bb][mq * 4];
                float4 e1 = *(const float4*)&er_s[1][bb][mq * 4];
                float4 a1 = *(const float4*)&ad_s[1][bb][mq * 4];
                float4 t = t0;
#define UPD(c) { t.c = t.c * (1.f - w0 * e0.c) + w0 * a0.c; \
                 t.c = t.c * (1.f - w1 * e1.c) + w1 * a1.c; }
                UPD(x) UPD(y) UPD(z) UPD(w)
#undef UPD
                __builtin_nontemporal_store(*(f32x4*)&t,
                    (f32x4*)&outv[(size_t)(b0 + bb) * 8192 + pos]);
            }
        }
    }
}

extern "C" void kernel_launch(void* const* d_in, const int* in_sizes, int n_in,
                              void* d_out, int out_size, void* d_ws, size_t ws_size,
                              hipStream_t stream)
{
    const float* X      = (const float*)d_in[0];
    const float* m0     = (const float*)d_in[1];
    const float* H0     = (const float*)d_in[2];
    const float* C0     = (const float*)d_in[3];
    const float* R0     = (const float*)d_in[4];
    const float* A0     = (const float*)d_in[5];
    const float* W_prep = (const float*)d_in[6];
    const float* b_prep = (const float*)d_in[7];
    const float* W_lstm = (const float*)d_in[8];
    const float* b_lstm = (const float*)d_in[9];
    const float* W_r    = (const float*)d_in[10];
    const float* b_r    = (const float*)d_in[11];
    const float* W_w    = (const float*)d_in[12];
    const float* b_w    = (const float*)d_in[13];
    const float* W_ou   = (const float*)d_in[14];
    const float* b_ou   = (const float*)d_in[15];
    float* ws  = (float*)d_ws;
    float* out = (float*)d_out;

    unsigned short* XHB   = (unsigned short*)(ws + OFF_XHB);
    unsigned short* HCAT  = (unsigned short*)(ws + OFF_HCAT);
    unsigned short* W1T   = (unsigned short*)(ws + OFF_W1T);
    unsigned short* WRWT  = (unsigned short*)(ws + OFF_WRWT);
    unsigned short* WCOMB = (unsigned short*)(ws + OFF_WCOMB);
    unsigned short* M0B   = (unsigned short*)(ws + OFF_M0B);
    unsigned short* ZX    = (unsigned short*)(ws + OFF_KMAT);

    // 1. critical prep
    k_prep<<<P_END, 256, 0, stream>>>(
        X, m0, H0, R0, A0, W_prep, b_prep, W_lstm, b_r, b_w, W_ou, ws);

    // 2. LSTM0 + ZX (L1 X-part) + pfold + late prep (concurrent)
    k_mid<<<M_END, 256, 0, stream>>>(
        W_lstm, W_r, W_w, W_ou, H0, b_lstm, C0, ws);

    // 3. LSTM layer 1 (K=512 h1-part; ZX added in epilogue)
    gemm_lstm<<<dim3(32, 16), 256, 0, stream>>>(
        XHB + 512, 1024, W1T + 512, 1024, ws + OFF_ZPART, b_lstm, C0, ZX, HCAT);

    // 4. heads + yh (out h-part)
    k_heads<<<H_END, 256, 0, stream>>>(
        HCAT, WRWT, WCOMB, ws + OFF_BIASH, ws + OFF_HEADS, ws + OFF_YH);

    // 5. kmat (fused tanh)
    gemm_kmat<<<dim3(128, 2), 256, 0, stream>>>(
        ws + OFF_HEADS, M0B, ws + OFF_KMAT);

    // 6. addressing
    k_addr<<<dim3(Bn, 4), 256, 0, stream>>>(
        ws + OFF_HEADS, ws + OFF_KMAT, ws + OFF_MNORM, ws + OFF_APREV,
        ws + OFF_AT, HCAT, ws + OFF_ERA, ws + OFF_ADD);

    // 7. out GEMM (K=512 + yh) + memt (overlapped)
    k_tail<<<T_END, 256, 0, stream>>>(
        HCAT, WCOMB, ws + OFF_YH, b_ou, m0, ws + OFF_AT, ws + OFF_ERA,
        ws + OFF_ADD, out);
}